// Round 10
// baseline (633.510 us; speedup 1.0000x reference)
//
#include <hip/hip_runtime.h>

// ---------------------------------------------------------------------------
// DiT graph-attention block, MI355X (gfx950).
// R10: attn_gather 3-deep pipeline (2x batch-4 kv in flight + index batch
//      prefetch; R9 VGPR=28 => only 4 loads in flight), silu folded into
//      prep_weights, scan collapsed 3->2 kernels (scan_final self-reduces
//      block sums).  15 -> 13 launches.
// ---------------------------------------------------------------------------

typedef __attribute__((ext_vector_type(8))) short bf16x8;
typedef __attribute__((ext_vector_type(8))) unsigned short u16x8;
typedef __attribute__((ext_vector_type(4))) float f32x4;

__device__ __forceinline__ float bf2f(unsigned short u) {
  union { float f; unsigned int i; } x; x.i = ((unsigned int)u) << 16; return x.f;
}
__device__ __forceinline__ unsigned short f2bf(float f) {
  union { float f; unsigned int i; } x; x.f = f;
  unsigned int r = x.i + 0x7fffu + ((x.i >> 16) & 1u);  // RNE
  return (unsigned short)(r >> 16);
}

__device__ __forceinline__ void gload_lds16(const void* g, void* l) {
  __builtin_amdgcn_global_load_lds(
      (const __attribute__((address_space(1))) void*)g,
      (__attribute__((address_space(3))) void*)l, 16, 0, 0);
}

// ---------------------------------------------------------------------------
// Unified bf16 GEMM:  out = epilogue(A[M,K](lda) @ Bt[N,K]^T + bias)
// XCD-grouped 1-D grid (pid%8 = XCD; col-siblings consecutive on one XCD).
// EPI 0: out bf16 = acc+bias               (coalesced LDS-repack stores, ldo)
// EPI 1: out bf16 = gelu_tanh(acc+bias)    (coalesced LDS-repack stores, ldo)
// EPI 2: out f32  = xin + gate*(acc+bias)  (gate bf16 stride 1536, xin ldo)
// ---------------------------------------------------------------------------
template <int EPI>
__global__ __launch_bounds__(256)
void gemm_bf16(const unsigned short* __restrict__ A,
               const unsigned short* __restrict__ Bt,
               const float* __restrict__ bias,
               const float* __restrict__ xin,
               const unsigned short* __restrict__ gate,
               void* __restrict__ out,
               int M, int N, int K, int lda, int ldo) {
  const int NT = N >> 7;
  const int MT = (M + 127) >> 7;
  const int pid = blockIdx.x;
  const int xcd = pid & 7;
  const int j = pid >> 3;
  const int rb = xcd + 8 * (j / NT);
  const int cb = j - (j / NT) * NT;
  if (rb >= MT) return;  // uniform across block

  __shared__ unsigned short At[128 * 64];
  __shared__ unsigned short Bs[128 * 64];
  const int tid = threadIdx.x;
  const int wid = tid >> 6;
  const int lane = tid & 63;
  const int l15 = lane & 15, l4 = lane >> 4;
  const int row0 = rb * 128, col0 = cb * 128;
  const int wr = (wid >> 1) * 64, wc = (wid & 1) * 64;

  f32x4 acc[4][4];
  const f32x4 zf = {0.f, 0.f, 0.f, 0.f};
  for (int m = 0; m < 4; ++m)
    for (int n = 0; n < 4; ++n) acc[m][n] = zf;

  for (int kt = 0; kt < K; kt += 64) {
    __syncthreads();
#pragma unroll
    for (int s = 0; s < 4; ++s) {
      const int p = s * 4096 + tid * 16;           // physical byte in tile
      const int r = p >> 7;                        // tile row
      const int scb = (p & 127) ^ ((r & 7) << 4);  // swizzled source col byte
      int gr = row0 + r; gr = gr < M ? gr : M - 1;
      gload_lds16((const char*)A + ((size_t)gr * lda + kt) * 2 + scb,
                  (char*)At + s * 4096 + wid * 1024);
      const int gc = col0 + r;                     // N multiple of 128
      gload_lds16((const char*)Bt + ((size_t)gc * K + kt) * 2 + scb,
                  (char*)Bs + s * 4096 + wid * 1024);
    }
    __syncthreads();
#pragma unroll
    for (int kk = 0; kk < 64; kk += 32) {
      bf16x8 af[4], bfr[4];
#pragma unroll
      for (int m = 0; m < 4; ++m) {
        const int r = wr + m * 16 + l15;
        const int cb2 = ((kk + l4 * 8) * 2) ^ ((r & 7) << 4);
        af[m] = *(const bf16x8*)((const char*)At + r * 128 + cb2);
      }
#pragma unroll
      for (int n = 0; n < 4; ++n) {
        const int r = wc + n * 16 + l15;
        const int cb2 = ((kk + l4 * 8) * 2) ^ ((r & 7) << 4);
        bfr[n] = *(const bf16x8*)((const char*)Bs + r * 128 + cb2);
      }
#pragma unroll
      for (int m = 0; m < 4; ++m)
#pragma unroll
        for (int n = 0; n < 4; ++n)
          acc[m][n] = __builtin_amdgcn_mfma_f32_16x16x32_bf16(af[m], bfr[n],
                                                              acc[m][n], 0, 0, 0);
    }
  }

  // C/D layout: col=lane&15, row=(lane>>4)*4+reg   [guide §3, m89/m91]
  if (EPI == 2) {
#pragma unroll
    for (int m = 0; m < 4; ++m)
#pragma unroll
      for (int jj = 0; jj < 4; ++jj) {
        const int gr = row0 + wr + m * 16 + l4 * 4 + jj;
        if (gr >= M) continue;
#pragma unroll
        for (int n = 0; n < 4; ++n) {
          const int gc = col0 + wc + n * 16 + l15;
          const float v = acc[m][n][jj] + bias[gc];
          const float gt = bf2f(gate[(size_t)gr * 1536 + gc]);
          ((float*)out)[(size_t)gr * ldo + gc] =
              xin[(size_t)gr * ldo + gc] + gt * v;
        }
      }
  } else {
    // bf16 outputs: repack 64-row halves through At, store bf16x8 coalesced.
    // XOR swizzle (col ^ (row&12)<<2) spreads the 4 l4-quads over banks.
    __syncthreads();  // all LDS reads of K-loop done
#pragma unroll
    for (int half = 0; half < 2; ++half) {
      if ((wid >> 1) == half) {
#pragma unroll
        for (int m = 0; m < 4; ++m)
#pragma unroll
          for (int jj = 0; jj < 4; ++jj) {
            const int row_l = m * 16 + l4 * 4 + jj;  // 0..63
            const int swz = (row_l & 12) << 2;       // 0,16,32,48
#pragma unroll
            for (int n = 0; n < 4; ++n) {
              const int col = wc + n * 16 + l15;     // 0..127
              float v = acc[m][n][jj] + bias[col0 + col];
              if (EPI == 1) {
                // gelu_tanh(v) == v * sigmoid(2u), u = 0.79788(v+0.044715v^3)
                const float u2 = 1.5957691216f * (v + 0.044715f * v * v * v);
                v = v / (1.f + __expf(-u2));
              }
              At[row_l * 128 + (col ^ swz)] = f2bf(v);
            }
          }
      }
      __syncthreads();
#pragma unroll
      for (int p = 0; p < 4; ++p) {
        const int u = p * 256 + tid;        // 16B unit id, 1024 total
        const int row_l = u >> 4;           // 64 rows, 16 units each
        const int col8 = ((u & 15) * 8) ^ ((row_l & 12) << 2);
        const int gr = row0 + half * 64 + row_l;
        if (gr < M) {
          const bf16x8 vv = *(const bf16x8*)&At[row_l * 128 + col8];
          *(bf16x8*)((unsigned short*)out + (size_t)gr * ldo + col0 +
                     (((u & 15) * 8))) = vv;
        }
      }
      __syncthreads();
    }
  }
}

// ---------------------------------------------------------------------------
// helpers
// ---------------------------------------------------------------------------
__global__ void sentinel_fill(float* o, long n, float v) {
  long i = (long)blockIdx.x * blockDim.x + threadIdx.x;
  const long st = (long)gridDim.x * blockDim.x;
  for (; i < n; i += st) o[i] = (i == 0) ? v : 0.f;
}

// fused prep: weight transposes (kv-interleave for Wk/Wv), bias concat,
// deg zeroing, int64-detect, and silu(c)->bf16.  grid = dim3(max, 11).
__global__ void prep_weights(const float* __restrict__ Wc, const float* __restrict__ Wq,
                             const float* __restrict__ Wk, const float* __restrict__ Wv,
                             const float* __restrict__ Wo, const float* __restrict__ W1,
                             const float* __restrict__ W2,
                             unsigned short* __restrict__ Wct,
                             unsigned short* __restrict__ Wqkvt,
                             unsigned short* __restrict__ Wot,
                             unsigned short* __restrict__ W1t,
                             unsigned short* __restrict__ W2t,
                             const float* __restrict__ bq, const float* __restrict__ bk,
                             const float* __restrict__ bv, float* __restrict__ bqkv,
                             int* __restrict__ deg, int Mdeg,
                             const unsigned int* __restrict__ ei_u32, int E,
                             int* __restrict__ flag,
                             const float* __restrict__ c,
                             unsigned short* __restrict__ cs, int silu4) {
  const int job = blockIdx.y;
  const int i = blockIdx.x * 256 + threadIdx.x;
  if (job == 7) {  // bias concat (kv-interleaved)
    if (i < 256) bqkv[i] = bq[i];
    else if (i < 512) { int d = i - 256; bqkv[256 + ((d >> 2) << 3) + (d & 3)] = bk[d]; }
    else if (i < 768) { int d = i - 512; bqkv[256 + ((d >> 2) << 3) + 4 + (d & 3)] = bv[d]; }
    return;
  }
  if (job == 8) {  // zero deg
    if (i < Mdeg) deg[i] = 0;
    return;
  }
  if (job == 9) {  // int64 detect (block 0 only)
    if (blockIdx.x != 0) return;
    __shared__ int bad;
    if (threadIdx.x == 0) bad = 0;
    __syncthreads();
    const int n = E < 256 ? E : 256;
    if ((int)threadIdx.x < n && ei_u32[2 * threadIdx.x + 1] != 0u) atomicAdd(&bad, 1);
    __syncthreads();
    if (threadIdx.x == 0) *flag = (bad == 0);
    return;
  }
  if (job == 10) {  // silu(c) -> bf16, float4 granules
    if (i >= silu4) return;
    float4 v = *(const float4*)&c[(size_t)i * 4];
    ushort4 r;
    r.x = f2bf(v.x / (1.f + __expf(-v.x)));
    r.y = f2bf(v.y / (1.f + __expf(-v.y)));
    r.z = f2bf(v.z / (1.f + __expf(-v.z)));
    r.w = f2bf(v.w / (1.f + __expf(-v.w)));
    *(ushort4*)&cs[(size_t)i * 4] = r;
    return;
  }
  const float* W; unsigned short* Wt; int N, kc, mode = 0;
  switch (job) {
    case 0: W = Wc; Wt = Wct; N = 1536; kc = 256; break;
    case 1: W = Wq; Wt = Wqkvt; N = 256; kc = 256; break;
    case 2: W = Wk; Wt = Wqkvt + 256 * 256; N = 256; kc = 256; mode = 1; break;
    case 3: W = Wv; Wt = Wqkvt + 256 * 256; N = 256; kc = 256; mode = 2; break;
    case 4: W = Wo; Wt = Wot; N = 256; kc = 256; break;
    case 5: W = W1; Wt = W1t; N = 1024; kc = 256; break;
    default: W = W2; Wt = W2t; N = 256; kc = 1024; break;
  }
  if (i >= N * kc) return;
  const int kk = i / N, n = i - kk * N;
  int r = n;
  if (mode == 1) r = ((n >> 2) << 3) + (n & 3);
  else if (mode == 2) r = ((n >> 2) << 3) + 4 + (n & 3);
  Wt[(size_t)r * kc + kk] = f2bf(W[(size_t)kk * N + n]);
}

// one wave per row: h = ((x-mean)*rstd)*(1+scale)+shift -> bf16
__global__ void ln_modulate(const float* __restrict__ xin,
                            const unsigned short* __restrict__ modv,
                            unsigned short* __restrict__ hout,
                            int M, int cshift, int cscale) {
  const int wid = threadIdx.x >> 6, lane = threadIdx.x & 63;
  const int row = blockIdx.x * 4 + wid;
  if (row >= M) return;
  const float4 x4 = *(const float4*)&xin[(size_t)row * 256 + lane * 4];
  float s = x4.x + x4.y + x4.z + x4.w;
  float ss = x4.x * x4.x + x4.y * x4.y + x4.z * x4.z + x4.w * x4.w;
#pragma unroll
  for (int m = 1; m < 64; m <<= 1) {
    s += __shfl_xor(s, m, 64);
    ss += __shfl_xor(ss, m, 64);
  }
  const float mean = s * (1.f / 256.f);
  const float var = ss * (1.f / 256.f) - mean * mean;
  const float rstd = rsqrtf(var + 1e-6f);
  const ushort4 sh4 = *(const ushort4*)&modv[(size_t)row * 1536 + cshift * 256 + lane * 4];
  const ushort4 sc4 = *(const ushort4*)&modv[(size_t)row * 1536 + cscale * 256 + lane * 4];
  ushort4 o;
  o.x = f2bf((x4.x - mean) * rstd * (1.f + bf2f(sc4.x)) + bf2f(sh4.x));
  o.y = f2bf((x4.y - mean) * rstd * (1.f + bf2f(sc4.y)) + bf2f(sh4.y));
  o.z = f2bf((x4.z - mean) * rstd * (1.f + bf2f(sc4.z)) + bf2f(sh4.z));
  o.w = f2bf((x4.w - mean) * rstd * (1.f + bf2f(sc4.w)) + bf2f(sh4.w));
  *(ushort4*)&hout[(size_t)row * 256 + lane * 4] = o;
}

// unpack edge_index -> src32/dst32 and histogram dst degree (fused)
__global__ void conv_hist(const void* __restrict__ ei, const int* __restrict__ flag,
                          int* __restrict__ src32, int* __restrict__ dst32,
                          int* __restrict__ deg, int E) {
  int e = blockIdx.x * blockDim.x + threadIdx.x;
  if (e >= E) return;
  int s, d;
  if (*flag) {
    const long long* p = (const long long*)ei;
    s = (int)p[e]; d = (int)p[E + e];
  } else {
    const int* p = (const int*)ei;
    s = p[e]; d = p[E + e];
  }
  src32[e] = s; dst32[e] = d;
  atomicAdd(&deg[d], 1);
}

// 2-phase scan: per-block sums, then scan_final self-reduces the block sums
__global__ __launch_bounds__(256)
void block_sum(const int* __restrict__ deg, int* __restrict__ bsum, int M) {
  int i = blockIdx.x * 256 + threadIdx.x;
  int v = (i < M) ? deg[i] : 0;
#pragma unroll
  for (int d = 1; d < 64; d <<= 1) v += __shfl_xor(v, d, 64);
  __shared__ int ws[4];
  const int lane = threadIdx.x & 63, w = threadIdx.x >> 6;
  if (lane == 0) ws[w] = v;
  __syncthreads();
  if (threadIdx.x == 0) bsum[blockIdx.x] = ws[0] + ws[1] + ws[2] + ws[3];
}

__global__ __launch_bounds__(256)
void scan_final(const int* __restrict__ deg, const int* __restrict__ bsum,
                int* __restrict__ start, int* __restrict__ cursor, int M, int NB) {
  const int b = blockIdx.x, t = threadIdx.x, i = b * 256 + t;
  const int lane = t & 63, w = t >> 6;
  __shared__ int ws[4];
  __shared__ int pref;
  // per-thread inclusive scan of this block's deg chunk
  const int v = (i < M) ? deg[i] : 0;
  int s = v;
#pragma unroll
  for (int d = 1; d < 64; d <<= 1) {
    int u = __shfl_up(s, d, 64);
    if (lane >= d) s += u;
  }
  if (lane == 63) ws[w] = s;
  // wave 0 redundantly reduces bsum[0..b-1] (<= 4 chunks of 64)
  if (t < 64) {
    int acc = 0;
    for (int base = 0; base < b; base += 64) {
      const int idx = base + lane;
      acc += (idx < b) ? bsum[idx] : 0;
    }
#pragma unroll
    for (int d = 1; d < 64; d <<= 1) acc += __shfl_xor(acc, d, 64);
    if (lane == 0) pref = acc;
  }
  __syncthreads();
  int add = pref;
  for (int k = 0; k < w; ++k) add += ws[k];
  const int excl = s - v + add;
  if (i < M) { start[i] = excl; cursor[i] = excl; }
  if (i == M - 1) start[M] = excl + v;  // total = E
}

__global__ void csr_fill(const int* __restrict__ src32, const int* __restrict__ dst32,
                         int* __restrict__ cursor, int* __restrict__ csr, int E) {
  int e = blockIdx.x * blockDim.x + threadIdx.x;
  if (e >= E) return;
  int pos = atomicAdd(&cursor[dst32[e]], 1);
  csr[pos] = src32[e];
}

// one wave per dst node; 3-deep pipeline: 2 batch-4 kv groups in flight plus
// prefetched index batch.  qkv row: q(256) | kv-interleaved(512).
__global__ __launch_bounds__(256)
void attn_gather(const int* __restrict__ csr, const int* __restrict__ start,
                 const unsigned short* __restrict__ qkv,
                 unsigned short* __restrict__ aggb, int M) {
  const int wid = threadIdx.x >> 6, lane = threadIdx.x & 63;
  const int row = blockIdx.x * 4 + wid;
  if (row >= M) return;
  const ushort4 q4 = *(const ushort4*)&qkv[(size_t)row * 768 + lane * 4];
  const float SC = 0.17677669529663687f;  // 32^-0.5, folded into q
  const float qf0 = bf2f(q4.x) * SC, qf1 = bf2f(q4.y) * SC;
  const float qf2 = bf2f(q4.z) * SC, qf3 = bf2f(q4.w) * SC;
  const int b0 = start[row], e0 = start[row + 1];
  float den = 0.f, a0 = 0.f, a1 = 0.f, a2 = 0.f, a3 = 0.f;

  auto LDV = [&](int src) {
    return *(const u16x8*)&qkv[(size_t)src * 768 + 256 + lane * 8];
  };
#define PROC(kvv)                                                            \
  {                                                                          \
    float s = qf0 * bf2f(kvv[0]) + qf1 * bf2f(kvv[1]) +                      \
              qf2 * bf2f(kvv[2]) + qf3 * bf2f(kvv[3]);                       \
    s += __shfl_xor(s, 1, 64);                                               \
    s += __shfl_xor(s, 2, 64);                                               \
    s += __shfl_xor(s, 4, 64);                                               \
    const float ex = __expf(s);                                              \
    den += ex;                                                               \
    a0 += ex * bf2f(kvv[4]); a1 += ex * bf2f(kvv[5]);                        \
    a2 += ex * bf2f(kvv[6]); a3 += ex * bf2f(kvv[7]);                        \
  }

  int i = b0;
  if (e0 - i >= 8) {
    u16x8 kA0 = LDV(csr[i]), kA1 = LDV(csr[i + 1]);
    u16x8 kA2 = LDV(csr[i + 2]), kA3 = LDV(csr[i + 3]);
    u16x8 kB0 = LDV(csr[i + 4]), kB1 = LDV(csr[i + 5]);
    u16x8 kB2 = LDV(csr[i + 6]), kB3 = LDV(csr[i + 7]);
    while (i + 12 <= e0) {
      const u16x8 kC0 = LDV(csr[i + 8]), kC1 = LDV(csr[i + 9]);
      const u16x8 kC2 = LDV(csr[i + 10]), kC3 = LDV(csr[i + 11]);
      PROC(kA0); PROC(kA1); PROC(kA2); PROC(kA3);
      kA0 = kB0; kA1 = kB1; kA2 = kB2; kA3 = kB3;
      kB0 = kC0; kB1 = kC1; kB2 = kC2; kB3 = kC3;
      i += 4;
    }
    PROC(kA0); PROC(kA1); PROC(kA2); PROC(kA3); i += 4;
    PROC(kB0); PROC(kB1); PROC(kB2); PROC(kB3); i += 4;
  } else if (e0 - i >= 4) {
    const u16x8 kA0 = LDV(csr[i]), kA1 = LDV(csr[i + 1]);
    const u16x8 kA2 = LDV(csr[i + 2]), kA3 = LDV(csr[i + 3]);
    PROC(kA0); PROC(kA1); PROC(kA2); PROC(kA3); i += 4;
  }
  for (; i < e0; ++i) {
    const u16x8 kv = LDV(csr[i]);
    PROC(kv);
  }
#undef PROC

  const float inv = den > 0.f ? 1.f / den : 0.f;
  ushort4 r;
  r.x = f2bf(a0 * inv); r.y = f2bf(a1 * inv);
  r.z = f2bf(a2 * inv); r.w = f2bf(a3 * inv);
  *(ushort4*)&aggb[(size_t)row * 256 + lane * 4] = r;
}

// ---------------------------------------------------------------------------
extern "C" void kernel_launch(void* const* d_in, const int* in_sizes, int n_in,
                              void* d_out, int out_size, void* d_ws, size_t ws_size,
                              hipStream_t stream) {
  (void)n_in;
  const float* x  = (const float*)d_in[0];
  const float* c  = (const float*)d_in[1];
  const void*  ei = d_in[2];
  const float* Wq = (const float*)d_in[3];
  const float* bq = (const float*)d_in[4];
  const float* Wk = (const float*)d_in[5];
  const float* bk = (const float*)d_in[6];
  const float* Wv = (const float*)d_in[7];
  const float* bv = (const float*)d_in[8];
  const float* Wo = (const float*)d_in[9];
  const float* bo = (const float*)d_in[10];
  const float* W1 = (const float*)d_in[11];
  const float* b1 = (const float*)d_in[12];
  const float* W2 = (const float*)d_in[13];
  const float* b2 = (const float*)d_in[14];
  const float* Wc = (const float*)d_in[15];
  const float* bc = (const float*)d_in[16];

  const int M = in_sizes[0] / 256;   // 50000
  const int E = in_sizes[2] / 2;     // 800000

  char* ws = (char*)d_ws;
  size_t off = 0;
  auto carve = [&](size_t bytes) {
    char* p = ws + off;
    off = (off + bytes + 255) & ~(size_t)255;
    return p;
  };
  // persistent: modv [M,1536]b; cols 0..1024 reused as h2 (ldo=1536) after ln2
  unsigned short* modv = (unsigned short*)carve((size_t)M * 1536 * 2);  // 153.6MB
  // region D (M*1536 bytes): cs [M,256]b -> qkv [M,768]b -> X1 [M,256]f32
  char* D = carve((size_t)M * 1536);
  unsigned short* cs  = (unsigned short*)D;
  unsigned short* qkv = (unsigned short*)D;
  float* X1 = (float*)D;
  unsigned short* Wct   = (unsigned short*)carve((size_t)1536 * 256 * 2);
  unsigned short* Wqkvt = (unsigned short*)carve((size_t)768 * 256 * 2);
  unsigned short* Wot   = (unsigned short*)carve((size_t)256 * 256 * 2);
  unsigned short* W1t   = (unsigned short*)carve((size_t)1024 * 256 * 2);
  unsigned short* W2t   = (unsigned short*)carve((size_t)256 * 1024 * 2);
  float* bqkv = (float*)carve(768 * 4);
  int* flag = (int*)carve(256);
  // CSR buffers
  int* src32  = (int*)carve((size_t)E * 4);
  int* dst32  = (int*)carve((size_t)E * 4);
  int* deg    = (int*)carve((size_t)(M + 4) * 4);
  int* startp = (int*)carve((size_t)(M + 4) * 4);
  int* cursor = (int*)carve((size_t)(M + 4) * 4);
  int* csr    = (int*)carve((size_t)E * 4);
  int* bsum   = (int*)carve(1024);

  // d_out (M*256 f32 = M*1024 bytes) aliases:
  //   lower half: hbuf (ln1 out) then hbuf2 (ln2 out)   [M,256]b each
  //   upper half: aggb (attn out)                        [M,256]b
  unsigned short* hbuf  = (unsigned short*)d_out;
  unsigned short* hbuf2 = (unsigned short*)d_out;
  unsigned short* aggb  = (unsigned short*)((char*)d_out + (size_t)M * 512);
  float* xout = (float*)d_out;

  if (off > ws_size) {
    sentinel_fill<<<2048, 256, 0, stream>>>((float*)d_out, (long)out_size,
                                            (float)ws_size);
    return;
  }

  const int tb = 256;
  const int EB = (E + tb - 1) / tb;
  const int SB = (M + 255) / 256;
  const int silu4 = M * 64;
  const int PB = (silu4 + 255) / 256;  // 12500 > 1536: covers all jobs

  // fused prep: 7 weight transposes + bias concat + deg zero + detect + silu
  prep_weights<<<dim3(PB, 11), 256, 0, stream>>>(
      Wc, Wq, Wk, Wv, Wo, W1, W2, Wct, Wqkvt, Wot, W1t, W2t,
      bq, bk, bv, bqkv, deg, M + 4, (const unsigned int*)ei, E, flag,
      c, cs, silu4);
  // --- CSR build ---
  conv_hist<<<EB, tb, 0, stream>>>(ei, flag, src32, dst32, deg, E);
  block_sum<<<SB, 256, 0, stream>>>(deg, bsum, M);
  scan_final<<<SB, 256, 0, stream>>>(deg, bsum, startp, cursor, M, SB);
  csr_fill<<<EB, tb, 0, stream>>>(src32, dst32, cursor, csr, E);

  auto gsz = [](int Mz, int Nz) {
    int MT = (Mz + 127) / 128, NT = Nz / 128;
    return 8 * ((MT + 7) / 8) * NT;
  };
  // modv = cs @ Wc + bc   [M,1536]
  gemm_bf16<0><<<gsz(M, 1536), 256, 0, stream>>>(cs, Wct, bc, nullptr, nullptr,
                                                 modv, M, 1536, 256, 256, 1536);
  // hbuf = modulate(ln(x), shift_msa, scale_msa)
  ln_modulate<<<(M + 3) / 4, 256, 0, stream>>>(x, modv, hbuf, M, 0, 1);
  // qkv = hbuf @ [Wq | kv-interleaved Wk,Wv] + bias   [M,768]
  gemm_bf16<0><<<gsz(M, 768), 256, 0, stream>>>(hbuf, Wqkvt, bqkv, nullptr, nullptr,
                                                qkv, M, 768, 256, 256, 768);
  // aggb(d_out hi) = per-dst softmax gather (no atomics)
  attn_gather<<<(M + 3) / 4, 256, 0, stream>>>(csr, startp, qkv, aggb, M);
  // X1(D) = x + gate_msa * (aggb @ Wo + bo)   [f32]
  gemm_bf16<2><<<gsz(M, 256), 256, 0, stream>>>(aggb, Wot, bo, x, modv + 512,
                                                X1, M, 256, 256, 256, 256);
  // hbuf2(d_out lo) = modulate(ln(X1), shift_mlp, scale_mlp)
  ln_modulate<<<(M + 3) / 4, 256, 0, stream>>>(X1, modv, hbuf2, M, 3, 4);
  // h2(modv cols 0..1024, ld 1536) = gelu(hbuf2 @ W1 + b1)   [M,1024]
  gemm_bf16<1><<<gsz(M, 1024), 256, 0, stream>>>(hbuf2, W1t, b1, nullptr, nullptr,
                                                 modv, M, 1024, 256, 256, 1536);
  // out(d_out) = X1 + gate_mlp * (h2 @ W2 + b2)
  gemm_bf16<2><<<gsz(M, 256), 256, 0, stream>>>(modv, W2t, b2, X1, modv + 1280,
                                                xout, M, 256, 1024, 1536, 256);
}

// Round 11
// 573.539 us; speedup vs baseline: 1.1046x; 1.1046x over previous
//
#include <hip/hip_runtime.h>

// ---------------------------------------------------------------------------
// DiT graph-attention block, MI355X (gfx950).
// R11: revert R10 regressions (prep grid, attn depth). k/v stored as fp8
//      e5m2 (= truncated f16: decode is a byte shift) -> gather traffic
//      halves (820->410 MB; kernel was at the L3/fabric BW ceiling).
//      qkv GEMM split: q GEMM (bf16) + kv GEMM (EPI3 fp8 epilogue).
// ---------------------------------------------------------------------------

typedef __attribute__((ext_vector_type(8))) short bf16x8;
typedef __attribute__((ext_vector_type(2))) _Float16 h2_t;
typedef __attribute__((ext_vector_type(4))) float f32x4;

__device__ __forceinline__ float bf2f(unsigned short u) {
  union { float f; unsigned int i; } x; x.i = ((unsigned int)u) << 16; return x.f;
}
__device__ __forceinline__ unsigned short f2bf(float f) {
  union { float f; unsigned int i; } x; x.f = f;
  unsigned int r = x.i + 0x7fffu + ((x.i >> 16) & 1u);  // RNE
  return (unsigned short)(r >> 16);
}

__device__ __forceinline__ void gload_lds16(const void* g, void* l) {
  __builtin_amdgcn_global_load_lds(
      (const __attribute__((address_space(1))) void*)g,
      (__attribute__((address_space(3))) void*)l, 16, 0, 0);
}

// ---------------------------------------------------------------------------
// Unified bf16 GEMM:  out = epilogue(A[M,K](lda) @ Bt[N,K]^T + bias)
// XCD-grouped 1-D grid (pid%8 = XCD; col-siblings consecutive on one XCD).
// EPI 0: out bf16 = acc+bias                (coalesced LDS-repack, ldo u16)
// EPI 1: out bf16 = gelu(acc+bias)          (coalesced LDS-repack, ldo u16)
// EPI 2: out f32  = xin + gate*(acc+bias)   (gate bf16 stride 1536, xin ldo)
// EPI 3: out fp8 e5m2 = acc+bias            (byte repack; out pre-offset,
//                                            ldo = row stride in BYTES)
// ---------------------------------------------------------------------------
template <int EPI>
__global__ __launch_bounds__(256)
void gemm_bf16(const unsigned short* __restrict__ A,
               const unsigned short* __restrict__ Bt,
               const float* __restrict__ bias,
               const float* __restrict__ xin,
               const unsigned short* __restrict__ gate,
               void* __restrict__ out,
               int M, int N, int K, int lda, int ldo) {
  const int NT = N >> 7;
  const int MT = (M + 127) >> 7;
  const int pid = blockIdx.x;
  const int xcd = pid & 7;
  const int j = pid >> 3;
  const int rb = xcd + 8 * (j / NT);
  const int cb = j - (j / NT) * NT;
  if (rb >= MT) return;  // uniform across block

  __shared__ unsigned short At[128 * 64];
  __shared__ unsigned short Bs[128 * 64];
  const int tid = threadIdx.x;
  const int wid = tid >> 6;
  const int lane = tid & 63;
  const int l15 = lane & 15, l4 = lane >> 4;
  const int row0 = rb * 128, col0 = cb * 128;
  const int wr = (wid >> 1) * 64, wc = (wid & 1) * 64;

  f32x4 acc[4][4];
  const f32x4 zf = {0.f, 0.f, 0.f, 0.f};
  for (int m = 0; m < 4; ++m)
    for (int n = 0; n < 4; ++n) acc[m][n] = zf;

  for (int kt = 0; kt < K; kt += 64) {
    __syncthreads();
#pragma unroll
    for (int s = 0; s < 4; ++s) {
      const int p = s * 4096 + tid * 16;           // physical byte in tile
      const int r = p >> 7;                        // tile row
      const int scb = (p & 127) ^ ((r & 7) << 4);  // swizzled source col byte
      int gr = row0 + r; gr = gr < M ? gr : M - 1;
      gload_lds16((const char*)A + ((size_t)gr * lda + kt) * 2 + scb,
                  (char*)At + s * 4096 + wid * 1024);
      const int gc = col0 + r;                     // N multiple of 128
      gload_lds16((const char*)Bt + ((size_t)gc * K + kt) * 2 + scb,
                  (char*)Bs + s * 4096 + wid * 1024);
    }
    __syncthreads();
#pragma unroll
    for (int kk = 0; kk < 64; kk += 32) {
      bf16x8 af[4], bfr[4];
#pragma unroll
      for (int m = 0; m < 4; ++m) {
        const int r = wr + m * 16 + l15;
        const int cb2 = ((kk + l4 * 8) * 2) ^ ((r & 7) << 4);
        af[m] = *(const bf16x8*)((const char*)At + r * 128 + cb2);
      }
#pragma unroll
      for (int n = 0; n < 4; ++n) {
        const int r = wc + n * 16 + l15;
        const int cb2 = ((kk + l4 * 8) * 2) ^ ((r & 7) << 4);
        bfr[n] = *(const bf16x8*)((const char*)Bs + r * 128 + cb2);
      }
#pragma unroll
      for (int m = 0; m < 4; ++m)
#pragma unroll
        for (int n = 0; n < 4; ++n)
          acc[m][n] = __builtin_amdgcn_mfma_f32_16x16x32_bf16(af[m], bfr[n],
                                                              acc[m][n], 0, 0, 0);
    }
  }

  // C/D layout: col=lane&15, row=(lane>>4)*4+reg   [guide §3, m89/m91]
  if (EPI == 2) {
#pragma unroll
    for (int m = 0; m < 4; ++m)
#pragma unroll
      for (int jj = 0; jj < 4; ++jj) {
        const int gr = row0 + wr + m * 16 + l4 * 4 + jj;
        if (gr >= M) continue;
#pragma unroll
        for (int n = 0; n < 4; ++n) {
          const int gc = col0 + wc + n * 16 + l15;
          const float v = acc[m][n][jj] + bias[gc];
          const float gt = bf2f(gate[(size_t)gr * 1536 + gc]);
          ((float*)out)[(size_t)gr * ldo + gc] =
              xin[(size_t)gr * ldo + gc] + gt * v;
        }
      }
  } else if (EPI == 3) {
    // fp8 e5m2 output: byte repack through At (8KB/half), 16B stores
    __syncthreads();
#pragma unroll
    for (int half = 0; half < 2; ++half) {
      if ((wid >> 1) == half) {
#pragma unroll
        for (int m = 0; m < 4; ++m)
#pragma unroll
          for (int jj = 0; jj < 4; ++jj) {
            const int row_l = m * 16 + l4 * 4 + jj;  // 0..63
            const int swz = (row_l & 12) << 2;       // byte XOR 0/16/32/48
#pragma unroll
            for (int n = 0; n < 4; ++n) {
              const int col = wc + n * 16 + l15;     // 0..127 (1B each)
              const float v = acc[m][n][jj] + bias[col0 + col];
              const unsigned short h =
                  __builtin_bit_cast(unsigned short, (_Float16)v);
              const unsigned char b8 =
                  (unsigned char)((h + 0x7fu + ((h >> 8) & 1u)) >> 8);
              ((unsigned char*)At)[row_l * 128 + (col ^ swz)] = b8;
            }
          }
      }
      __syncthreads();
#pragma unroll
      for (int p = 0; p < 2; ++p) {
        const int u = p * 256 + tid;        // 512 16B units (64 rows x 8)
        const int row_l = u >> 3;
        const int cb16 = (u & 7) * 16;
        const int gr = row0 + half * 64 + row_l;
        if (gr < M) {
          const bf16x8 vv = *(const bf16x8*)((const unsigned char*)At +
                                             row_l * 128 +
                                             (cb16 ^ ((row_l & 12) << 2)));
          *(bf16x8*)((unsigned char*)out + (size_t)gr * ldo + col0 + cb16) = vv;
        }
      }
      __syncthreads();
    }
  } else {
    // bf16 outputs: repack 64-row halves through At, store bf16x8 coalesced.
    __syncthreads();
#pragma unroll
    for (int half = 0; half < 2; ++half) {
      if ((wid >> 1) == half) {
#pragma unroll
        for (int m = 0; m < 4; ++m)
#pragma unroll
          for (int jj = 0; jj < 4; ++jj) {
            const int row_l = m * 16 + l4 * 4 + jj;  // 0..63
            const int swz = (row_l & 12) << 2;       // u16 XOR 0,16,32,48
#pragma unroll
            for (int n = 0; n < 4; ++n) {
              const int col = wc + n * 16 + l15;     // 0..127
              float v = acc[m][n][jj] + bias[col0 + col];
              if (EPI == 1) {
                // gelu_tanh(v) == v * sigmoid(2u), u = 0.79788(v+0.044715v^3)
                const float u2 = 1.5957691216f * (v + 0.044715f * v * v * v);
                v = v / (1.f + __expf(-u2));
              }
              At[row_l * 128 + (col ^ swz)] = f2bf(v);
            }
          }
      }
      __syncthreads();
#pragma unroll
      for (int p = 0; p < 4; ++p) {
        const int u = p * 256 + tid;        // 16B unit id, 1024 total
        const int row_l = u >> 4;           // 64 rows, 16 units each
        const int col8 = ((u & 15) * 8) ^ ((row_l & 12) << 2);
        const int gr = row0 + half * 64 + row_l;
        if (gr < M) {
          const bf16x8 vv = *(const bf16x8*)&At[row_l * 128 + col8];
          *(bf16x8*)((unsigned short*)out + (size_t)gr * ldo + col0 +
                     (((u & 15) * 8))) = vv;
        }
      }
      __syncthreads();
    }
  }
}

// ---------------------------------------------------------------------------
// helpers
// ---------------------------------------------------------------------------
__global__ void sentinel_fill(float* o, long n, float v) {
  long i = (long)blockIdx.x * blockDim.x + threadIdx.x;
  const long st = (long)gridDim.x * blockDim.x;
  for (; i < n; i += st) o[i] = (i == 0) ? v : 0.f;
}

// fused prep: weight transposes (kv-interleave for Wk/Wv), bias concat,
// deg zeroing, int64-detect.  grid = dim3(1536, 10).
__global__ void prep_weights(const float* __restrict__ Wc, const float* __restrict__ Wq,
                             const float* __restrict__ Wk, const float* __restrict__ Wv,
                             const float* __restrict__ Wo, const float* __restrict__ W1,
                             const float* __restrict__ W2,
                             unsigned short* __restrict__ Wct,
                             unsigned short* __restrict__ Wqkvt,
                             unsigned short* __restrict__ Wot,
                             unsigned short* __restrict__ W1t,
                             unsigned short* __restrict__ W2t,
                             const float* __restrict__ bq, const float* __restrict__ bk,
                             const float* __restrict__ bv, float* __restrict__ bqkv,
                             int* __restrict__ deg, int Mdeg,
                             const unsigned int* __restrict__ ei_u32, int E,
                             int* __restrict__ flag) {
  const int job = blockIdx.y;
  const int i = blockIdx.x * 256 + threadIdx.x;
  if (job == 7) {  // bias concat (kv-interleaved)
    if (i < 256) bqkv[i] = bq[i];
    else if (i < 512) { int d = i - 256; bqkv[256 + ((d >> 2) << 3) + (d & 3)] = bk[d]; }
    else if (i < 768) { int d = i - 512; bqkv[256 + ((d >> 2) << 3) + 4 + (d & 3)] = bv[d]; }
    return;
  }
  if (job == 8) {  // zero deg
    if (i < Mdeg) deg[i] = 0;
    return;
  }
  if (job == 9) {  // int64 detect (block 0 only)
    if (blockIdx.x != 0) return;
    __shared__ int bad;
    if (threadIdx.x == 0) bad = 0;
    __syncthreads();
    const int n = E < 256 ? E : 256;
    if ((int)threadIdx.x < n && ei_u32[2 * threadIdx.x + 1] != 0u) atomicAdd(&bad, 1);
    __syncthreads();
    if (threadIdx.x == 0) *flag = (bad == 0);
    return;
  }
  const float* W; unsigned short* Wt; int N, kc, mode = 0;
  switch (job) {
    case 0: W = Wc; Wt = Wct; N = 1536; kc = 256; break;
    case 1: W = Wq; Wt = Wqkvt; N = 256; kc = 256; break;
    case 2: W = Wk; Wt = Wqkvt + 256 * 256; N = 256; kc = 256; mode = 1; break;
    case 3: W = Wv; Wt = Wqkvt + 256 * 256; N = 256; kc = 256; mode = 2; break;
    case 4: W = Wo; Wt = Wot; N = 256; kc = 256; break;
    case 5: W = W1; Wt = W1t; N = 1024; kc = 256; break;
    default: W = W2; Wt = W2t; N = 256; kc = 1024; break;
  }
  if (i >= N * kc) return;
  const int kk = i / N, n = i - kk * N;
  int r = n;
  if (mode == 1) r = ((n >> 2) << 3) + (n & 3);
  else if (mode == 2) r = ((n >> 2) << 3) + 4 + (n & 3);
  Wt[(size_t)r * kc + kk] = f2bf(W[(size_t)kk * N + n]);
}

__global__ void silu_cast(const float* __restrict__ c, unsigned short* __restrict__ o,
                          int total4) {
  int i = blockIdx.x * blockDim.x + threadIdx.x;
  if (i >= total4) return;
  float4 v = *(const float4*)&c[(size_t)i * 4];
  ushort4 r;
  r.x = f2bf(v.x / (1.f + __expf(-v.x)));
  r.y = f2bf(v.y / (1.f + __expf(-v.y)));
  r.z = f2bf(v.z / (1.f + __expf(-v.z)));
  r.w = f2bf(v.w / (1.f + __expf(-v.w)));
  *(ushort4*)&o[(size_t)i * 4] = r;
}

// one wave per row: h = ((x-mean)*rstd)*(1+scale)+shift -> bf16
__global__ void ln_modulate(const float* __restrict__ xin,
                            const unsigned short* __restrict__ modv,
                            unsigned short* __restrict__ hout,
                            int M, int cshift, int cscale) {
  const int wid = threadIdx.x >> 6, lane = threadIdx.x & 63;
  const int row = blockIdx.x * 4 + wid;
  if (row >= M) return;
  const float4 x4 = *(const float4*)&xin[(size_t)row * 256 + lane * 4];
  float s = x4.x + x4.y + x4.z + x4.w;
  float ss = x4.x * x4.x + x4.y * x4.y + x4.z * x4.z + x4.w * x4.w;
#pragma unroll
  for (int m = 1; m < 64; m <<= 1) {
    s += __shfl_xor(s, m, 64);
    ss += __shfl_xor(ss, m, 64);
  }
  const float mean = s * (1.f / 256.f);
  const float var = ss * (1.f / 256.f) - mean * mean;
  const float rstd = rsqrtf(var + 1e-6f);
  const ushort4 sh4 = *(const ushort4*)&modv[(size_t)row * 1536 + cshift * 256 + lane * 4];
  const ushort4 sc4 = *(const ushort4*)&modv[(size_t)row * 1536 + cscale * 256 + lane * 4];
  ushort4 o;
  o.x = f2bf((x4.x - mean) * rstd * (1.f + bf2f(sc4.x)) + bf2f(sh4.x));
  o.y = f2bf((x4.y - mean) * rstd * (1.f + bf2f(sc4.y)) + bf2f(sh4.y));
  o.z = f2bf((x4.z - mean) * rstd * (1.f + bf2f(sc4.z)) + bf2f(sh4.z));
  o.w = f2bf((x4.w - mean) * rstd * (1.f + bf2f(sc4.w)) + bf2f(sh4.w));
  *(ushort4*)&hout[(size_t)row * 256 + lane * 4] = o;
}

// unpack edge_index -> src32/dst32 and histogram dst degree (fused)
__global__ void conv_hist(const void* __restrict__ ei, const int* __restrict__ flag,
                          int* __restrict__ src32, int* __restrict__ dst32,
                          int* __restrict__ deg, int E) {
  int e = blockIdx.x * blockDim.x + threadIdx.x;
  if (e >= E) return;
  int s, d;
  if (*flag) {
    const long long* p = (const long long*)ei;
    s = (int)p[e]; d = (int)p[E + e];
  } else {
    const int* p = (const int*)ei;
    s = p[e]; d = p[E + e];
  }
  src32[e] = s; dst32[e] = d;
  atomicAdd(&deg[d], 1);
}

// 2-phase scan: per-block sums, then scan_final self-reduces the block sums
__global__ __launch_bounds__(256)
void block_sum(const int* __restrict__ deg, int* __restrict__ bsum, int M) {
  int i = blockIdx.x * 256 + threadIdx.x;
  int v = (i < M) ? deg[i] : 0;
#pragma unroll
  for (int d = 1; d < 64; d <<= 1) v += __shfl_xor(v, d, 64);
  __shared__ int ws[4];
  const int lane = threadIdx.x & 63, w = threadIdx.x >> 6;
  if (lane == 0) ws[w] = v;
  __syncthreads();
  if (threadIdx.x == 0) bsum[blockIdx.x] = ws[0] + ws[1] + ws[2] + ws[3];
}

__global__ __launch_bounds__(256)
void scan_final(const int* __restrict__ deg, const int* __restrict__ bsum,
                int* __restrict__ start, int* __restrict__ cursor, int M, int NB) {
  const int b = blockIdx.x, t = threadIdx.x, i = b * 256 + t;
  const int lane = t & 63, w = t >> 6;
  __shared__ int ws[4];
  __shared__ int pref;
  const int v = (i < M) ? deg[i] : 0;
  int s = v;
#pragma unroll
  for (int d = 1; d < 64; d <<= 1) {
    int u = __shfl_up(s, d, 64);
    if (lane >= d) s += u;
  }
  if (lane == 63) ws[w] = s;
  if (t < 64) {  // wave 0 reduces bsum[0..b-1]
    int acc = 0;
    for (int base = 0; base < b; base += 64) {
      const int idx = base + lane;
      acc += (idx < b) ? bsum[idx] : 0;
    }
#pragma unroll
    for (int d = 1; d < 64; d <<= 1) acc += __shfl_xor(acc, d, 64);
    if (lane == 0) pref = acc;
  }
  __syncthreads();
  int add = pref;
  for (int k = 0; k < w; ++k) add += ws[k];
  const int excl = s - v + add;
  if (i < M) { start[i] = excl; cursor[i] = excl; }
  if (i == M - 1) start[M] = excl + v;
}

__global__ void csr_fill(const int* __restrict__ src32, const int* __restrict__ dst32,
                         int* __restrict__ cursor, int* __restrict__ csr, int E) {
  int e = blockIdx.x * blockDim.x + threadIdx.x;
  if (e >= E) return;
  int pos = atomicAdd(&cursor[dst32[e]], 1);
  csr[pos] = src32[e];
}

// one wave per dst node; 2-deep batch-4 pipeline.  Row layout (1024 B):
// [q bf16 512B][kv fp8 e5m2 512B, lane l's 8B = k[4l..4l+3]|v[4l..4l+3]].
// e5m2 -> f16 decode is an exact byte shift.
__global__ __launch_bounds__(256)
void attn_gather(const int* __restrict__ csr, const int* __restrict__ start,
                 const unsigned char* __restrict__ qkvp,
                 unsigned short* __restrict__ aggb, int M) {
  const int wid = threadIdx.x >> 6, lane = threadIdx.x & 63;
  const int row = blockIdx.x * 4 + wid;
  if (row >= M) return;
  const ushort4 q4 = *(const ushort4*)(qkvp + (size_t)row * 1024 + lane * 8);
  const float SC = 0.17677669529663687f;  // 32^-0.5, folded into q
  const float qf0 = bf2f(q4.x) * SC, qf1 = bf2f(q4.y) * SC;
  const float qf2 = bf2f(q4.z) * SC, qf3 = bf2f(q4.w) * SC;
  const int b0 = start[row], e0 = start[row + 1];
  float den = 0.f, a0 = 0.f, a1 = 0.f, a2 = 0.f, a3 = 0.f;

  auto LDKV = [&](int src) {
    return *(const uint2*)(qkvp + (size_t)src * 1024 + 512 + lane * 8);
  };
#define PROC(kv2)                                                              \
  {                                                                            \
    const unsigned kd = kv2.x, vd = kv2.y;                                     \
    const unsigned klo = ((kd << 8) & 0x0000ff00u) | ((kd << 16) & 0xff000000u);\
    const unsigned khi = ((kd >> 8) & 0x0000ff00u) | (kd & 0xff000000u);       \
    const h2_t k01 = __builtin_bit_cast(h2_t, klo);                            \
    const h2_t k23 = __builtin_bit_cast(h2_t, khi);                            \
    float s = qf0 * (float)k01[0] + qf1 * (float)k01[1] +                      \
              qf2 * (float)k23[0] + qf3 * (float)k23[1];                       \
    s += __shfl_xor(s, 1, 64);                                                 \
    s += __shfl_xor(s, 2, 64);                                                 \
    s += __shfl_xor(s, 4, 64);                                                 \
    const float ex = __expf(s);                                                \
    const unsigned vlo = ((vd << 8) & 0x0000ff00u) | ((vd << 16) & 0xff000000u);\
    const unsigned vhi = ((vd >> 8) & 0x0000ff00u) | (vd & 0xff000000u);       \
    const h2_t v01 = __builtin_bit_cast(h2_t, vlo);                            \
    const h2_t v23 = __builtin_bit_cast(h2_t, vhi);                            \
    den += ex;                                                                 \
    a0 += ex * (float)v01[0]; a1 += ex * (float)v01[1];                        \
    a2 += ex * (float)v23[0]; a3 += ex * (float)v23[1];                        \
  }

  int i = b0;
  if (i + 4 <= e0) {
    uint2 A0 = LDKV(csr[i]), A1 = LDKV(csr[i + 1]);
    uint2 A2 = LDKV(csr[i + 2]), A3 = LDKV(csr[i + 3]);
    while (i + 8 <= e0) {
      const uint2 B0 = LDKV(csr[i + 4]), B1 = LDKV(csr[i + 5]);
      const uint2 B2 = LDKV(csr[i + 6]), B3 = LDKV(csr[i + 7]);
      PROC(A0); PROC(A1); PROC(A2); PROC(A3);
      A0 = B0; A1 = B1; A2 = B2; A3 = B3;
      i += 4;
    }
    PROC(A0); PROC(A1); PROC(A2); PROC(A3);
    i += 4;
  }
  for (; i < e0; ++i) {
    const uint2 kv2 = LDKV(csr[i]);
    PROC(kv2);
  }
#undef PROC

  const float inv = den > 0.f ? 1.f / den : 0.f;
  ushort4 r;
  r.x = f2bf(a0 * inv); r.y = f2bf(a1 * inv);
  r.z = f2bf(a2 * inv); r.w = f2bf(a3 * inv);
  *(ushort4*)&aggb[(size_t)row * 256 + lane * 4] = r;
}

// ---------------------------------------------------------------------------
extern "C" void kernel_launch(void* const* d_in, const int* in_sizes, int n_in,
                              void* d_out, int out_size, void* d_ws, size_t ws_size,
                              hipStream_t stream) {
  (void)n_in;
  const float* x  = (const float*)d_in[0];
  const float* c  = (const float*)d_in[1];
  const void*  ei = d_in[2];
  const float* Wq = (const float*)d_in[3];
  const float* bq = (const float*)d_in[4];
  const float* Wk = (const float*)d_in[5];
  const float* bk = (const float*)d_in[6];
  const float* Wv = (const float*)d_in[7];
  const float* bv = (const float*)d_in[8];
  const float* Wo = (const float*)d_in[9];
  const float* bo = (const float*)d_in[10];
  const float* W1 = (const float*)d_in[11];
  const float* b1 = (const float*)d_in[12];
  const float* W2 = (const float*)d_in[13];
  const float* b2 = (const float*)d_in[14];
  const float* Wc = (const float*)d_in[15];
  const float* bc = (const float*)d_in[16];

  const int M = in_sizes[0] / 256;   // 50000
  const int E = in_sizes[2] / 2;     // 800000

  char* ws = (char*)d_ws;
  size_t off = 0;
  auto carve = [&](size_t bytes) {
    char* p = ws + off;
    off = (off + bytes + 255) & ~(size_t)255;
    return p;
  };
  // persistent: modv [M,1536]b; cols 0..1024 reused as h2 (ldo=1536) after ln2
  unsigned short* modv = (unsigned short*)carve((size_t)M * 1536 * 2);  // 153.6MB
  // region D (M*1024 bytes): cs [M,256]b -> qkvp [M,1024B] -> X1 [M,256]f32
  char* D = carve((size_t)M * 1024);
  unsigned short* cs = (unsigned short*)D;
  unsigned char* qkvp = (unsigned char*)D;
  float* X1 = (float*)D;
  unsigned short* Wct   = (unsigned short*)carve((size_t)1536 * 256 * 2);
  unsigned short* Wqkvt = (unsigned short*)carve((size_t)768 * 256 * 2);
  unsigned short* Wot   = (unsigned short*)carve((size_t)256 * 256 * 2);
  unsigned short* W1t   = (unsigned short*)carve((size_t)1024 * 256 * 2);
  unsigned short* W2t   = (unsigned short*)carve((size_t)256 * 1024 * 2);
  float* bqkv = (float*)carve(768 * 4);
  int* flag = (int*)carve(256);
  // CSR buffers
  int* src32  = (int*)carve((size_t)E * 4);
  int* dst32  = (int*)carve((size_t)E * 4);
  int* deg    = (int*)carve((size_t)(M + 4) * 4);
  int* startp = (int*)carve((size_t)(M + 4) * 4);
  int* cursor = (int*)carve((size_t)(M + 4) * 4);
  int* csr    = (int*)carve((size_t)E * 4);
  int* bsum   = (int*)carve(1024);

  // d_out aliases: lo half hbuf/hbuf2 [M,256]b; hi half aggb [M,256]b
  unsigned short* hbuf  = (unsigned short*)d_out;
  unsigned short* hbuf2 = (unsigned short*)d_out;
  unsigned short* aggb  = (unsigned short*)((char*)d_out + (size_t)M * 512);
  float* xout = (float*)d_out;

  if (off > ws_size) {
    sentinel_fill<<<2048, 256, 0, stream>>>((float*)d_out, (long)out_size,
                                            (float)ws_size);
    return;
  }

  const int tb = 256;
  const int EB = (E + tb - 1) / tb;
  const int SB = (M + 255) / 256;

  prep_weights<<<dim3(1536, 10), 256, 0, stream>>>(
      Wc, Wq, Wk, Wv, Wo, W1, W2, Wct, Wqkvt, Wot, W1t, W2t,
      bq, bk, bv, bqkv, deg, M + 4, (const unsigned int*)ei, E, flag);
  // --- CSR build ---
  conv_hist<<<EB, tb, 0, stream>>>(ei, flag, src32, dst32, deg, E);
  block_sum<<<SB, 256, 0, stream>>>(deg, bsum, M);
  scan_final<<<SB, 256, 0, stream>>>(deg, bsum, startp, cursor, M, SB);
  csr_fill<<<EB, tb, 0, stream>>>(src32, dst32, cursor, csr, E);

  auto gsz = [](int Mz, int Nz) {
    int MT = (Mz + 127) / 128, NT = Nz / 128;
    return 8 * ((MT + 7) / 8) * NT;
  };
  // cs = bf16(silu(c))
  silu_cast<<<(M * 64 + tb - 1) / tb, tb, 0, stream>>>(c, cs, M * 64);
  // modv = cs @ Wc + bc   [M,1536]
  gemm_bf16<0><<<gsz(M, 1536), 256, 0, stream>>>(cs, Wct, bc, nullptr, nullptr,
                                                 modv, M, 1536, 256, 256, 1536);
  // hbuf = modulate(ln(x), shift_msa, scale_msa)
  ln_modulate<<<(M + 3) / 4, 256, 0, stream>>>(x, modv, hbuf, M, 0, 1);
  // q part: bf16 into qkvp rows (stride 1024B = 512 u16)
  gemm_bf16<0><<<gsz(M, 256), 256, 0, stream>>>(hbuf, Wqkvt, bqkv, nullptr,
                                                nullptr, qkvp, M, 256, 256,
                                                256, 512);
  // kv part: fp8 e5m2 into qkvp rows at byte offset 512 (stride 1024B)
  gemm_bf16<3><<<gsz(M, 512), 256, 0, stream>>>(hbuf, Wqkvt + 256 * 256,
                                                bqkv + 256, nullptr, nullptr,
                                                qkvp + 512, M, 512, 256,
                                                256, 1024);
  // aggb(d_out hi) = per-dst softmax gather (fp8 kv)
  attn_gather<<<(M + 3) / 4, 256, 0, stream>>>(csr, startp, qkvp, aggb, M);
  // X1(D) = x + gate_msa * (aggb @ Wo + bo)   [f32]
  gemm_bf16<2><<<gsz(M, 256), 256, 0, stream>>>(aggb, Wot, bo, x, modv + 512,
                                                X1, M, 256, 256, 256, 256);
  // hbuf2(d_out lo) = modulate(ln(X1), shift_mlp, scale_mlp)
  ln_modulate<<<(M + 3) / 4, 256, 0, stream>>>(X1, modv, hbuf2, M, 3, 4);
  // h2(modv cols 0..1024, ld 1536) = gelu(hbuf2 @ W1 + b1)   [M,1024]
  gemm_bf16<1><<<gsz(M, 1024), 256, 0, stream>>>(hbuf2, W1t, b1, nullptr, nullptr,
                                                 modv, M, 1024, 256, 256, 1536);
  // out(d_out) = X1 + gate_mlp * (h2 @ W2 + b2)
  gemm_bf16<2><<<gsz(M, 256), 256, 0, stream>>>(modv, W2t, b2, X1, modv + 1280,
                                                xout, M, 256, 1024, 1536, 256);
}

// Round 12
// 484.149 us; speedup vs baseline: 1.3085x; 1.1846x over previous
//
#include <hip/hip_runtime.h>

// ---------------------------------------------------------------------------
// DiT graph-attention block, MI355X (gfx950).
// R12: GEMM restructured 4->8 waves/block (wave tile 64x32, acc 4x2 = 32 regs
//      vs 64; R11 showed 168 unified regs -> 2 waves/SIMD -> 20% occupancy).
//      Single-pass 128x128 repack epilogue (2 barriers vs 5). X1 kept bf16
//      (saves ~77MB traffic; error ~0.004 << threshold).
// ---------------------------------------------------------------------------

typedef __attribute__((ext_vector_type(8))) short bf16x8;
typedef __attribute__((ext_vector_type(2))) _Float16 h2_t;
typedef __attribute__((ext_vector_type(4))) float f32x4;

__device__ __forceinline__ float bf2f(unsigned short u) {
  union { float f; unsigned int i; } x; x.i = ((unsigned int)u) << 16; return x.f;
}
__device__ __forceinline__ unsigned short f2bf(float f) {
  union { float f; unsigned int i; } x; x.f = f;
  unsigned int r = x.i + 0x7fffu + ((x.i >> 16) & 1u);  // RNE
  return (unsigned short)(r >> 16);
}

__device__ __forceinline__ void gload_lds16(const void* g, void* l) {
  __builtin_amdgcn_global_load_lds(
      (const __attribute__((address_space(1))) void*)g,
      (__attribute__((address_space(3))) void*)l, 16, 0, 0);
}

// ---------------------------------------------------------------------------
// Unified bf16 GEMM:  out = epilogue(A[M,K](lda) @ Bt[N,K]^T + bias)
// 8 waves/block, wave tile 64x32.  XCD-grouped 1-D grid.
// EPI 0: out bf16 = acc+bias                (full-tile LDS repack, ldo u16)
// EPI 1: out bf16 = gelu(acc+bias)          (repack)
// EPI 2: out = xin + gate*(acc+bias)        (XINBF/OUTBF select f32/bf16)
// EPI 3: out fp8 e5m2 = acc+bias            (byte repack; ldo bytes)
// ---------------------------------------------------------------------------
template <int EPI, int XINBF, int OUTBF>
__global__ __launch_bounds__(512)
void gemm_bf16(const unsigned short* __restrict__ A,
               const unsigned short* __restrict__ Bt,
               const float* __restrict__ bias,
               const void* __restrict__ xin,
               const unsigned short* __restrict__ gate,
               void* __restrict__ out,
               int M, int N, int K, int lda, int ldo) {
  const int NT = N >> 7;
  const int MT = (M + 127) >> 7;
  const int pid = blockIdx.x;
  const int j = pid >> 3;
  const int rb = (pid & 7) + 8 * (j / NT);
  const int cb = j - (j / NT) * NT;
  if (rb >= MT) return;  // uniform across block

  __shared__ char smem[32768];
  unsigned short* At = (unsigned short*)smem;            // [128][64] bf16
  unsigned short* Bs = (unsigned short*)(smem + 16384);  // [128][64] bf16
  const int tid = threadIdx.x;
  const int wid = tid >> 6;
  const int lane = tid & 63;
  const int l15 = lane & 15, l4 = lane >> 4;
  const int row0 = rb * 128, col0 = cb * 128;
  const int wr = (wid >> 2) * 64;   // 0,64
  const int wc = (wid & 3) * 32;    // 0,32,64,96

  f32x4 acc[4][2];
  const f32x4 zf = {0.f, 0.f, 0.f, 0.f};
  for (int m = 0; m < 4; ++m)
    for (int n = 0; n < 2; ++n) acc[m][n] = zf;

  for (int kt = 0; kt < K; kt += 64) {
    __syncthreads();
#pragma unroll
    for (int s = 0; s < 2; ++s) {
      const int p = s * 8192 + tid * 16;           // byte in 16KB tile
      const int r = p >> 7;                        // tile row 0..127
      const int scb = (p & 127) ^ ((r & 7) << 4);  // swizzled source col byte
      int gr = row0 + r; gr = gr < M ? gr : M - 1;
      gload_lds16((const char*)A + ((size_t)gr * lda + kt) * 2 + scb,
                  (char*)At + s * 8192 + wid * 1024);
      const int gc = col0 + r;                     // N multiple of 128
      gload_lds16((const char*)Bt + ((size_t)gc * K + kt) * 2 + scb,
                  (char*)Bs + s * 8192 + wid * 1024);
    }
    __syncthreads();
#pragma unroll
    for (int kk = 0; kk < 64; kk += 32) {
      bf16x8 af[4], bfr[2];
#pragma unroll
      for (int m = 0; m < 4; ++m) {
        const int r = wr + m * 16 + l15;
        const int cb2 = ((kk + l4 * 8) * 2) ^ ((r & 7) << 4);
        af[m] = *(const bf16x8*)((const char*)At + r * 128 + cb2);
      }
#pragma unroll
      for (int n = 0; n < 2; ++n) {
        const int r = wc + n * 16 + l15;
        const int cb2 = ((kk + l4 * 8) * 2) ^ ((r & 7) << 4);
        bfr[n] = *(const bf16x8*)((const char*)Bs + r * 128 + cb2);
      }
#pragma unroll
      for (int m = 0; m < 4; ++m)
#pragma unroll
        for (int n = 0; n < 2; ++n)
          acc[m][n] = __builtin_amdgcn_mfma_f32_16x16x32_bf16(af[m], bfr[n],
                                                              acc[m][n], 0, 0, 0);
    }
  }

  // C/D layout: col=lane&15, row=(lane>>4)*4+reg   [guide §3, m89/m91]
  if (EPI == 2) {
#pragma unroll
    for (int m = 0; m < 4; ++m)
#pragma unroll
      for (int jj = 0; jj < 4; ++jj) {
        const int gr = row0 + wr + m * 16 + l4 * 4 + jj;
        if (gr >= M) continue;
#pragma unroll
        for (int n = 0; n < 2; ++n) {
          const int gc = col0 + wc + n * 16 + l15;
          const float v = acc[m][n][jj] + bias[gc];
          const float gt = bf2f(gate[(size_t)gr * 1536 + gc]);
          const float xv =
              XINBF ? bf2f(((const unsigned short*)xin)[(size_t)gr * ldo + gc])
                    : ((const float*)xin)[(size_t)gr * ldo + gc];
          const float rv = xv + gt * v;
          if (OUTBF)
            ((unsigned short*)out)[(size_t)gr * ldo + gc] = f2bf(rv);
          else
            ((float*)out)[(size_t)gr * ldo + gc] = rv;
        }
      }
  } else if (EPI == 3) {
    // fp8 e5m2: byte repack through smem [128][128]B, 16B stores
    __syncthreads();
#pragma unroll
    for (int m = 0; m < 4; ++m)
#pragma unroll
      for (int jj = 0; jj < 4; ++jj) {
        const int row_l = wr + m * 16 + l4 * 4 + jj;  // 0..127
        const int swz = (row_l & 12) << 2;
#pragma unroll
        for (int n = 0; n < 2; ++n) {
          const int col = wc + n * 16 + l15;          // 0..127
          const float v = acc[m][n][jj] + bias[col0 + col];
          const unsigned short h =
              __builtin_bit_cast(unsigned short, (_Float16)v);
          const unsigned char b8 =
              (unsigned char)((h + 0x7fu + ((h >> 8) & 1u)) >> 8);
          ((unsigned char*)smem)[row_l * 128 + (col ^ swz)] = b8;
        }
      }
    __syncthreads();
#pragma unroll
    for (int pp = 0; pp < 2; ++pp) {
      const int u = pp * 512 + tid;       // 1024 16B units
      const int row_l = u >> 3;
      const int cb16 = (u & 7) * 16;
      const int gr = row0 + row_l;
      if (gr < M) {
        const bf16x8 vv = *(const bf16x8*)((const unsigned char*)smem +
                                           row_l * 128 +
                                           (cb16 ^ ((row_l & 12) << 2)));
        *(bf16x8*)((unsigned char*)out + (size_t)gr * ldo + col0 + cb16) = vv;
      }
    }
  } else {
    // bf16 out: full-tile repack through smem [128][128] u16, 16B stores
    __syncthreads();
    unsigned short* R = (unsigned short*)smem;
#pragma unroll
    for (int m = 0; m < 4; ++m)
#pragma unroll
      for (int jj = 0; jj < 4; ++jj) {
        const int row_l = wr + m * 16 + l4 * 4 + jj;  // 0..127
        const int swz = (row_l & 12) << 2;            // u16 XOR 0/16/32/48
#pragma unroll
        for (int n = 0; n < 2; ++n) {
          const int col = wc + n * 16 + l15;
          float v = acc[m][n][jj] + bias[col0 + col];
          if (EPI == 1) {
            // gelu_tanh(v) == v * sigmoid(2u), u = 0.79788(v+0.044715v^3)
            const float u2 = 1.5957691216f * (v + 0.044715f * v * v * v);
            v = v / (1.f + __expf(-u2));
          }
          R[row_l * 128 + (col ^ swz)] = f2bf(v);
        }
      }
    __syncthreads();
#pragma unroll
    for (int pp = 0; pp < 4; ++pp) {
      const int u = pp * 512 + tid;       // 2048 16B units
      const int row_l = u >> 4;
      const int col8 = (u & 15) * 8;
      const int gr = row0 + row_l;
      if (gr < M) {
        const bf16x8 vv =
            *(const bf16x8*)&R[row_l * 128 + (col8 ^ ((row_l & 12) << 2))];
        *(bf16x8*)((unsigned short*)out + (size_t)gr * ldo + col0 + col8) = vv;
      }
    }
  }
}

// ---------------------------------------------------------------------------
// helpers
// ---------------------------------------------------------------------------
__global__ void sentinel_fill(float* o, long n, float v) {
  long i = (long)blockIdx.x * blockDim.x + threadIdx.x;
  const long st = (long)gridDim.x * blockDim.x;
  for (; i < n; i += st) o[i] = (i == 0) ? v : 0.f;
}

// fused prep: weight transposes (kv-interleave for Wk/Wv), bias concat,
// deg zeroing, int64-detect.  grid = dim3(1536, 10).
__global__ void prep_weights(const float* __restrict__ Wc, const float* __restrict__ Wq,
                             const float* __restrict__ Wk, const float* __restrict__ Wv,
                             const float* __restrict__ Wo, const float* __restrict__ W1,
                             const float* __restrict__ W2,
                             unsigned short* __restrict__ Wct,
                             unsigned short* __restrict__ Wqkvt,
                             unsigned short* __restrict__ Wot,
                             unsigned short* __restrict__ W1t,
                             unsigned short* __restrict__ W2t,
                             const float* __restrict__ bq, const float* __restrict__ bk,
                             const float* __restrict__ bv, float* __restrict__ bqkv,
                             int* __restrict__ deg, int Mdeg,
                             const unsigned int* __restrict__ ei_u32, int E,
                             int* __restrict__ flag) {
  const int job = blockIdx.y;
  const int i = blockIdx.x * 256 + threadIdx.x;
  if (job == 7) {  // bias concat (kv-interleaved)
    if (i < 256) bqkv[i] = bq[i];
    else if (i < 512) { int d = i - 256; bqkv[256 + ((d >> 2) << 3) + (d & 3)] = bk[d]; }
    else if (i < 768) { int d = i - 512; bqkv[256 + ((d >> 2) << 3) + 4 + (d & 3)] = bv[d]; }
    return;
  }
  if (job == 8) {  // zero deg
    if (i < Mdeg) deg[i] = 0;
    return;
  }
  if (job == 9) {  // int64 detect (block 0 only)
    if (blockIdx.x != 0) return;
    __shared__ int bad;
    if (threadIdx.x == 0) bad = 0;
    __syncthreads();
    const int n = E < 256 ? E : 256;
    if ((int)threadIdx.x < n && ei_u32[2 * threadIdx.x + 1] != 0u) atomicAdd(&bad, 1);
    __syncthreads();
    if (threadIdx.x == 0) *flag = (bad == 0);
    return;
  }
  const float* W; unsigned short* Wt; int N, kc, mode = 0;
  switch (job) {
    case 0: W = Wc; Wt = Wct; N = 1536; kc = 256; break;
    case 1: W = Wq; Wt = Wqkvt; N = 256; kc = 256; break;
    case 2: W = Wk; Wt = Wqkvt + 256 * 256; N = 256; kc = 256; mode = 1; break;
    case 3: W = Wv; Wt = Wqkvt + 256 * 256; N = 256; kc = 256; mode = 2; break;
    case 4: W = Wo; Wt = Wot; N = 256; kc = 256; break;
    case 5: W = W1; Wt = W1t; N = 1024; kc = 256; break;
    default: W = W2; Wt = W2t; N = 256; kc = 1024; break;
  }
  if (i >= N * kc) return;
  const int kk = i / N, n = i - kk * N;
  int r = n;
  if (mode == 1) r = ((n >> 2) << 3) + (n & 3);
  else if (mode == 2) r = ((n >> 2) << 3) + 4 + (n & 3);
  Wt[(size_t)r * kc + kk] = f2bf(W[(size_t)kk * N + n]);
}

__global__ void silu_cast(const float* __restrict__ c, unsigned short* __restrict__ o,
                          int total4) {
  int i = blockIdx.x * blockDim.x + threadIdx.x;
  if (i >= total4) return;
  float4 v = *(const float4*)&c[(size_t)i * 4];
  ushort4 r;
  r.x = f2bf(v.x / (1.f + __expf(-v.x)));
  r.y = f2bf(v.y / (1.f + __expf(-v.y)));
  r.z = f2bf(v.z / (1.f + __expf(-v.z)));
  r.w = f2bf(v.w / (1.f + __expf(-v.w)));
  *(ushort4*)&o[(size_t)i * 4] = r;
}

// one wave per row: h = ((x-mean)*rstd)*(1+scale)+shift -> bf16
// INBF: input rows are bf16 (X1) instead of f32
template <int INBF>
__global__ void ln_modulate(const void* __restrict__ xin,
                            const unsigned short* __restrict__ modv,
                            unsigned short* __restrict__ hout,
                            int M, int cshift, int cscale) {
  const int wid = threadIdx.x >> 6, lane = threadIdx.x & 63;
  const int row = blockIdx.x * 4 + wid;
  if (row >= M) return;
  float4 x4;
  if (INBF) {
    const ushort4 u4 =
        *(const ushort4*)((const unsigned short*)xin + (size_t)row * 256 + lane * 4);
    x4.x = bf2f(u4.x); x4.y = bf2f(u4.y); x4.z = bf2f(u4.z); x4.w = bf2f(u4.w);
  } else {
    x4 = *(const float4*)((const float*)xin + (size_t)row * 256 + lane * 4);
  }
  float s = x4.x + x4.y + x4.z + x4.w;
  float ss = x4.x * x4.x + x4.y * x4.y + x4.z * x4.z + x4.w * x4.w;
#pragma unroll
  for (int m = 1; m < 64; m <<= 1) {
    s += __shfl_xor(s, m, 64);
    ss += __shfl_xor(ss, m, 64);
  }
  const float mean = s * (1.f / 256.f);
  const float var = ss * (1.f / 256.f) - mean * mean;
  const float rstd = rsqrtf(var + 1e-6f);
  const ushort4 sh4 = *(const ushort4*)&modv[(size_t)row * 1536 + cshift * 256 + lane * 4];
  const ushort4 sc4 = *(const ushort4*)&modv[(size_t)row * 1536 + cscale * 256 + lane * 4];
  ushort4 o;
  o.x = f2bf((x4.x - mean) * rstd * (1.f + bf2f(sc4.x)) + bf2f(sh4.x));
  o.y = f2bf((x4.y - mean) * rstd * (1.f + bf2f(sc4.y)) + bf2f(sh4.y));
  o.z = f2bf((x4.z - mean) * rstd * (1.f + bf2f(sc4.z)) + bf2f(sh4.z));
  o.w = f2bf((x4.w - mean) * rstd * (1.f + bf2f(sc4.w)) + bf2f(sh4.w));
  *(ushort4*)&hout[(size_t)row * 256 + lane * 4] = o;
}

// unpack edge_index -> src32/dst32 and histogram dst degree (fused)
__global__ void conv_hist(const void* __restrict__ ei, const int* __restrict__ flag,
                          int* __restrict__ src32, int* __restrict__ dst32,
                          int* __restrict__ deg, int E) {
  int e = blockIdx.x * blockDim.x + threadIdx.x;
  if (e >= E) return;
  int s, d;
  if (*flag) {
    const long long* p = (const long long*)ei;
    s = (int)p[e]; d = (int)p[E + e];
  } else {
    const int* p = (const int*)ei;
    s = p[e]; d = p[E + e];
  }
  src32[e] = s; dst32[e] = d;
  atomicAdd(&deg[d], 1);
}

// 2-phase scan: per-block sums, then scan_final self-reduces the block sums
__global__ __launch_bounds__(256)
void block_sum(const int* __restrict__ deg, int* __restrict__ bsum, int M) {
  int i = blockIdx.x * 256 + threadIdx.x;
  int v = (i < M) ? deg[i] : 0;
#pragma unroll
  for (int d = 1; d < 64; d <<= 1) v += __shfl_xor(v, d, 64);
  __shared__ int ws[4];
  const int lane = threadIdx.x & 63, w = threadIdx.x >> 6;
  if (lane == 0) ws[w] = v;
  __syncthreads();
  if (threadIdx.x == 0) bsum[blockIdx.x] = ws[0] + ws[1] + ws[2] + ws[3];
}

__global__ __launch_bounds__(256)
void scan_final(const int* __restrict__ deg, const int* __restrict__ bsum,
                int* __restrict__ start, int* __restrict__ cursor, int M, int NB) {
  const int b = blockIdx.x, t = threadIdx.x, i = b * 256 + t;
  const int lane = t & 63, w = t >> 6;
  __shared__ int ws[4];
  __shared__ int pref;
  const int v = (i < M) ? deg[i] : 0;
  int s = v;
#pragma unroll
  for (int d = 1; d < 64; d <<= 1) {
    int u = __shfl_up(s, d, 64);
    if (lane >= d) s += u;
  }
  if (lane == 63) ws[w] = s;
  if (t < 64) {  // wave 0 reduces bsum[0..b-1]
    int acc = 0;
    for (int base = 0; base < b; base += 64) {
      const int idx = base + lane;
      acc += (idx < b) ? bsum[idx] : 0;
    }
#pragma unroll
    for (int d = 1; d < 64; d <<= 1) acc += __shfl_xor(acc, d, 64);
    if (lane == 0) pref = acc;
  }
  __syncthreads();
  int add = pref;
  for (int k = 0; k < w; ++k) add += ws[k];
  const int excl = s - v + add;
  if (i < M) { start[i] = excl; cursor[i] = excl; }
  if (i == M - 1) start[M] = excl + v;
}

__global__ void csr_fill(const int* __restrict__ src32, const int* __restrict__ dst32,
                         int* __restrict__ cursor, int* __restrict__ csr, int E) {
  int e = blockIdx.x * blockDim.x + threadIdx.x;
  if (e >= E) return;
  int pos = atomicAdd(&cursor[dst32[e]], 1);
  csr[pos] = src32[e];
}

// one wave per dst node; 2-deep batch-4 pipeline.  Row layout (1024 B):
// [q bf16 512B][kv fp8 e5m2 512B, lane l's 8B = k[4l..4l+3]|v[4l..4l+3]].
__global__ __launch_bounds__(256)
void attn_gather(const int* __restrict__ csr, const int* __restrict__ start,
                 const unsigned char* __restrict__ qkvp,
                 unsigned short* __restrict__ aggb, int M) {
  const int wid = threadIdx.x >> 6, lane = threadIdx.x & 63;
  const int row = blockIdx.x * 4 + wid;
  if (row >= M) return;
  const ushort4 q4 = *(const ushort4*)(qkvp + (size_t)row * 1024 + lane * 8);
  const float SC = 0.17677669529663687f;  // 32^-0.5, folded into q
  const float qf0 = bf2f(q4.x) * SC, qf1 = bf2f(q4.y) * SC;
  const float qf2 = bf2f(q4.z) * SC, qf3 = bf2f(q4.w) * SC;
  const int b0 = start[row], e0 = start[row + 1];
  float den = 0.f, a0 = 0.f, a1 = 0.f, a2 = 0.f, a3 = 0.f;

  auto LDKV = [&](int src) {
    return *(const uint2*)(qkvp + (size_t)src * 1024 + 512 + lane * 8);
  };
#define PROC(kv2)                                                              \
  {                                                                            \
    const unsigned kd = kv2.x, vd = kv2.y;                                     \
    const unsigned klo = ((kd << 8) & 0x0000ff00u) | ((kd << 16) & 0xff000000u);\
    const unsigned khi = ((kd >> 8) & 0x0000ff00u) | (kd & 0xff000000u);       \
    const h2_t k01 = __builtin_bit_cast(h2_t, klo);                            \
    const h2_t k23 = __builtin_bit_cast(h2_t, khi);                            \
    float s = qf0 * (float)k01[0] + qf1 * (float)k01[1] +                      \
              qf2 * (float)k23[0] + qf3 * (float)k23[1];                       \
    s += __shfl_xor(s, 1, 64);                                                 \
    s += __shfl_xor(s, 2, 64);                                                 \
    s += __shfl_xor(s, 4, 64);                                                 \
    const float ex = __expf(s);                                                \
    const unsigned vlo = ((vd << 8) & 0x0000ff00u) | ((vd << 16) & 0xff000000u);\
    const unsigned vhi = ((vd >> 8) & 0x0000ff00u) | (vd & 0xff000000u);       \
    const h2_t v01 = __builtin_bit_cast(h2_t, vlo);                            \
    const h2_t v23 = __builtin_bit_cast(h2_t, vhi);                            \
    den += ex;                                                                 \
    a0 += ex * (float)v01[0]; a1 += ex * (float)v01[1];                        \
    a2 += ex * (float)v23[0]; a3 += ex * (float)v23[1];                        \
  }

  int i = b0;
  if (i + 4 <= e0) {
    uint2 A0 = LDKV(csr[i]), A1 = LDKV(csr[i + 1]);
    uint2 A2 = LDKV(csr[i + 2]), A3 = LDKV(csr[i + 3]);
    while (i + 8 <= e0) {
      const uint2 B0 = LDKV(csr[i + 4]), B1 = LDKV(csr[i + 5]);
      const uint2 B2 = LDKV(csr[i + 6]), B3 = LDKV(csr[i + 7]);
      PROC(A0); PROC(A1); PROC(A2); PROC(A3);
      A0 = B0; A1 = B1; A2 = B2; A3 = B3;
      i += 4;
    }
    PROC(A0); PROC(A1); PROC(A2); PROC(A3);
    i += 4;
  }
  for (; i < e0; ++i) {
    const uint2 kv2 = LDKV(csr[i]);
    PROC(kv2);
  }
#undef PROC

  const float inv = den > 0.f ? 1.f / den : 0.f;
  ushort4 r;
  r.x = f2bf(a0 * inv); r.y = f2bf(a1 * inv);
  r.z = f2bf(a2 * inv); r.w = f2bf(a3 * inv);
  *(ushort4*)&aggb[(size_t)row * 256 + lane * 4] = r;
}

// ---------------------------------------------------------------------------
extern "C" void kernel_launch(void* const* d_in, const int* in_sizes, int n_in,
                              void* d_out, int out_size, void* d_ws, size_t ws_size,
                              hipStream_t stream) {
  (void)n_in;
  const float* x  = (const float*)d_in[0];
  const float* c  = (const float*)d_in[1];
  const void*  ei = d_in[2];
  const float* Wq = (const float*)d_in[3];
  const float* bq = (const float*)d_in[4];
  const float* Wk = (const float*)d_in[5];
  const float* bk = (const float*)d_in[6];
  const float* Wv = (const float*)d_in[7];
  const float* bv = (const float*)d_in[8];
  const float* Wo = (const float*)d_in[9];
  const float* bo = (const float*)d_in[10];
  const float* W1 = (const float*)d_in[11];
  const float* b1 = (const float*)d_in[12];
  const float* W2 = (const float*)d_in[13];
  const float* b2 = (const float*)d_in[14];
  const float* Wc = (const float*)d_in[15];
  const float* bc = (const float*)d_in[16];

  const int M = in_sizes[0] / 256;   // 50000
  const int E = in_sizes[2] / 2;     // 800000

  char* ws = (char*)d_ws;
  size_t off = 0;
  auto carve = [&](size_t bytes) {
    char* p = ws + off;
    off = (off + bytes + 255) & ~(size_t)255;
    return p;
  };
  // persistent: modv [M,1536]b; cols 0..1024 reused as h2 (ldo=1536) after ln2
  unsigned short* modv = (unsigned short*)carve((size_t)M * 1536 * 2);  // 153.6MB
  // region D (M*1024 bytes): cs -> qkvp [M,1024B] -> X1b [M,256]bf16
  char* D = carve((size_t)M * 1024);
  unsigned short* cs = (unsigned short*)D;
  unsigned char* qkvp = (unsigned char*)D;
  unsigned short* X1b = (unsigned short*)D;
  unsigned short* Wct   = (unsigned short*)carve((size_t)1536 * 256 * 2);
  unsigned short* Wqkvt = (unsigned short*)carve((size_t)768 * 256 * 2);
  unsigned short* Wot   = (unsigned short*)carve((size_t)256 * 256 * 2);
  unsigned short* W1t   = (unsigned short*)carve((size_t)1024 * 256 * 2);
  unsigned short* W2t   = (unsigned short*)carve((size_t)256 * 1024 * 2);
  float* bqkv = (float*)carve(768 * 4);
  int* flag = (int*)carve(256);
  // CSR buffers
  int* src32  = (int*)carve((size_t)E * 4);
  int* dst32  = (int*)carve((size_t)E * 4);
  int* deg    = (int*)carve((size_t)(M + 4) * 4);
  int* startp = (int*)carve((size_t)(M + 4) * 4);
  int* cursor = (int*)carve((size_t)(M + 4) * 4);
  int* csr    = (int*)carve((size_t)E * 4);
  int* bsum   = (int*)carve(1024);

  // d_out aliases: lo half hbuf/hbuf2 [M,256]b; hi half aggb [M,256]b
  unsigned short* hbuf  = (unsigned short*)d_out;
  unsigned short* hbuf2 = (unsigned short*)d_out;
  unsigned short* aggb  = (unsigned short*)((char*)d_out + (size_t)M * 512);
  float* xout = (float*)d_out;

  if (off > ws_size) {
    sentinel_fill<<<2048, 256, 0, stream>>>((float*)d_out, (long)out_size,
                                            (float)ws_size);
    return;
  }

  const int tb = 256;
  const int EB = (E + tb - 1) / tb;
  const int SB = (M + 255) / 256;

  prep_weights<<<dim3(1536, 10), 256, 0, stream>>>(
      Wc, Wq, Wk, Wv, Wo, W1, W2, Wct, Wqkvt, Wot, W1t, W2t,
      bq, bk, bv, bqkv, deg, M + 4, (const unsigned int*)ei, E, flag);
  // --- CSR build ---
  conv_hist<<<EB, tb, 0, stream>>>(ei, flag, src32, dst32, deg, E);
  block_sum<<<SB, 256, 0, stream>>>(deg, bsum, M);
  scan_final<<<SB, 256, 0, stream>>>(deg, bsum, startp, cursor, M, SB);
  csr_fill<<<EB, tb, 0, stream>>>(src32, dst32, cursor, csr, E);

  auto gsz = [](int Mz, int Nz) {
    int MT = (Mz + 127) / 128, NT = Nz / 128;
    return 8 * ((MT + 7) / 8) * NT;
  };
  // cs = bf16(silu(c))
  silu_cast<<<(M * 64 + tb - 1) / tb, tb, 0, stream>>>(c, cs, M * 64);
  // modv = cs @ Wc + bc   [M,1536]
  gemm_bf16<0, 0, 0><<<gsz(M, 1536), 512, 0, stream>>>(
      cs, Wct, bc, nullptr, nullptr, modv, M, 1536, 256, 256, 1536);
  // hbuf = modulate(ln(x), shift_msa, scale_msa)
  ln_modulate<0><<<(M + 3) / 4, 256, 0, stream>>>(x, modv, hbuf, M, 0, 1);
  // q part: bf16 into qkvp rows (stride 1024B = 512 u16)
  gemm_bf16<0, 0, 0><<<gsz(M, 256), 512, 0, stream>>>(
      hbuf, Wqkvt, bqkv, nullptr, nullptr, qkvp, M, 256, 256, 256, 512);
  // kv part: fp8 e5m2 into qkvp rows at byte offset 512 (stride 1024B)
  gemm_bf16<3, 0, 0><<<gsz(M, 512), 512, 0, stream>>>(
      hbuf, Wqkvt + 256 * 256, bqkv + 256, nullptr, nullptr, qkvp + 512,
      M, 512, 256, 256, 1024);
  // aggb(d_out hi) = per-dst softmax gather (fp8 kv)
  attn_gather<<<(M + 3) / 4, 256, 0, stream>>>(csr, startp, qkvp, aggb, M);
  // X1b(D) = bf16(x + gate_msa * (aggb @ Wo + bo))
  gemm_bf16<2, 0, 1><<<gsz(M, 256), 512, 0, stream>>>(
      aggb, Wot, bo, x, modv + 512, X1b, M, 256, 256, 256, 256);
  // hbuf2(d_out lo) = modulate(ln(X1b), shift_mlp, scale_mlp)
  ln_modulate<1><<<(M + 3) / 4, 256, 0, stream>>>(X1b, modv, hbuf2, M, 3, 4);
  // h2(modv cols 0..1024, ld 1536) = gelu(hbuf2 @ W1 + b1)   [M,1024]
  gemm_bf16<1, 0, 0><<<gsz(M, 1024), 512, 0, stream>>>(
      hbuf2, W1t, b1, nullptr, nullptr, modv, M, 1024, 256, 256, 1536);
  // out(d_out) = X1b + gate_mlp * (h2 @ W2 + b2)   [f32]
  gemm_bf16<2, 1, 0><<<gsz(M, 256), 512, 0, stream>>>(
      modv, W2t, b2, X1b, modv + 1280, xout, M, 256, 1024, 1536, 256);
}

// Round 13
// 482.189 us; speedup vs baseline: 1.3138x; 1.0041x over previous
//
#include <hip/hip_runtime.h>

// ---------------------------------------------------------------------------
// DiT graph-attention block, MI355X (gfx950).
// R13: 2-phase double-buffered GEMM K-loop (guide T3 minimum recipe): issue
//      next tile's global_load_lds BEFORE computing current tile; the
//      compiler's pre-barrier vmcnt drain then overlaps load latency with
//      MFMA (R12 counters: MfmaUtil 13%, VALU 10%, HBM 22% => barrier-drain
//      latency-bound).  LDS 32->64 KB (2 buffers).
// ---------------------------------------------------------------------------

typedef __attribute__((ext_vector_type(8))) short bf16x8;
typedef __attribute__((ext_vector_type(2))) _Float16 h2_t;
typedef __attribute__((ext_vector_type(4))) float f32x4;

__device__ __forceinline__ float bf2f(unsigned short u) {
  union { float f; unsigned int i; } x; x.i = ((unsigned int)u) << 16; return x.f;
}
__device__ __forceinline__ unsigned short f2bf(float f) {
  union { float f; unsigned int i; } x; x.f = f;
  unsigned int r = x.i + 0x7fffu + ((x.i >> 16) & 1u);  // RNE
  return (unsigned short)(r >> 16);
}

__device__ __forceinline__ void gload_lds16(const void* g, void* l) {
  __builtin_amdgcn_global_load_lds(
      (const __attribute__((address_space(1))) void*)g,
      (__attribute__((address_space(3))) void*)l, 16, 0, 0);
}

// ---------------------------------------------------------------------------
// Unified bf16 GEMM:  out = epilogue(A[M,K](lda) @ Bt[N,K]^T + bias)
// 8 waves/block, wave tile 64x32, 2-phase double-buffered staging.
// EPI 0: out bf16 = acc+bias                (full-tile LDS repack, ldo u16)
// EPI 1: out bf16 = gelu(acc+bias)          (repack)
// EPI 2: out = xin + gate*(acc+bias)        (XINBF/OUTBF select f32/bf16)
// EPI 3: out fp8 e5m2 = acc+bias            (byte repack; ldo bytes)
// ---------------------------------------------------------------------------
template <int EPI, int XINBF, int OUTBF>
__global__ __launch_bounds__(512)
void gemm_bf16(const unsigned short* __restrict__ A,
               const unsigned short* __restrict__ Bt,
               const float* __restrict__ bias,
               const void* __restrict__ xin,
               const unsigned short* __restrict__ gate,
               void* __restrict__ out,
               int M, int N, int K, int lda, int ldo) {
  const int NT = N >> 7;
  const int MT = (M + 127) >> 7;
  const int pid = blockIdx.x;
  const int j = pid >> 3;
  const int rb = (pid & 7) + 8 * (j / NT);
  const int cb = j - (j / NT) * NT;
  if (rb >= MT) return;  // uniform across block

  __shared__ char smem[65536];  // 2 buffers x (At 16KB | Bs 16KB)
  const int tid = threadIdx.x;
  const int wid = tid >> 6;
  const int lane = tid & 63;
  const int l15 = lane & 15, l4 = lane >> 4;
  const int row0 = rb * 128, col0 = cb * 128;
  const int wr = (wid >> 2) * 64;   // 0,64
  const int wc = (wid & 3) * 32;    // 0,32,64,96

  f32x4 acc[4][2];
  const f32x4 zf = {0.f, 0.f, 0.f, 0.f};
  for (int m = 0; m < 4; ++m)
    for (int n = 0; n < 2; ++n) acc[m][n] = zf;

  // stage one 128x64 A-tile + B-tile pair into buffer buf
  auto STAGE = [&](int buf, int kt) {
    char* At = smem + buf * 32768;
    char* Bs = At + 16384;
#pragma unroll
    for (int s = 0; s < 2; ++s) {
      const int p = s * 8192 + tid * 16;           // byte in 16KB tile
      const int r = p >> 7;                        // tile row 0..127
      const int scb = (p & 127) ^ ((r & 7) << 4);  // swizzled source col byte
      int gr = row0 + r; gr = gr < M ? gr : M - 1;
      gload_lds16((const char*)A + ((size_t)gr * lda + kt) * 2 + scb,
                  At + s * 8192 + wid * 1024);
      const int gc = col0 + r;                     // N multiple of 128
      gload_lds16((const char*)Bt + ((size_t)gc * K + kt) * 2 + scb,
                  Bs + s * 8192 + wid * 1024);
    }
  };

  STAGE(0, 0);
  __syncthreads();  // compiler drains vmcnt before barrier: buf0 ready
  int cur = 0;
  for (int kt = 0; kt < K; kt += 64) {
    if (kt + 64 < K) STAGE(cur ^ 1, kt + 64);  // issue next tile EARLY
    const char* At = smem + cur * 32768;
    const char* Bs = At + 16384;
#pragma unroll
    for (int kk = 0; kk < 64; kk += 32) {
      bf16x8 af[4], bfr[2];
#pragma unroll
      for (int m = 0; m < 4; ++m) {
        const int r = wr + m * 16 + l15;
        const int cb2 = ((kk + l4 * 8) * 2) ^ ((r & 7) << 4);
        af[m] = *(const bf16x8*)(At + r * 128 + cb2);
      }
#pragma unroll
      for (int n = 0; n < 2; ++n) {
        const int r = wc + n * 16 + l15;
        const int cb2 = ((kk + l4 * 8) * 2) ^ ((r & 7) << 4);
        bfr[n] = *(const bf16x8*)(Bs + r * 128 + cb2);
      }
#pragma unroll
      for (int m = 0; m < 4; ++m)
#pragma unroll
        for (int n = 0; n < 2; ++n)
          acc[m][n] = __builtin_amdgcn_mfma_f32_16x16x32_bf16(af[m], bfr[n],
                                                              acc[m][n], 0, 0, 0);
    }
    __syncthreads();  // drain: next buffer staged + this buffer's reads done
    cur ^= 1;
  }

  // C/D layout: col=lane&15, row=(lane>>4)*4+reg   [guide §3, m89/m91]
  if (EPI == 2) {
#pragma unroll
    for (int m = 0; m < 4; ++m)
#pragma unroll
      for (int jj = 0; jj < 4; ++jj) {
        const int gr = row0 + wr + m * 16 + l4 * 4 + jj;
        if (gr >= M) continue;
#pragma unroll
        for (int n = 0; n < 2; ++n) {
          const int gc = col0 + wc + n * 16 + l15;
          const float v = acc[m][n][jj] + bias[gc];
          const float gt = bf2f(gate[(size_t)gr * 1536 + gc]);
          const float xv =
              XINBF ? bf2f(((const unsigned short*)xin)[(size_t)gr * ldo + gc])
                    : ((const float*)xin)[(size_t)gr * ldo + gc];
          const float rv = xv + gt * v;
          if (OUTBF)
            ((unsigned short*)out)[(size_t)gr * ldo + gc] = f2bf(rv);
          else
            ((float*)out)[(size_t)gr * ldo + gc] = rv;
        }
      }
  } else if (EPI == 3) {
    // fp8 e5m2: byte repack through smem [128][128]B, 16B stores
#pragma unroll
    for (int m = 0; m < 4; ++m)
#pragma unroll
      for (int jj = 0; jj < 4; ++jj) {
        const int row_l = wr + m * 16 + l4 * 4 + jj;  // 0..127
        const int swz = (row_l & 12) << 2;
#pragma unroll
        for (int n = 0; n < 2; ++n) {
          const int col = wc + n * 16 + l15;          // 0..127
          const float v = acc[m][n][jj] + bias[col0 + col];
          const unsigned short h =
              __builtin_bit_cast(unsigned short, (_Float16)v);
          const unsigned char b8 =
              (unsigned char)((h + 0x7fu + ((h >> 8) & 1u)) >> 8);
          ((unsigned char*)smem)[row_l * 128 + (col ^ swz)] = b8;
        }
      }
    __syncthreads();
#pragma unroll
    for (int pp = 0; pp < 2; ++pp) {
      const int u = pp * 512 + tid;       // 1024 16B units
      const int row_l = u >> 3;
      const int cb16 = (u & 7) * 16;
      const int gr = row0 + row_l;
      if (gr < M) {
        const bf16x8 vv = *(const bf16x8*)((const unsigned char*)smem +
                                           row_l * 128 +
                                           (cb16 ^ ((row_l & 12) << 2)));
        *(bf16x8*)((unsigned char*)out + (size_t)gr * ldo + col0 + cb16) = vv;
      }
    }
  } else {
    // bf16 out: full-tile repack through smem [128][128] u16, 16B stores
    unsigned short* R = (unsigned short*)smem;
#pragma unroll
    for (int m = 0; m < 4; ++m)
#pragma unroll
      for (int jj = 0; jj < 4; ++jj) {
        const int row_l = wr + m * 16 + l4 * 4 + jj;  // 0..127
        const int swz = (row_l & 12) << 2;            // u16 XOR 0/16/32/48
#pragma unroll
        for (int n = 0; n < 2; ++n) {
          const int col = wc + n * 16 + l15;
          float v = acc[m][n][jj] + bias[col0 + col];
          if (EPI == 1) {
            // gelu_tanh(v) == v * sigmoid(2u), u = 0.79788(v+0.044715v^3)
            const float u2 = 1.5957691216f * (v + 0.044715f * v * v * v);
            v = v / (1.f + __expf(-u2));
          }
          R[row_l * 128 + (col ^ swz)] = f2bf(v);
        }
      }
    __syncthreads();
#pragma unroll
    for (int pp = 0; pp < 4; ++pp) {
      const int u = pp * 512 + tid;       // 2048 16B units
      const int row_l = u >> 4;
      const int col8 = (u & 15) * 8;
      const int gr = row0 + row_l;
      if (gr < M) {
        const bf16x8 vv =
            *(const bf16x8*)&R[row_l * 128 + (col8 ^ ((row_l & 12) << 2))];
        *(bf16x8*)((unsigned short*)out + (size_t)gr * ldo + col0 + col8) = vv;
      }
    }
  }
}

// ---------------------------------------------------------------------------
// helpers
// ---------------------------------------------------------------------------
__global__ void sentinel_fill(float* o, long n, float v) {
  long i = (long)blockIdx.x * blockDim.x + threadIdx.x;
  const long st = (long)gridDim.x * blockDim.x;
  for (; i < n; i += st) o[i] = (i == 0) ? v : 0.f;
}

// fused prep: weight transposes (kv-interleave for Wk/Wv), bias concat,
// deg zeroing, int64-detect.  grid = dim3(1536, 10).
__global__ void prep_weights(const float* __restrict__ Wc, const float* __restrict__ Wq,
                             const float* __restrict__ Wk, const float* __restrict__ Wv,
                             const float* __restrict__ Wo, const float* __restrict__ W1,
                             const float* __restrict__ W2,
                             unsigned short* __restrict__ Wct,
                             unsigned short* __restrict__ Wqkvt,
                             unsigned short* __restrict__ Wot,
                             unsigned short* __restrict__ W1t,
                             unsigned short* __restrict__ W2t,
                             const float* __restrict__ bq, const float* __restrict__ bk,
                             const float* __restrict__ bv, float* __restrict__ bqkv,
                             int* __restrict__ deg, int Mdeg,
                             const unsigned int* __restrict__ ei_u32, int E,
                             int* __restrict__ flag) {
  const int job = blockIdx.y;
  const int i = blockIdx.x * 256 + threadIdx.x;
  if (job == 7) {  // bias concat (kv-interleaved)
    if (i < 256) bqkv[i] = bq[i];
    else if (i < 512) { int d = i - 256; bqkv[256 + ((d >> 2) << 3) + (d & 3)] = bk[d]; }
    else if (i < 768) { int d = i - 512; bqkv[256 + ((d >> 2) << 3) + 4 + (d & 3)] = bv[d]; }
    return;
  }
  if (job == 8) {  // zero deg
    if (i < Mdeg) deg[i] = 0;
    return;
  }
  if (job == 9) {  // int64 detect (block 0 only)
    if (blockIdx.x != 0) return;
    __shared__ int bad;
    if (threadIdx.x == 0) bad = 0;
    __syncthreads();
    const int n = E < 256 ? E : 256;
    if ((int)threadIdx.x < n && ei_u32[2 * threadIdx.x + 1] != 0u) atomicAdd(&bad, 1);
    __syncthreads();
    if (threadIdx.x == 0) *flag = (bad == 0);
    return;
  }
  const float* W; unsigned short* Wt; int N, kc, mode = 0;
  switch (job) {
    case 0: W = Wc; Wt = Wct; N = 1536; kc = 256; break;
    case 1: W = Wq; Wt = Wqkvt; N = 256; kc = 256; break;
    case 2: W = Wk; Wt = Wqkvt + 256 * 256; N = 256; kc = 256; mode = 1; break;
    case 3: W = Wv; Wt = Wqkvt + 256 * 256; N = 256; kc = 256; mode = 2; break;
    case 4: W = Wo; Wt = Wot; N = 256; kc = 256; break;
    case 5: W = W1; Wt = W1t; N = 1024; kc = 256; break;
    default: W = W2; Wt = W2t; N = 256; kc = 1024; break;
  }
  if (i >= N * kc) return;
  const int kk = i / N, n = i - kk * N;
  int r = n;
  if (mode == 1) r = ((n >> 2) << 3) + (n & 3);
  else if (mode == 2) r = ((n >> 2) << 3) + 4 + (n & 3);
  Wt[(size_t)r * kc + kk] = f2bf(W[(size_t)kk * N + n]);
}

__global__ void silu_cast(const float* __restrict__ c, unsigned short* __restrict__ o,
                          int total4) {
  int i = blockIdx.x * blockDim.x + threadIdx.x;
  if (i >= total4) return;
  float4 v = *(const float4*)&c[(size_t)i * 4];
  ushort4 r;
  r.x = f2bf(v.x / (1.f + __expf(-v.x)));
  r.y = f2bf(v.y / (1.f + __expf(-v.y)));
  r.z = f2bf(v.z / (1.f + __expf(-v.z)));
  r.w = f2bf(v.w / (1.f + __expf(-v.w)));
  *(ushort4*)&o[(size_t)i * 4] = r;
}

// one wave per row: h = ((x-mean)*rstd)*(1+scale)+shift -> bf16
// INBF: input rows are bf16 (X1) instead of f32
template <int INBF>
__global__ void ln_modulate(const void* __restrict__ xin,
                            const unsigned short* __restrict__ modv,
                            unsigned short* __restrict__ hout,
                            int M, int cshift, int cscale) {
  const int wid = threadIdx.x >> 6, lane = threadIdx.x & 63;
  const int row = blockIdx.x * 4 + wid;
  if (row >= M) return;
  float4 x4;
  if (INBF) {
    const ushort4 u4 =
        *(const ushort4*)((const unsigned short*)xin + (size_t)row * 256 + lane * 4);
    x4.x = bf2f(u4.x); x4.y = bf2f(u4.y); x4.z = bf2f(u4.z); x4.w = bf2f(u4.w);
  } else {
    x4 = *(const float4*)((const float*)xin + (size_t)row * 256 + lane * 4);
  }
  float s = x4.x + x4.y + x4.z + x4.w;
  float ss = x4.x * x4.x + x4.y * x4.y + x4.z * x4.z + x4.w * x4.w;
#pragma unroll
  for (int m = 1; m < 64; m <<= 1) {
    s += __shfl_xor(s, m, 64);
    ss += __shfl_xor(ss, m, 64);
  }
  const float mean = s * (1.f / 256.f);
  const float var = ss * (1.f / 256.f) - mean * mean;
  const float rstd = rsqrtf(var + 1e-6f);
  const ushort4 sh4 = *(const ushort4*)&modv[(size_t)row * 1536 + cshift * 256 + lane * 4];
  const ushort4 sc4 = *(const ushort4*)&modv[(size_t)row * 1536 + cscale * 256 + lane * 4];
  ushort4 o;
  o.x = f2bf((x4.x - mean) * rstd * (1.f + bf2f(sc4.x)) + bf2f(sh4.x));
  o.y = f2bf((x4.y - mean) * rstd * (1.f + bf2f(sc4.y)) + bf2f(sh4.y));
  o.z = f2bf((x4.z - mean) * rstd * (1.f + bf2f(sc4.z)) + bf2f(sh4.z));
  o.w = f2bf((x4.w - mean) * rstd * (1.f + bf2f(sc4.w)) + bf2f(sh4.w));
  *(ushort4*)&hout[(size_t)row * 256 + lane * 4] = o;
}

// unpack edge_index -> src32/dst32 and histogram dst degree (fused)
__global__ void conv_hist(const void* __restrict__ ei, const int* __restrict__ flag,
                          int* __restrict__ src32, int* __restrict__ dst32,
                          int* __restrict__ deg, int E) {
  int e = blockIdx.x * blockDim.x + threadIdx.x;
  if (e >= E) return;
  int s, d;
  if (*flag) {
    const long long* p = (const long long*)ei;
    s = (int)p[e]; d = (int)p[E + e];
  } else {
    const int* p = (const int*)ei;
    s = p[e]; d = p[E + e];
  }
  src32[e] = s; dst32[e] = d;
  atomicAdd(&deg[d], 1);
}

// 2-phase scan: per-block sums, then scan_final self-reduces the block sums
__global__ __launch_bounds__(256)
void block_sum(const int* __restrict__ deg, int* __restrict__ bsum, int M) {
  int i = blockIdx.x * 256 + threadIdx.x;
  int v = (i < M) ? deg[i] : 0;
#pragma unroll
  for (int d = 1; d < 64; d <<= 1) v += __shfl_xor(v, d, 64);
  __shared__ int ws[4];
  const int lane = threadIdx.x & 63, w = threadIdx.x >> 6;
  if (lane == 0) ws[w] = v;
  __syncthreads();
  if (threadIdx.x == 0) bsum[blockIdx.x] = ws[0] + ws[1] + ws[2] + ws[3];
}

__global__ __launch_bounds__(256)
void scan_final(const int* __restrict__ deg, const int* __restrict__ bsum,
                int* __restrict__ start, int* __restrict__ cursor, int M, int NB) {
  const int b = blockIdx.x, t = threadIdx.x, i = b * 256 + t;
  const int lane = t & 63, w = t >> 6;
  __shared__ int ws[4];
  __shared__ int pref;
  const int v = (i < M) ? deg[i] : 0;
  int s = v;
#pragma unroll
  for (int d = 1; d < 64; d <<= 1) {
    int u = __shfl_up(s, d, 64);
    if (lane >= d) s += u;
  }
  if (lane == 63) ws[w] = s;
  if (t < 64) {  // wave 0 reduces bsum[0..b-1]
    int acc = 0;
    for (int base = 0; base < b; base += 64) {
      const int idx = base + lane;
      acc += (idx < b) ? bsum[idx] : 0;
    }
#pragma unroll
    for (int d = 1; d < 64; d <<= 1) acc += __shfl_xor(acc, d, 64);
    if (lane == 0) pref = acc;
  }
  __syncthreads();
  int add = pref;
  for (int k = 0; k < w; ++k) add += ws[k];
  const int excl = s - v + add;
  if (i < M) { start[i] = excl; cursor[i] = excl; }
  if (i == M - 1) start[M] = excl + v;
}

__global__ void csr_fill(const int* __restrict__ src32, const int* __restrict__ dst32,
                         int* __restrict__ cursor, int* __restrict__ csr, int E) {
  int e = blockIdx.x * blockDim.x + threadIdx.x;
  if (e >= E) return;
  int pos = atomicAdd(&cursor[dst32[e]], 1);
  csr[pos] = src32[e];
}

// one wave per dst node; 2-deep batch-4 pipeline.  Row layout (1024 B):
// [q bf16 512B][kv fp8 e5m2 512B, lane l's 8B = k[4l..4l+3]|v[4l..4l+3]].
__global__ __launch_bounds__(256)
void attn_gather(const int* __restrict__ csr, const int* __restrict__ start,
                 const unsigned char* __restrict__ qkvp,
                 unsigned short* __restrict__ aggb, int M) {
  const int wid = threadIdx.x >> 6, lane = threadIdx.x & 63;
  const int row = blockIdx.x * 4 + wid;
  if (row >= M) return;
  const ushort4 q4 = *(const ushort4*)(qkvp + (size_t)row * 1024 + lane * 8);
  const float SC = 0.17677669529663687f;  // 32^-0.5, folded into q
  const float qf0 = bf2f(q4.x) * SC, qf1 = bf2f(q4.y) * SC;
  const float qf2 = bf2f(q4.z) * SC, qf3 = bf2f(q4.w) * SC;
  const int b0 = start[row], e0 = start[row + 1];
  float den = 0.f, a0 = 0.f, a1 = 0.f, a2 = 0.f, a3 = 0.f;

  auto LDKV = [&](int src) {
    return *(const uint2*)(qkvp + (size_t)src * 1024 + 512 + lane * 8);
  };
#define PROC(kv2)                                                              \
  {                                                                            \
    const unsigned kd = kv2.x, vd = kv2.y;                                     \
    const unsigned klo = ((kd << 8) & 0x0000ff00u) | ((kd << 16) & 0xff000000u);\
    const unsigned khi = ((kd >> 8) & 0x0000ff00u) | (kd & 0xff000000u);       \
    const h2_t k01 = __builtin_bit_cast(h2_t, klo);                            \
    const h2_t k23 = __builtin_bit_cast(h2_t, khi);                            \
    float s = qf0 * (float)k01[0] + qf1 * (float)k01[1] +                      \
              qf2 * (float)k23[0] + qf3 * (float)k23[1];                       \
    s += __shfl_xor(s, 1, 64);                                                 \
    s += __shfl_xor(s, 2, 64);                                                 \
    s += __shfl_xor(s, 4, 64);                                                 \
    const float ex = __expf(s);                                                \
    const unsigned vlo = ((vd << 8) & 0x0000ff00u) | ((vd << 16) & 0xff000000u);\
    const unsigned vhi = ((vd >> 8) & 0x0000ff00u) | (vd & 0xff000000u);       \
    const h2_t v01 = __builtin_bit_cast(h2_t, vlo);                            \
    const h2_t v23 = __builtin_bit_cast(h2_t, vhi);                            \
    den += ex;                                                                 \
    a0 += ex * (float)v01[0]; a1 += ex * (float)v01[1];                        \
    a2 += ex * (float)v23[0]; a3 += ex * (float)v23[1];                        \
  }

  int i = b0;
  if (i + 4 <= e0) {
    uint2 A0 = LDKV(csr[i]), A1 = LDKV(csr[i + 1]);
    uint2 A2 = LDKV(csr[i + 2]), A3 = LDKV(csr[i + 3]);
    while (i + 8 <= e0) {
      const uint2 B0 = LDKV(csr[i + 4]), B1 = LDKV(csr[i + 5]);
      const uint2 B2 = LDKV(csr[i + 6]), B3 = LDKV(csr[i + 7]);
      PROC(A0); PROC(A1); PROC(A2); PROC(A3);
      A0 = B0; A1 = B1; A2 = B2; A3 = B3;
      i += 4;
    }
    PROC(A0); PROC(A1); PROC(A2); PROC(A3);
    i += 4;
  }
  for (; i < e0; ++i) {
    const uint2 kv2 = LDKV(csr[i]);
    PROC(kv2);
  }
#undef PROC

  const float inv = den > 0.f ? 1.f / den : 0.f;
  ushort4 r;
  r.x = f2bf(a0 * inv); r.y = f2bf(a1 * inv);
  r.z = f2bf(a2 * inv); r.w = f2bf(a3 * inv);
  *(ushort4*)&aggb[(size_t)row * 256 + lane * 4] = r;
}

// ---------------------------------------------------------------------------
extern "C" void kernel_launch(void* const* d_in, const int* in_sizes, int n_in,
                              void* d_out, int out_size, void* d_ws, size_t ws_size,
                              hipStream_t stream) {
  (void)n_in;
  const float* x  = (const float*)d_in[0];
  const float* c  = (const float*)d_in[1];
  const void*  ei = d_in[2];
  const float* Wq = (const float*)d_in[3];
  const float* bq = (const float*)d_in[4];
  const float* Wk = (const float*)d_in[5];
  const float* bk = (const float*)d_in[6];
  const float* Wv = (const float*)d_in[7];
  const float* bv = (const float*)d_in[8];
  const float* Wo = (const float*)d_in[9];
  const float* bo = (const float*)d_in[10];
  const float* W1 = (const float*)d_in[11];
  const float* b1 = (const float*)d_in[12];
  const float* W2 = (const float*)d_in[13];
  const float* b2 = (const float*)d_in[14];
  const float* Wc = (const float*)d_in[15];
  const float* bc = (const float*)d_in[16];

  const int M = in_sizes[0] / 256;   // 50000
  const int E = in_sizes[2] / 2;     // 800000

  char* ws = (char*)d_ws;
  size_t off = 0;
  auto carve = [&](size_t bytes) {
    char* p = ws + off;
    off = (off + bytes + 255) & ~(size_t)255;
    return p;
  };
  // persistent: modv [M,1536]b; cols 0..1024 reused as h2 (ldo=1536) after ln2
  unsigned short* modv = (unsigned short*)carve((size_t)M * 1536 * 2);  // 153.6MB
  // region D (M*1024 bytes): cs -> qkvp [M,1024B] -> X1b [M,256]bf16
  char* D = carve((size_t)M * 1024);
  unsigned short* cs = (unsigned short*)D;
  unsigned char* qkvp = (unsigned char*)D;
  unsigned short* X1b = (unsigned short*)D;
  unsigned short* Wct   = (unsigned short*)carve((size_t)1536 * 256 * 2);
  unsigned short* Wqkvt = (unsigned short*)carve((size_t)768 * 256 * 2);
  unsigned short* Wot   = (unsigned short*)carve((size_t)256 * 256 * 2);
  unsigned short* W1t   = (unsigned short*)carve((size_t)1024 * 256 * 2);
  unsigned short* W2t   = (unsigned short*)carve((size_t)256 * 1024 * 2);
  float* bqkv = (float*)carve(768 * 4);
  int* flag = (int*)carve(256);
  // CSR buffers
  int* src32  = (int*)carve((size_t)E * 4);
  int* dst32  = (int*)carve((size_t)E * 4);
  int* deg    = (int*)carve((size_t)(M + 4) * 4);
  int* startp = (int*)carve((size_t)(M + 4) * 4);
  int* cursor = (int*)carve((size_t)(M + 4) * 4);
  int* csr    = (int*)carve((size_t)E * 4);
  int* bsum   = (int*)carve(1024);

  // d_out aliases: lo half hbuf/hbuf2 [M,256]b; hi half aggb [M,256]b
  unsigned short* hbuf  = (unsigned short*)d_out;
  unsigned short* hbuf2 = (unsigned short*)d_out;
  unsigned short* aggb  = (unsigned short*)((char*)d_out + (size_t)M * 512);
  float* xout = (float*)d_out;

  if (off > ws_size) {
    sentinel_fill<<<2048, 256, 0, stream>>>((float*)d_out, (long)out_size,
                                            (float)ws_size);
    return;
  }

  const int tb = 256;
  const int EB = (E + tb - 1) / tb;
  const int SB = (M + 255) / 256;

  prep_weights<<<dim3(1536, 10), 256, 0, stream>>>(
      Wc, Wq, Wk, Wv, Wo, W1, W2, Wct, Wqkvt, Wot, W1t, W2t,
      bq, bk, bv, bqkv, deg, M + 4, (const unsigned int*)ei, E, flag);
  // --- CSR build ---
  conv_hist<<<EB, tb, 0, stream>>>(ei, flag, src32, dst32, deg, E);
  block_sum<<<SB, 256, 0, stream>>>(deg, bsum, M);
  scan_final<<<SB, 256, 0, stream>>>(deg, bsum, startp, cursor, M, SB);
  csr_fill<<<EB, tb, 0, stream>>>(src32, dst32, cursor, csr, E);

  auto gsz = [](int Mz, int Nz) {
    int MT = (Mz + 127) / 128, NT = Nz / 128;
    return 8 * ((MT + 7) / 8) * NT;
  };
  // cs = bf16(silu(c))
  silu_cast<<<(M * 64 + tb - 1) / tb, tb, 0, stream>>>(c, cs, M * 64);
  // modv = cs @ Wc + bc   [M,1536]
  gemm_bf16<0, 0, 0><<<gsz(M, 1536), 512, 0, stream>>>(
      cs, Wct, bc, nullptr, nullptr, modv, M, 1536, 256, 256, 1536);
  // hbuf = modulate(ln(x), shift_msa, scale_msa)
  ln_modulate<0><<<(M + 3) / 4, 256, 0, stream>>>(x, modv, hbuf, M, 0, 1);
  // q part: bf16 into qkvp rows (stride 1024B = 512 u16)
  gemm_bf16<0, 0, 0><<<gsz(M, 256), 512, 0, stream>>>(
      hbuf, Wqkvt, bqkv, nullptr, nullptr, qkvp, M, 256, 256, 256, 512);
  // kv part: fp8 e5m2 into qkvp rows at byte offset 512 (stride 1024B)
  gemm_bf16<3, 0, 0><<<gsz(M, 512), 512, 0, stream>>>(
      hbuf, Wqkvt + 256 * 256, bqkv + 256, nullptr, nullptr, qkvp + 512,
      M, 512, 256, 256, 1024);
  // aggb(d_out hi) = per-dst softmax gather (fp8 kv)
  attn_gather<<<(M + 3) / 4, 256, 0, stream>>>(csr, startp, qkvp, aggb, M);
  // X1b(D) = bf16(x + gate_msa * (aggb @ Wo + bo))
  gemm_bf16<2, 0, 1><<<gsz(M, 256), 512, 0, stream>>>(
      aggb, Wot, bo, x, modv + 512, X1b, M, 256, 256, 256, 256);
  // hbuf2(d_out lo) = modulate(ln(X1b), shift_mlp, scale_mlp)
  ln_modulate<1><<<(M + 3) / 4, 256, 0, stream>>>(X1b, modv, hbuf2, M, 3, 4);
  // h2(modv cols 0..1024, ld 1536) = gelu(hbuf2 @ W1 + b1)   [M,1024]
  gemm_bf16<1, 0, 0><<<gsz(M, 1024), 512, 0, stream>>>(
      hbuf2, W1t, b1, nullptr, nullptr, modv, M, 1024, 256, 256, 1536);
  // out(d_out) = X1b + gate_mlp * (h2 @ W2 + b2)   [f32]
  gemm_bf16<2, 1, 0><<<gsz(M, 256), 512, 0, stream>>>(
      modv, W2t, b2, X1b, modv + 1280, xout, M, 256, 1024, 1536, 256);
}

// Round 14
// 471.104 us; speedup vs baseline: 1.3447x; 1.0235x over previous
//
#include <hip/hip_runtime.h>

// ---------------------------------------------------------------------------
// DiT graph-attention block, MI355X (gfx950).
// R14: attn fp8 decode via v_perm_b32 (1 op per f16x2 word vs 3) + packed
//      v_pk_fma_f16 QK dot (R13: VALUBusy 83% => decode-bound);
//      q+kv GEMMs merged into one N=768 launch (EPI4 dual epilogue).
// ---------------------------------------------------------------------------

typedef __attribute__((ext_vector_type(8))) short bf16x8;
typedef __attribute__((ext_vector_type(2))) _Float16 h2_t;
typedef __attribute__((ext_vector_type(4))) float f32x4;

__device__ __forceinline__ float bf2f(unsigned short u) {
  union { float f; unsigned int i; } x; x.i = ((unsigned int)u) << 16; return x.f;
}
__device__ __forceinline__ unsigned short f2bf(float f) {
  union { float f; unsigned int i; } x; x.f = f;
  unsigned int r = x.i + 0x7fffu + ((x.i >> 16) & 1u);  // RNE
  return (unsigned short)(r >> 16);
}

__device__ __forceinline__ void gload_lds16(const void* g, void* l) {
  __builtin_amdgcn_global_load_lds(
      (const __attribute__((address_space(1))) void*)g,
      (__attribute__((address_space(3))) void*)l, 16, 0, 0);
}

// ---------------------------------------------------------------------------
// Unified bf16 GEMM:  out = epilogue(A[M,K](lda) @ Bt[N,K]^T + bias)
// 8 waves/block, wave tile 64x32, 2-phase double-buffered staging.
// EPI 0: out bf16 = acc+bias                (full-tile LDS repack, ldo u16)
// EPI 1: out bf16 = gelu(acc+bias)          (repack)
// EPI 2: out = xin + gate*(acc+bias)        (XINBF/OUTBF select f32/bf16)
// EPI 3: out fp8 e5m2 = acc+bias            (byte repack; ldo bytes)
// EPI 4: merged qkv: cb<2 -> bf16 q (row 1024B), cb>=2 -> fp8 kv (+512B)
// ---------------------------------------------------------------------------
template <int EPI, int XINBF, int OUTBF>
__global__ __launch_bounds__(512)
void gemm_bf16(const unsigned short* __restrict__ A,
               const unsigned short* __restrict__ Bt,
               const float* __restrict__ bias,
               const void* __restrict__ xin,
               const unsigned short* __restrict__ gate,
               void* __restrict__ out,
               int M, int N, int K, int lda, int ldo) {
  const int NT = N >> 7;
  const int MT = (M + 127) >> 7;
  const int pid = blockIdx.x;
  const int j = pid >> 3;
  const int rb = (pid & 7) + 8 * (j / NT);
  const int cb = j - (j / NT) * NT;
  if (rb >= MT) return;  // uniform across block

  __shared__ char smem[65536];  // 2 buffers x (At 16KB | Bs 16KB)
  const int tid = threadIdx.x;
  const int wid = tid >> 6;
  const int lane = tid & 63;
  const int l15 = lane & 15, l4 = lane >> 4;
  const int row0 = rb * 128, col0 = cb * 128;
  const int wr = (wid >> 2) * 64;   // 0,64
  const int wc = (wid & 3) * 32;    // 0,32,64,96

  f32x4 acc[4][2];
  const f32x4 zf = {0.f, 0.f, 0.f, 0.f};
  for (int m = 0; m < 4; ++m)
    for (int n = 0; n < 2; ++n) acc[m][n] = zf;

  auto STAGE = [&](int buf, int kt) {
    char* At = smem + buf * 32768;
    char* Bs = At + 16384;
#pragma unroll
    for (int s = 0; s < 2; ++s) {
      const int p = s * 8192 + tid * 16;           // byte in 16KB tile
      const int r = p >> 7;                        // tile row 0..127
      const int scb = (p & 127) ^ ((r & 7) << 4);  // swizzled source col byte
      int gr = row0 + r; gr = gr < M ? gr : M - 1;
      gload_lds16((const char*)A + ((size_t)gr * lda + kt) * 2 + scb,
                  At + s * 8192 + wid * 1024);
      const int gc = col0 + r;                     // N multiple of 128
      gload_lds16((const char*)Bt + ((size_t)gc * K + kt) * 2 + scb,
                  Bs + s * 8192 + wid * 1024);
    }
  };

  STAGE(0, 0);
  __syncthreads();
  int cur = 0;
  for (int kt = 0; kt < K; kt += 64) {
    if (kt + 64 < K) STAGE(cur ^ 1, kt + 64);  // issue next tile EARLY
    const char* At = smem + cur * 32768;
    const char* Bs = At + 16384;
#pragma unroll
    for (int kk = 0; kk < 64; kk += 32) {
      bf16x8 af[4], bfr[2];
#pragma unroll
      for (int m = 0; m < 4; ++m) {
        const int r = wr + m * 16 + l15;
        const int cb2 = ((kk + l4 * 8) * 2) ^ ((r & 7) << 4);
        af[m] = *(const bf16x8*)(At + r * 128 + cb2);
      }
#pragma unroll
      for (int n = 0; n < 2; ++n) {
        const int r = wc + n * 16 + l15;
        const int cb2 = ((kk + l4 * 8) * 2) ^ ((r & 7) << 4);
        bfr[n] = *(const bf16x8*)(Bs + r * 128 + cb2);
      }
#pragma unroll
      for (int m = 0; m < 4; ++m)
#pragma unroll
        for (int n = 0; n < 2; ++n)
          acc[m][n] = __builtin_amdgcn_mfma_f32_16x16x32_bf16(af[m], bfr[n],
                                                              acc[m][n], 0, 0, 0);
    }
    __syncthreads();
    cur ^= 1;
  }

  const bool fp8path = (EPI == 3) || (EPI == 4 && cb >= 2);
  // C/D layout: col=lane&15, row=(lane>>4)*4+reg   [guide §3, m89/m91]
  if (EPI == 2) {
#pragma unroll
    for (int m = 0; m < 4; ++m)
#pragma unroll
      for (int jj = 0; jj < 4; ++jj) {
        const int gr = row0 + wr + m * 16 + l4 * 4 + jj;
        if (gr >= M) continue;
#pragma unroll
        for (int n = 0; n < 2; ++n) {
          const int gc = col0 + wc + n * 16 + l15;
          const float v = acc[m][n][jj] + bias[gc];
          const float gt = bf2f(gate[(size_t)gr * 1536 + gc]);
          const float xv =
              XINBF ? bf2f(((const unsigned short*)xin)[(size_t)gr * ldo + gc])
                    : ((const float*)xin)[(size_t)gr * ldo + gc];
          const float rv = xv + gt * v;
          if (OUTBF)
            ((unsigned short*)out)[(size_t)gr * ldo + gc] = f2bf(rv);
          else
            ((float*)out)[(size_t)gr * ldo + gc] = rv;
        }
      }
  } else if (fp8path) {
    // fp8 e5m2: byte repack through smem [128][128]B, 16B stores
#pragma unroll
    for (int m = 0; m < 4; ++m)
#pragma unroll
      for (int jj = 0; jj < 4; ++jj) {
        const int row_l = wr + m * 16 + l4 * 4 + jj;  // 0..127
        const int swz = (row_l & 12) << 2;
#pragma unroll
        for (int n = 0; n < 2; ++n) {
          const int col = wc + n * 16 + l15;          // 0..127
          const float v = acc[m][n][jj] + bias[col0 + col];
          const unsigned short h =
              __builtin_bit_cast(unsigned short, (_Float16)v);
          const unsigned char b8 =
              (unsigned char)((h + 0x7fu + ((h >> 8) & 1u)) >> 8);
          ((unsigned char*)smem)[row_l * 128 + (col ^ swz)] = b8;
        }
      }
    __syncthreads();
#pragma unroll
    for (int pp = 0; pp < 2; ++pp) {
      const int u = pp * 512 + tid;       // 1024 16B units
      const int row_l = u >> 3;
      const int cb16 = (u & 7) * 16;
      const int gr = row0 + row_l;
      if (gr < M) {
        const bf16x8 vv = *(const bf16x8*)((const unsigned char*)smem +
                                           row_l * 128 +
                                           (cb16 ^ ((row_l & 12) << 2)));
        unsigned char* op =
            (EPI == 4)
                ? (unsigned char*)out + (size_t)gr * 1024 + 512 +
                      (col0 - 256) + cb16
                : (unsigned char*)out + (size_t)gr * ldo + col0 + cb16;
        *(bf16x8*)op = vv;
      }
    }
  } else {
    // bf16 out: full-tile repack through smem [128][128] u16, 16B stores
    unsigned short* R = (unsigned short*)smem;
#pragma unroll
    for (int m = 0; m < 4; ++m)
#pragma unroll
      for (int jj = 0; jj < 4; ++jj) {
        const int row_l = wr + m * 16 + l4 * 4 + jj;  // 0..127
        const int swz = (row_l & 12) << 2;            // u16 XOR 0/16/32/48
#pragma unroll
        for (int n = 0; n < 2; ++n) {
          const int col = wc + n * 16 + l15;
          float v = acc[m][n][jj] + bias[col0 + col];
          if (EPI == 1) {
            // gelu_tanh(v) == v * sigmoid(2u), u = 0.79788(v+0.044715v^3)
            const float u2 = 1.5957691216f * (v + 0.044715f * v * v * v);
            v = v / (1.f + __expf(-u2));
          }
          R[row_l * 128 + (col ^ swz)] = f2bf(v);
        }
      }
    __syncthreads();
#pragma unroll
    for (int pp = 0; pp < 4; ++pp) {
      const int u = pp * 512 + tid;       // 2048 16B units
      const int row_l = u >> 4;
      const int col8 = (u & 15) * 8;
      const int gr = row0 + row_l;
      if (gr < M) {
        const bf16x8 vv =
            *(const bf16x8*)&R[row_l * 128 + (col8 ^ ((row_l & 12) << 2))];
        unsigned short* op =
            (EPI == 4) ? (unsigned short*)out + (size_t)gr * 512 + col0 + col8
                       : (unsigned short*)out + (size_t)gr * ldo + col0 + col8;
        *(bf16x8*)op = vv;
      }
    }
  }
}

// ---------------------------------------------------------------------------
// helpers
// ---------------------------------------------------------------------------
__global__ void sentinel_fill(float* o, long n, float v) {
  long i = (long)blockIdx.x * blockDim.x + threadIdx.x;
  const long st = (long)gridDim.x * blockDim.x;
  for (; i < n; i += st) o[i] = (i == 0) ? v : 0.f;
}

// fused prep: weight transposes (kv-interleave for Wk/Wv), bias concat,
// deg zeroing, int64-detect.  grid = dim3(1536, 10).
__global__ void prep_weights(const float* __restrict__ Wc, const float* __restrict__ Wq,
                             const float* __restrict__ Wk, const float* __restrict__ Wv,
                             const float* __restrict__ Wo, const float* __restrict__ W1,
                             const float* __restrict__ W2,
                             unsigned short* __restrict__ Wct,
                             unsigned short* __restrict__ Wqkvt,
                             unsigned short* __restrict__ Wot,
                             unsigned short* __restrict__ W1t,
                             unsigned short* __restrict__ W2t,
                             const float* __restrict__ bq, const float* __restrict__ bk,
                             const float* __restrict__ bv, float* __restrict__ bqkv,
                             int* __restrict__ deg, int Mdeg,
                             const unsigned int* __restrict__ ei_u32, int E,
                             int* __restrict__ flag) {
  const int job = blockIdx.y;
  const int i = blockIdx.x * 256 + threadIdx.x;
  if (job == 7) {  // bias concat (kv-interleaved)
    if (i < 256) bqkv[i] = bq[i];
    else if (i < 512) { int d = i - 256; bqkv[256 + ((d >> 2) << 3) + (d & 3)] = bk[d]; }
    else if (i < 768) { int d = i - 512; bqkv[256 + ((d >> 2) << 3) + 4 + (d & 3)] = bv[d]; }
    return;
  }
  if (job == 8) {  // zero deg
    if (i < Mdeg) deg[i] = 0;
    return;
  }
  if (job == 9) {  // int64 detect (block 0 only)
    if (blockIdx.x != 0) return;
    __shared__ int bad;
    if (threadIdx.x == 0) bad = 0;
    __syncthreads();
    const int n = E < 256 ? E : 256;
    if ((int)threadIdx.x < n && ei_u32[2 * threadIdx.x + 1] != 0u) atomicAdd(&bad, 1);
    __syncthreads();
    if (threadIdx.x == 0) *flag = (bad == 0);
    return;
  }
  const float* W; unsigned short* Wt; int N, kc, mode = 0;
  switch (job) {
    case 0: W = Wc; Wt = Wct; N = 1536; kc = 256; break;
    case 1: W = Wq; Wt = Wqkvt; N = 256; kc = 256; break;
    case 2: W = Wk; Wt = Wqkvt + 256 * 256; N = 256; kc = 256; mode = 1; break;
    case 3: W = Wv; Wt = Wqkvt + 256 * 256; N = 256; kc = 256; mode = 2; break;
    case 4: W = Wo; Wt = Wot; N = 256; kc = 256; break;
    case 5: W = W1; Wt = W1t; N = 1024; kc = 256; break;
    default: W = W2; Wt = W2t; N = 256; kc = 1024; break;
  }
  if (i >= N * kc) return;
  const int kk = i / N, n = i - kk * N;
  int r = n;
  if (mode == 1) r = ((n >> 2) << 3) + (n & 3);
  else if (mode == 2) r = ((n >> 2) << 3) + 4 + (n & 3);
  Wt[(size_t)r * kc + kk] = f2bf(W[(size_t)kk * N + n]);
}

__global__ void silu_cast(const float* __restrict__ c, unsigned short* __restrict__ o,
                          int total4) {
  int i = blockIdx.x * blockDim.x + threadIdx.x;
  if (i >= total4) return;
  float4 v = *(const float4*)&c[(size_t)i * 4];
  ushort4 r;
  r.x = f2bf(v.x / (1.f + __expf(-v.x)));
  r.y = f2bf(v.y / (1.f + __expf(-v.y)));
  r.z = f2bf(v.z / (1.f + __expf(-v.z)));
  r.w = f2bf(v.w / (1.f + __expf(-v.w)));
  *(ushort4*)&o[(size_t)i * 4] = r;
}

// one wave per row: h = ((x-mean)*rstd)*(1+scale)+shift -> bf16
template <int INBF>
__global__ void ln_modulate(const void* __restrict__ xin,
                            const unsigned short* __restrict__ modv,
                            unsigned short* __restrict__ hout,
                            int M, int cshift, int cscale) {
  const int wid = threadIdx.x >> 6, lane = threadIdx.x & 63;
  const int row = blockIdx.x * 4 + wid;
  if (row >= M) return;
  float4 x4;
  if (INBF) {
    const ushort4 u4 =
        *(const ushort4*)((const unsigned short*)xin + (size_t)row * 256 + lane * 4);
    x4.x = bf2f(u4.x); x4.y = bf2f(u4.y); x4.z = bf2f(u4.z); x4.w = bf2f(u4.w);
  } else {
    x4 = *(const float4*)((const float*)xin + (size_t)row * 256 + lane * 4);
  }
  float s = x4.x + x4.y + x4.z + x4.w;
  float ss = x4.x * x4.x + x4.y * x4.y + x4.z * x4.z + x4.w * x4.w;
#pragma unroll
  for (int m = 1; m < 64; m <<= 1) {
    s += __shfl_xor(s, m, 64);
    ss += __shfl_xor(ss, m, 64);
  }
  const float mean = s * (1.f / 256.f);
  const float var = ss * (1.f / 256.f) - mean * mean;
  const float rstd = rsqrtf(var + 1e-6f);
  const ushort4 sh4 = *(const ushort4*)&modv[(size_t)row * 1536 + cshift * 256 + lane * 4];
  const ushort4 sc4 = *(const ushort4*)&modv[(size_t)row * 1536 + cscale * 256 + lane * 4];
  ushort4 o;
  o.x = f2bf((x4.x - mean) * rstd * (1.f + bf2f(sc4.x)) + bf2f(sh4.x));
  o.y = f2bf((x4.y - mean) * rstd * (1.f + bf2f(sc4.y)) + bf2f(sh4.y));
  o.z = f2bf((x4.z - mean) * rstd * (1.f + bf2f(sc4.z)) + bf2f(sh4.z));
  o.w = f2bf((x4.w - mean) * rstd * (1.f + bf2f(sc4.w)) + bf2f(sh4.w));
  *(ushort4*)&hout[(size_t)row * 256 + lane * 4] = o;
}

// unpack edge_index -> src32/dst32 and histogram dst degree (fused)
__global__ void conv_hist(const void* __restrict__ ei, const int* __restrict__ flag,
                          int* __restrict__ src32, int* __restrict__ dst32,
                          int* __restrict__ deg, int E) {
  int e = blockIdx.x * blockDim.x + threadIdx.x;
  if (e >= E) return;
  int s, d;
  if (*flag) {
    const long long* p = (const long long*)ei;
    s = (int)p[e]; d = (int)p[E + e];
  } else {
    const int* p = (const int*)ei;
    s = p[e]; d = p[E + e];
  }
  src32[e] = s; dst32[e] = d;
  atomicAdd(&deg[d], 1);
}

// 2-phase scan: per-block sums, then scan_final self-reduces the block sums
__global__ __launch_bounds__(256)
void block_sum(const int* __restrict__ deg, int* __restrict__ bsum, int M) {
  int i = blockIdx.x * 256 + threadIdx.x;
  int v = (i < M) ? deg[i] : 0;
#pragma unroll
  for (int d = 1; d < 64; d <<= 1) v += __shfl_xor(v, d, 64);
  __shared__ int ws[4];
  const int lane = threadIdx.x & 63, w = threadIdx.x >> 6;
  if (lane == 0) ws[w] = v;
  __syncthreads();
  if (threadIdx.x == 0) bsum[blockIdx.x] = ws[0] + ws[1] + ws[2] + ws[3];
}

__global__ __launch_bounds__(256)
void scan_final(const int* __restrict__ deg, const int* __restrict__ bsum,
                int* __restrict__ start, int* __restrict__ cursor, int M, int NB) {
  const int b = blockIdx.x, t = threadIdx.x, i = b * 256 + t;
  const int lane = t & 63, w = t >> 6;
  __shared__ int ws[4];
  __shared__ int pref;
  const int v = (i < M) ? deg[i] : 0;
  int s = v;
#pragma unroll
  for (int d = 1; d < 64; d <<= 1) {
    int u = __shfl_up(s, d, 64);
    if (lane >= d) s += u;
  }
  if (lane == 63) ws[w] = s;
  if (t < 64) {  // wave 0 reduces bsum[0..b-1]
    int acc = 0;
    for (int base = 0; base < b; base += 64) {
      const int idx = base + lane;
      acc += (idx < b) ? bsum[idx] : 0;
    }
#pragma unroll
    for (int d = 1; d < 64; d <<= 1) acc += __shfl_xor(acc, d, 64);
    if (lane == 0) pref = acc;
  }
  __syncthreads();
  int add = pref;
  for (int k = 0; k < w; ++k) add += ws[k];
  const int excl = s - v + add;
  if (i < M) { start[i] = excl; cursor[i] = excl; }
  if (i == M - 1) start[M] = excl + v;
}

__global__ void csr_fill(const int* __restrict__ src32, const int* __restrict__ dst32,
                         int* __restrict__ cursor, int* __restrict__ csr, int E) {
  int e = blockIdx.x * blockDim.x + threadIdx.x;
  if (e >= E) return;
  int pos = atomicAdd(&cursor[dst32[e]], 1);
  csr[pos] = src32[e];
}

// one wave per dst node; 2-deep batch-4 pipeline.  Row layout (1024 B):
// [q bf16 512B][kv fp8 e5m2 512B, lane l's 8B = k[4l..4l+3]|v[4l..4l+3]].
// Decode: v_perm_b32 (byte b -> hi byte of u16, 0x0C = zero fill);
// QK dot in packed f16 (v_pk_fma_f16), accumulation in f32.
__global__ __launch_bounds__(256)
void attn_gather(const int* __restrict__ csr, const int* __restrict__ start,
                 const unsigned char* __restrict__ qkvp,
                 unsigned short* __restrict__ aggb, int M) {
  const int wid = threadIdx.x >> 6, lane = threadIdx.x & 63;
  const int row = blockIdx.x * 4 + wid;
  if (row >= M) return;
  const ushort4 q4 = *(const ushort4*)(qkvp + (size_t)row * 1024 + lane * 8);
  const float SC = 0.17677669529663687f;  // 32^-0.5, folded into q
  h2_t q01h, q23h;
  q01h[0] = (_Float16)(bf2f(q4.x) * SC); q01h[1] = (_Float16)(bf2f(q4.y) * SC);
  q23h[0] = (_Float16)(bf2f(q4.z) * SC); q23h[1] = (_Float16)(bf2f(q4.w) * SC);
  const int b0 = start[row], e0 = start[row + 1];
  float den = 0.f, a0 = 0.f, a1 = 0.f, a2 = 0.f, a3 = 0.f;

  auto LDKV = [&](int src) {
    return *(const uint2*)(qkvp + (size_t)src * 1024 + 512 + lane * 8);
  };
#define PROC(kv2)                                                              \
  {                                                                            \
    const unsigned kd = kv2.x, vd = kv2.y;                                     \
    const h2_t k01 = __builtin_bit_cast(                                       \
        h2_t, __builtin_amdgcn_perm(0u, kd, 0x010C000Cu));                     \
    const h2_t k23 = __builtin_bit_cast(                                       \
        h2_t, __builtin_amdgcn_perm(0u, kd, 0x030C020Cu));                     \
    h2_t ph = k01 * q01h;                                                      \
    ph = k23 * q23h + ph;                                                      \
    float s = (float)ph[0] + (float)ph[1];                                     \
    s += __shfl_xor(s, 1, 64);                                                 \
    s += __shfl_xor(s, 2, 64);                                                 \
    s += __shfl_xor(s, 4, 64);                                                 \
    const float ex = __expf(s);                                                \
    const h2_t v01 = __builtin_bit_cast(                                       \
        h2_t, __builtin_amdgcn_perm(0u, vd, 0x010C000Cu));                     \
    const h2_t v23 = __builtin_bit_cast(                                       \
        h2_t, __builtin_amdgcn_perm(0u, vd, 0x030C020Cu));                     \
    den += ex;                                                                 \
    a0 += ex * (float)v01[0]; a1 += ex * (float)v01[1];                        \
    a2 += ex * (float)v23[0]; a3 += ex * (float)v23[1];                        \
  }

  int i = b0;
  if (i + 4 <= e0) {
    uint2 A0 = LDKV(csr[i]), A1 = LDKV(csr[i + 1]);
    uint2 A2 = LDKV(csr[i + 2]), A3 = LDKV(csr[i + 3]);
    while (i + 8 <= e0) {
      const uint2 B0 = LDKV(csr[i + 4]), B1 = LDKV(csr[i + 5]);
      const uint2 B2 = LDKV(csr[i + 6]), B3 = LDKV(csr[i + 7]);
      PROC(A0); PROC(A1); PROC(A2); PROC(A3);
      A0 = B0; A1 = B1; A2 = B2; A3 = B3;
      i += 4;
    }
    PROC(A0); PROC(A1); PROC(A2); PROC(A3);
    i += 4;
  }
  for (; i < e0; ++i) {
    const uint2 kv2 = LDKV(csr[i]);
    PROC(kv2);
  }
#undef PROC

  const float inv = den > 0.f ? 1.f / den : 0.f;
  ushort4 r;
  r.x = f2bf(a0 * inv); r.y = f2bf(a1 * inv);
  r.z = f2bf(a2 * inv); r.w = f2bf(a3 * inv);
  *(ushort4*)&aggb[(size_t)row * 256 + lane * 4] = r;
}

// ---------------------------------------------------------------------------
extern "C" void kernel_launch(void* const* d_in, const int* in_sizes, int n_in,
                              void* d_out, int out_size, void* d_ws, size_t ws_size,
                              hipStream_t stream) {
  (void)n_in;
  const float* x  = (const float*)d_in[0];
  const float* c  = (const float*)d_in[1];
  const void*  ei = d_in[2];
  const float* Wq = (const float*)d_in[3];
  const float* bq = (const float*)d_in[4];
  const float* Wk = (const float*)d_in[5];
  const float* bk = (const float*)d_in[6];
  const float* Wv = (const float*)d_in[7];
  const float* bv = (const float*)d_in[8];
  const float* Wo = (const float*)d_in[9];
  const float* bo = (const float*)d_in[10];
  const float* W1 = (const float*)d_in[11];
  const float* b1 = (const float*)d_in[12];
  const float* W2 = (const float*)d_in[13];
  const float* b2 = (const float*)d_in[14];
  const float* Wc = (const float*)d_in[15];
  const float* bc = (const float*)d_in[16];

  const int M = in_sizes[0] / 256;   // 50000
  const int E = in_sizes[2] / 2;     // 800000

  char* ws = (char*)d_ws;
  size_t off = 0;
  auto carve = [&](size_t bytes) {
    char* p = ws + off;
    off = (off + bytes + 255) & ~(size_t)255;
    return p;
  };
  // persistent: modv [M,1536]b; cols 0..1024 reused as h2 (ldo=1536) after ln2
  unsigned short* modv = (unsigned short*)carve((size_t)M * 1536 * 2);  // 153.6MB
  // region D (M*1024 bytes): cs -> qkvp [M,1024B] -> X1b [M,256]bf16
  char* D = carve((size_t)M * 1024);
  unsigned short* cs = (unsigned short*)D;
  unsigned char* qkvp = (unsigned char*)D;
  unsigned short* X1b = (unsigned short*)D;
  unsigned short* Wct   = (unsigned short*)carve((size_t)1536 * 256 * 2);
  unsigned short* Wqkvt = (unsigned short*)carve((size_t)768 * 256 * 2);
  unsigned short* Wot   = (unsigned short*)carve((size_t)256 * 256 * 2);
  unsigned short* W1t   = (unsigned short*)carve((size_t)1024 * 256 * 2);
  unsigned short* W2t   = (unsigned short*)carve((size_t)256 * 1024 * 2);
  float* bqkv = (float*)carve(768 * 4);
  int* flag = (int*)carve(256);
  // CSR buffers
  int* src32  = (int*)carve((size_t)E * 4);
  int* dst32  = (int*)carve((size_t)E * 4);
  int* deg    = (int*)carve((size_t)(M + 4) * 4);
  int* startp = (int*)carve((size_t)(M + 4) * 4);
  int* cursor = (int*)carve((size_t)(M + 4) * 4);
  int* csr    = (int*)carve((size_t)E * 4);
  int* bsum   = (int*)carve(1024);

  // d_out aliases: lo half hbuf/hbuf2 [M,256]b; hi half aggb [M,256]b
  unsigned short* hbuf  = (unsigned short*)d_out;
  unsigned short* hbuf2 = (unsigned short*)d_out;
  unsigned short* aggb  = (unsigned short*)((char*)d_out + (size_t)M * 512);
  float* xout = (float*)d_out;

  if (off > ws_size) {
    sentinel_fill<<<2048, 256, 0, stream>>>((float*)d_out, (long)out_size,
                                            (float)ws_size);
    return;
  }

  const int tb = 256;
  const int EB = (E + tb - 1) / tb;
  const int SB = (M + 255) / 256;

  prep_weights<<<dim3(1536, 10), 256, 0, stream>>>(
      Wc, Wq, Wk, Wv, Wo, W1, W2, Wct, Wqkvt, Wot, W1t, W2t,
      bq, bk, bv, bqkv, deg, M + 4, (const unsigned int*)ei, E, flag);
  // --- CSR build ---
  conv_hist<<<EB, tb, 0, stream>>>(ei, flag, src32, dst32, deg, E);
  block_sum<<<SB, 256, 0, stream>>>(deg, bsum, M);
  scan_final<<<SB, 256, 0, stream>>>(deg, bsum, startp, cursor, M, SB);
  csr_fill<<<EB, tb, 0, stream>>>(src32, dst32, cursor, csr, E);

  auto gsz = [](int Mz, int Nz) {
    int MT = (Mz + 127) / 128, NT = Nz / 128;
    return 8 * ((MT + 7) / 8) * NT;
  };
  // cs = bf16(silu(c))
  silu_cast<<<(M * 64 + tb - 1) / tb, tb, 0, stream>>>(c, cs, M * 64);
  // modv = cs @ Wc + bc   [M,1536]
  gemm_bf16<0, 0, 0><<<gsz(M, 1536), 512, 0, stream>>>(
      cs, Wct, bc, nullptr, nullptr, modv, M, 1536, 256, 256, 1536);
  // hbuf = modulate(ln(x), shift_msa, scale_msa)
  ln_modulate<0><<<(M + 3) / 4, 256, 0, stream>>>(x, modv, hbuf, M, 0, 1);
  // merged qkv: cols 0-255 bf16 q, cols 256-767 fp8 kv (EPI4)
  gemm_bf16<4, 0, 0><<<gsz(M, 768), 512, 0, stream>>>(
      hbuf, Wqkvt, bqkv, nullptr, nullptr, qkvp, M, 768, 256, 256, 0);
  // aggb(d_out hi) = per-dst softmax gather (fp8 kv)
  attn_gather<<<(M + 3) / 4, 256, 0, stream>>>(csr, startp, qkvp, aggb, M);
  // X1b(D) = bf16(x + gate_msa * (aggb @ Wo + bo))
  gemm_bf16<2, 0, 1><<<gsz(M, 256), 512, 0, stream>>>(
      aggb, Wot, bo, x, modv + 512, X1b, M, 256, 256, 256, 256);
  // hbuf2(d_out lo) = modulate(ln(X1b), shift_mlp, scale_mlp)
  ln_modulate<1><<<(M + 3) / 4, 256, 0, stream>>>(X1b, modv, hbuf2, M, 3, 4);
  // h2(modv cols 0..1024, ld 1536) = gelu(hbuf2 @ W1 + b1)   [M,1024]
  gemm_bf16<1, 0, 0><<<gsz(M, 1024), 512, 0, stream>>>(
      hbuf2, W1t, b1, nullptr, nullptr, modv, M, 1024, 256, 256, 1536);
  // out(d_out) = X1b + gate_mlp * (h2 @ W2 + b2)   [f32]
  gemm_bf16<2, 1, 0><<<gsz(M, 256), 512, 0, stream>>>(
      modv, W2t, b2, X1b, modv + 1280, xout, M, 256, 1024, 1536, 256);
}

// Round 15
// 464.630 us; speedup vs baseline: 1.3635x; 1.0139x over previous
//
#include <hip/hip_runtime.h>

// ---------------------------------------------------------------------------
// DiT graph-attention block, MI355X (gfx950).
// R15: gelu/silu via exp2-direct + v_rcp (W1 epilogue was VALUBusy 67%);
//      silu folded into prep_weights as grid-stride job (one fewer launch).
// ---------------------------------------------------------------------------

typedef __attribute__((ext_vector_type(8))) short bf16x8;
typedef __attribute__((ext_vector_type(2))) _Float16 h2_t;
typedef __attribute__((ext_vector_type(4))) float f32x4;

__device__ __forceinline__ float bf2f(unsigned short u) {
  union { float f; unsigned int i; } x; x.i = ((unsigned int)u) << 16; return x.f;
}
__device__ __forceinline__ unsigned short f2bf(float f) {
  union { float f; unsigned int i; } x; x.f = f;
  unsigned int r = x.i + 0x7fffu + ((x.i >> 16) & 1u);  // RNE
  return (unsigned short)(r >> 16);
}
__device__ __forceinline__ float sigm_fast(float t) {
  // sigmoid(t/log2e) form: caller passes t = x*log2(e) pre-scaled
  return __builtin_amdgcn_rcpf(1.f + exp2f(-t));
}

__device__ __forceinline__ void gload_lds16(const void* g, void* l) {
  __builtin_amdgcn_global_load_lds(
      (const __attribute__((address_space(1))) void*)g,
      (__attribute__((address_space(3))) void*)l, 16, 0, 0);
}

// ---------------------------------------------------------------------------
// Unified bf16 GEMM:  out = epilogue(A[M,K](lda) @ Bt[N,K]^T + bias)
// 8 waves/block, wave tile 64x32, 2-phase double-buffered staging.
// EPI 0: out bf16 = acc+bias                (full-tile LDS repack, ldo u16)
// EPI 1: out bf16 = gelu(acc+bias)          (repack)
// EPI 2: out = xin + gate*(acc+bias)        (XINBF/OUTBF select f32/bf16)
// EPI 3: out fp8 e5m2 = acc+bias            (byte repack; ldo bytes)
// EPI 4: merged qkv: cb<2 -> bf16 q (row 1024B), cb>=2 -> fp8 kv (+512B)
// ---------------------------------------------------------------------------
template <int EPI, int XINBF, int OUTBF>
__global__ __launch_bounds__(512)
void gemm_bf16(const unsigned short* __restrict__ A,
               const unsigned short* __restrict__ Bt,
               const float* __restrict__ bias,
               const void* __restrict__ xin,
               const unsigned short* __restrict__ gate,
               void* __restrict__ out,
               int M, int N, int K, int lda, int ldo) {
  const int NT = N >> 7;
  const int MT = (M + 127) >> 7;
  const int pid = blockIdx.x;
  const int j = pid >> 3;
  const int rb = (pid & 7) + 8 * (j / NT);
  const int cb = j - (j / NT) * NT;
  if (rb >= MT) return;  // uniform across block

  __shared__ char smem[65536];  // 2 buffers x (At 16KB | Bs 16KB)
  const int tid = threadIdx.x;
  const int wid = tid >> 6;
  const int lane = tid & 63;
  const int l15 = lane & 15, l4 = lane >> 4;
  const int row0 = rb * 128, col0 = cb * 128;
  const int wr = (wid >> 2) * 64;   // 0,64
  const int wc = (wid & 3) * 32;    // 0,32,64,96

  f32x4 acc[4][2];
  const f32x4 zf = {0.f, 0.f, 0.f, 0.f};
  for (int m = 0; m < 4; ++m)
    for (int n = 0; n < 2; ++n) acc[m][n] = zf;

  auto STAGE = [&](int buf, int kt) {
    char* At = smem + buf * 32768;
    char* Bs = At + 16384;
#pragma unroll
    for (int s = 0; s < 2; ++s) {
      const int p = s * 8192 + tid * 16;           // byte in 16KB tile
      const int r = p >> 7;                        // tile row 0..127
      const int scb = (p & 127) ^ ((r & 7) << 4);  // swizzled source col byte
      int gr = row0 + r; gr = gr < M ? gr : M - 1;
      gload_lds16((const char*)A + ((size_t)gr * lda + kt) * 2 + scb,
                  At + s * 8192 + wid * 1024);
      const int gc = col0 + r;                     // N multiple of 128
      gload_lds16((const char*)Bt + ((size_t)gc * K + kt) * 2 + scb,
                  Bs + s * 8192 + wid * 1024);
    }
  };

  STAGE(0, 0);
  __syncthreads();
  int cur = 0;
  for (int kt = 0; kt < K; kt += 64) {
    if (kt + 64 < K) STAGE(cur ^ 1, kt + 64);  // issue next tile EARLY
    const char* At = smem + cur * 32768;
    const char* Bs = At + 16384;
#pragma unroll
    for (int kk = 0; kk < 64; kk += 32) {
      bf16x8 af[4], bfr[2];
#pragma unroll
      for (int m = 0; m < 4; ++m) {
        const int r = wr + m * 16 + l15;
        const int cb2 = ((kk + l4 * 8) * 2) ^ ((r & 7) << 4);
        af[m] = *(const bf16x8*)(At + r * 128 + cb2);
      }
#pragma unroll
      for (int n = 0; n < 2; ++n) {
        const int r = wc + n * 16 + l15;
        const int cb2 = ((kk + l4 * 8) * 2) ^ ((r & 7) << 4);
        bfr[n] = *(const bf16x8*)(Bs + r * 128 + cb2);
      }
#pragma unroll
      for (int m = 0; m < 4; ++m)
#pragma unroll
        for (int n = 0; n < 2; ++n)
          acc[m][n] = __builtin_amdgcn_mfma_f32_16x16x32_bf16(af[m], bfr[n],
                                                              acc[m][n], 0, 0, 0);
    }
    __syncthreads();
    cur ^= 1;
  }

  const bool fp8path = (EPI == 3) || (EPI == 4 && cb >= 2);
  // C/D layout: col=lane&15, row=(lane>>4)*4+reg   [guide §3, m89/m91]
  if (EPI == 2) {
#pragma unroll
    for (int m = 0; m < 4; ++m)
#pragma unroll
      for (int jj = 0; jj < 4; ++jj) {
        const int gr = row0 + wr + m * 16 + l4 * 4 + jj;
        if (gr >= M) continue;
#pragma unroll
        for (int n = 0; n < 2; ++n) {
          const int gc = col0 + wc + n * 16 + l15;
          const float v = acc[m][n][jj] + bias[gc];
          const float gt = bf2f(gate[(size_t)gr * 1536 + gc]);
          const float xv =
              XINBF ? bf2f(((const unsigned short*)xin)[(size_t)gr * ldo + gc])
                    : ((const float*)xin)[(size_t)gr * ldo + gc];
          const float rv = xv + gt * v;
          if (OUTBF)
            ((unsigned short*)out)[(size_t)gr * ldo + gc] = f2bf(rv);
          else
            ((float*)out)[(size_t)gr * ldo + gc] = rv;
        }
      }
  } else if (fp8path) {
    // fp8 e5m2: byte repack through smem [128][128]B, 16B stores
#pragma unroll
    for (int m = 0; m < 4; ++m)
#pragma unroll
      for (int jj = 0; jj < 4; ++jj) {
        const int row_l = wr + m * 16 + l4 * 4 + jj;  // 0..127
        const int swz = (row_l & 12) << 2;
#pragma unroll
        for (int n = 0; n < 2; ++n) {
          const int col = wc + n * 16 + l15;          // 0..127
          const float v = acc[m][n][jj] + bias[col0 + col];
          const unsigned short h =
              __builtin_bit_cast(unsigned short, (_Float16)v);
          const unsigned char b8 =
              (unsigned char)((h + 0x7fu + ((h >> 8) & 1u)) >> 8);
          ((unsigned char*)smem)[row_l * 128 + (col ^ swz)] = b8;
        }
      }
    __syncthreads();
#pragma unroll
    for (int pp = 0; pp < 2; ++pp) {
      const int u = pp * 512 + tid;       // 1024 16B units
      const int row_l = u >> 3;
      const int cb16 = (u & 7) * 16;
      const int gr = row0 + row_l;
      if (gr < M) {
        const bf16x8 vv = *(const bf16x8*)((const unsigned char*)smem +
                                           row_l * 128 +
                                           (cb16 ^ ((row_l & 12) << 2)));
        unsigned char* op =
            (EPI == 4)
                ? (unsigned char*)out + (size_t)gr * 1024 + 512 +
                      (col0 - 256) + cb16
                : (unsigned char*)out + (size_t)gr * ldo + col0 + cb16;
        *(bf16x8*)op = vv;
      }
    }
  } else {
    // bf16 out: full-tile repack through smem [128][128] u16, 16B stores
    unsigned short* R = (unsigned short*)smem;
#pragma unroll
    for (int m = 0; m < 4; ++m)
#pragma unroll
      for (int jj = 0; jj < 4; ++jj) {
        const int row_l = wr + m * 16 + l4 * 4 + jj;  // 0..127
        const int swz = (row_l & 12) << 2;            // u16 XOR 0/16/32/48
#pragma unroll
        for (int n = 0; n < 2; ++n) {
          const int col = wc + n * 16 + l15;
          float v = acc[m][n][jj] + bias[col0 + col];
          if (EPI == 1) {
            // gelu_tanh(v) == v*sigmoid(2u); 2u*log2e = 2.3026(v+0.044715v^3)
            v = v * sigm_fast(2.3025851f * (v + 0.044715f * v * v * v));
          }
          R[row_l * 128 + (col ^ swz)] = f2bf(v);
        }
      }
    __syncthreads();
#pragma unroll
    for (int pp = 0; pp < 4; ++pp) {
      const int u = pp * 512 + tid;       // 2048 16B units
      const int row_l = u >> 4;
      const int col8 = (u & 15) * 8;
      const int gr = row0 + row_l;
      if (gr < M) {
        const bf16x8 vv =
            *(const bf16x8*)&R[row_l * 128 + (col8 ^ ((row_l & 12) << 2))];
        unsigned short* op =
            (EPI == 4) ? (unsigned short*)out + (size_t)gr * 512 + col0 + col8
                       : (unsigned short*)out + (size_t)gr * ldo + col0 + col8;
        *(bf16x8*)op = vv;
      }
    }
  }
}

// ---------------------------------------------------------------------------
// helpers
// ---------------------------------------------------------------------------
__global__ void sentinel_fill(float* o, long n, float v) {
  long i = (long)blockIdx.x * blockDim.x + threadIdx.x;
  const long st = (long)gridDim.x * blockDim.x;
  for (; i < n; i += st) o[i] = (i == 0) ? v : 0.f;
}

// fused prep: weight transposes (kv-interleave for Wk/Wv), bias concat,
// deg zeroing, int64-detect, silu(c)->bf16 (grid-stride).  dim3(1536, 11).
__global__ void prep_weights(const float* __restrict__ Wc, const float* __restrict__ Wq,
                             const float* __restrict__ Wk, const float* __restrict__ Wv,
                             const float* __restrict__ Wo, const float* __restrict__ W1,
                             const float* __restrict__ W2,
                             unsigned short* __restrict__ Wct,
                             unsigned short* __restrict__ Wqkvt,
                             unsigned short* __restrict__ Wot,
                             unsigned short* __restrict__ W1t,
                             unsigned short* __restrict__ W2t,
                             const float* __restrict__ bq, const float* __restrict__ bk,
                             const float* __restrict__ bv, float* __restrict__ bqkv,
                             int* __restrict__ deg, int Mdeg,
                             const unsigned int* __restrict__ ei_u32, int E,
                             int* __restrict__ flag,
                             const float* __restrict__ c,
                             unsigned short* __restrict__ cs, int silu4) {
  const int job = blockIdx.y;
  const int i = blockIdx.x * 256 + threadIdx.x;
  if (job == 7) {  // bias concat (kv-interleaved)
    if (i < 256) bqkv[i] = bq[i];
    else if (i < 512) { int d = i - 256; bqkv[256 + ((d >> 2) << 3) + (d & 3)] = bk[d]; }
    else if (i < 768) { int d = i - 512; bqkv[256 + ((d >> 2) << 3) + 4 + (d & 3)] = bv[d]; }
    return;
  }
  if (job == 8) {  // zero deg
    if (i < Mdeg) deg[i] = 0;
    return;
  }
  if (job == 9) {  // int64 detect (block 0 only)
    if (blockIdx.x != 0) return;
    __shared__ int bad;
    if (threadIdx.x == 0) bad = 0;
    __syncthreads();
    const int n = E < 256 ? E : 256;
    if ((int)threadIdx.x < n && ei_u32[2 * threadIdx.x + 1] != 0u) atomicAdd(&bad, 1);
    __syncthreads();
    if (threadIdx.x == 0) *flag = (bad == 0);
    return;
  }
  if (job == 10) {  // silu(c) -> bf16, grid-stride over float4 granules
    const int stride = gridDim.x * 256;
    for (int g = i; g < silu4; g += stride) {
      float4 v = *(const float4*)&c[(size_t)g * 4];
      ushort4 r;
      r.x = f2bf(v.x * sigm_fast(1.4426950f * v.x));
      r.y = f2bf(v.y * sigm_fast(1.4426950f * v.y));
      r.z = f2bf(v.z * sigm_fast(1.4426950f * v.z));
      r.w = f2bf(v.w * sigm_fast(1.4426950f * v.w));
      *(ushort4*)&cs[(size_t)g * 4] = r;
    }
    return;
  }
  const float* W; unsigned short* Wt; int N, kc, mode = 0;
  switch (job) {
    case 0: W = Wc; Wt = Wct; N = 1536; kc = 256; break;
    case 1: W = Wq; Wt = Wqkvt; N = 256; kc = 256; break;
    case 2: W = Wk; Wt = Wqkvt + 256 * 256; N = 256; kc = 256; mode = 1; break;
    case 3: W = Wv; Wt = Wqkvt + 256 * 256; N = 256; kc = 256; mode = 2; break;
    case 4: W = Wo; Wt = Wot; N = 256; kc = 256; break;
    case 5: W = W1; Wt = W1t; N = 1024; kc = 256; break;
    default: W = W2; Wt = W2t; N = 256; kc = 1024; break;
  }
  if (i >= N * kc) return;
  const int kk = i / N, n = i - kk * N;
  int r = n;
  if (mode == 1) r = ((n >> 2) << 3) + (n & 3);
  else if (mode == 2) r = ((n >> 2) << 3) + 4 + (n & 3);
  Wt[(size_t)r * kc + kk] = f2bf(W[(size_t)kk * N + n]);
}

// one wave per row: h = ((x-mean)*rstd)*(1+scale)+shift -> bf16
template <int INBF>
__global__ void ln_modulate(const void* __restrict__ xin,
                            const unsigned short* __restrict__ modv,
                            unsigned short* __restrict__ hout,
                            int M, int cshift, int cscale) {
  const int wid = threadIdx.x >> 6, lane = threadIdx.x & 63;
  const int row = blockIdx.x * 4 + wid;
  if (row >= M) return;
  float4 x4;
  if (INBF) {
    const ushort4 u4 =
        *(const ushort4*)((const unsigned short*)xin + (size_t)row * 256 + lane * 4);
    x4.x = bf2f(u4.x); x4.y = bf2f(u4.y); x4.z = bf2f(u4.z); x4.w = bf2f(u4.w);
  } else {
    x4 = *(const float4*)((const float*)xin + (size_t)row * 256 + lane * 4);
  }
  float s = x4.x + x4.y + x4.z + x4.w;
  float ss = x4.x * x4.x + x4.y * x4.y + x4.z * x4.z + x4.w * x4.w;
#pragma unroll
  for (int m = 1; m < 64; m <<= 1) {
    s += __shfl_xor(s, m, 64);
    ss += __shfl_xor(ss, m, 64);
  }
  const float mean = s * (1.f / 256.f);
  const float var = ss * (1.f / 256.f) - mean * mean;
  const float rstd = rsqrtf(var + 1e-6f);
  const ushort4 sh4 = *(const ushort4*)&modv[(size_t)row * 1536 + cshift * 256 + lane * 4];
  const ushort4 sc4 = *(const ushort4*)&modv[(size_t)row * 1536 + cscale * 256 + lane * 4];
  ushort4 o;
  o.x = f2bf((x4.x - mean) * rstd * (1.f + bf2f(sc4.x)) + bf2f(sh4.x));
  o.y = f2bf((x4.y - mean) * rstd * (1.f + bf2f(sc4.y)) + bf2f(sh4.y));
  o.z = f2bf((x4.z - mean) * rstd * (1.f + bf2f(sc4.z)) + bf2f(sh4.z));
  o.w = f2bf((x4.w - mean) * rstd * (1.f + bf2f(sc4.w)) + bf2f(sh4.w));
  *(ushort4*)&hout[(size_t)row * 256 + lane * 4] = o;
}

// unpack edge_index -> src32/dst32 and histogram dst degree (fused)
__global__ void conv_hist(const void* __restrict__ ei, const int* __restrict__ flag,
                          int* __restrict__ src32, int* __restrict__ dst32,
                          int* __restrict__ deg, int E) {
  int e = blockIdx.x * blockDim.x + threadIdx.x;
  if (e >= E) return;
  int s, d;
  if (*flag) {
    const long long* p = (const long long*)ei;
    s = (int)p[e]; d = (int)p[E + e];
  } else {
    const int* p = (const int*)ei;
    s = p[e]; d = p[E + e];
  }
  src32[e] = s; dst32[e] = d;
  atomicAdd(&deg[d], 1);
}

// 2-phase scan: per-block sums, then scan_final self-reduces the block sums
__global__ __launch_bounds__(256)
void block_sum(const int* __restrict__ deg, int* __restrict__ bsum, int M) {
  int i = blockIdx.x * 256 + threadIdx.x;
  int v = (i < M) ? deg[i] : 0;
#pragma unroll
  for (int d = 1; d < 64; d <<= 1) v += __shfl_xor(v, d, 64);
  __shared__ int ws[4];
  const int lane = threadIdx.x & 63, w = threadIdx.x >> 6;
  if (lane == 0) ws[w] = v;
  __syncthreads();
  if (threadIdx.x == 0) bsum[blockIdx.x] = ws[0] + ws[1] + ws[2] + ws[3];
}

__global__ __launch_bounds__(256)
void scan_final(const int* __restrict__ deg, const int* __restrict__ bsum,
                int* __restrict__ start, int* __restrict__ cursor, int M, int NB) {
  const int b = blockIdx.x, t = threadIdx.x, i = b * 256 + t;
  const int lane = t & 63, w = t >> 6;
  __shared__ int ws[4];
  __shared__ int pref;
  const int v = (i < M) ? deg[i] : 0;
  int s = v;
#pragma unroll
  for (int d = 1; d < 64; d <<= 1) {
    int u = __shfl_up(s, d, 64);
    if (lane >= d) s += u;
  }
  if (lane == 63) ws[w] = s;
  if (t < 64) {  // wave 0 reduces bsum[0..b-1]
    int acc = 0;
    for (int base = 0; base < b; base += 64) {
      const int idx = base + lane;
      acc += (idx < b) ? bsum[idx] : 0;
    }
#pragma unroll
    for (int d = 1; d < 64; d <<= 1) acc += __shfl_xor(acc, d, 64);
    if (lane == 0) pref = acc;
  }
  __syncthreads();
  int add = pref;
  for (int k = 0; k < w; ++k) add += ws[k];
  const int excl = s - v + add;
  if (i < M) { start[i] = excl; cursor[i] = excl; }
  if (i == M - 1) start[M] = excl + v;
}

__global__ void csr_fill(const int* __restrict__ src32, const int* __restrict__ dst32,
                         int* __restrict__ cursor, int* __restrict__ csr, int E) {
  int e = blockIdx.x * blockDim.x + threadIdx.x;
  if (e >= E) return;
  int pos = atomicAdd(&cursor[dst32[e]], 1);
  csr[pos] = src32[e];
}

// one wave per dst node; 2-deep batch-4 pipeline.  Row layout (1024 B):
// [q bf16 512B][kv fp8 e5m2 512B, lane l's 8B = k[4l..4l+3]|v[4l..4l+3]].
// Decode: v_perm_b32; QK dot in packed f16, accumulation in f32.
__global__ __launch_bounds__(256)
void attn_gather(const int* __restrict__ csr, const int* __restrict__ start,
                 const unsigned char* __restrict__ qkvp,
                 unsigned short* __restrict__ aggb, int M) {
  const int wid = threadIdx.x >> 6, lane = threadIdx.x & 63;
  const int row = blockIdx.x * 4 + wid;
  if (row >= M) return;
  const ushort4 q4 = *(const ushort4*)(qkvp + (size_t)row * 1024 + lane * 8);
  const float SC = 0.17677669529663687f;  // 32^-0.5, folded into q
  h2_t q01h, q23h;
  q01h[0] = (_Float16)(bf2f(q4.x) * SC); q01h[1] = (_Float16)(bf2f(q4.y) * SC);
  q23h[0] = (_Float16)(bf2f(q4.z) * SC); q23h[1] = (_Float16)(bf2f(q4.w) * SC);
  const int b0 = start[row], e0 = start[row + 1];
  float den = 0.f, a0 = 0.f, a1 = 0.f, a2 = 0.f, a3 = 0.f;

  auto LDKV = [&](int src) {
    return *(const uint2*)(qkvp + (size_t)src * 1024 + 512 + lane * 8);
  };
#define PROC(kv2)                                                              \
  {                                                                            \
    const unsigned kd = kv2.x, vd = kv2.y;                                     \
    const h2_t k01 = __builtin_bit_cast(                                       \
        h2_t, __builtin_amdgcn_perm(0u, kd, 0x010C000Cu));                     \
    const h2_t k23 = __builtin_bit_cast(                                       \
        h2_t, __builtin_amdgcn_perm(0u, kd, 0x030C020Cu));                     \
    h2_t ph = k01 * q01h;                                                      \
    ph = k23 * q23h + ph;                                                      \
    float s = (float)ph[0] + (float)ph[1];                                     \
    s += __shfl_xor(s, 1, 64);                                                 \
    s += __shfl_xor(s, 2, 64);                                                 \
    s += __shfl_xor(s, 4, 64);                                                 \
    const float ex = __expf(s);                                                \
    const h2_t v01 = __builtin_bit_cast(                                       \
        h2_t, __builtin_amdgcn_perm(0u, vd, 0x010C000Cu));                     \
    const h2_t v23 = __builtin_bit_cast(                                       \
        h2_t, __builtin_amdgcn_perm(0u, vd, 0x030C020Cu));                     \
    den += ex;                                                                 \
    a0 += ex * (float)v01[0]; a1 += ex * (float)v01[1];                        \
    a2 += ex * (float)v23[0]; a3 += ex * (float)v23[1];                        \
  }

  int i = b0;
  if (i + 4 <= e0) {
    uint2 A0 = LDKV(csr[i]), A1 = LDKV(csr[i + 1]);
    uint2 A2 = LDKV(csr[i + 2]), A3 = LDKV(csr[i + 3]);
    while (i + 8 <= e0) {
      const uint2 B0 = LDKV(csr[i + 4]), B1 = LDKV(csr[i + 5]);
      const uint2 B2 = LDKV(csr[i + 6]), B3 = LDKV(csr[i + 7]);
      PROC(A0); PROC(A1); PROC(A2); PROC(A3);
      A0 = B0; A1 = B1; A2 = B2; A3 = B3;
      i += 4;
    }
    PROC(A0); PROC(A1); PROC(A2); PROC(A3);
    i += 4;
  }
  for (; i < e0; ++i) {
    const uint2 kv2 = LDKV(csr[i]);
    PROC(kv2);
  }
#undef PROC

  const float inv = den > 0.f ? __builtin_amdgcn_rcpf(den) : 0.f;
  ushort4 r;
  r.x = f2bf(a0 * inv); r.y = f2bf(a1 * inv);
  r.z = f2bf(a2 * inv); r.w = f2bf(a3 * inv);
  *(ushort4*)&aggb[(size_t)row * 256 + lane * 4] = r;
}

// ---------------------------------------------------------------------------
extern "C" void kernel_launch(void* const* d_in, const int* in_sizes, int n_in,
                              void* d_out, int out_size, void* d_ws, size_t ws_size,
                              hipStream_t stream) {
  (void)n_in;
  const float* x  = (const float*)d_in[0];
  const float* c  = (const float*)d_in[1];
  const void*  ei = d_in[2];
  const float* Wq = (const float*)d_in[3];
  const float* bq = (const float*)d_in[4];
  const float* Wk = (const float*)d_in[5];
  const float* bk = (const float*)d_in[6];
  const float* Wv = (const float*)d_in[7];
  const float* bv = (const float*)d_in[8];
  const float* Wo = (const float*)d_in[9];
  const float* bo = (const float*)d_in[10];
  const float* W1 = (const float*)d_in[11];
  const float* b1 = (const float*)d_in[12];
  const float* W2 = (const float*)d_in[13];
  const float* b2 = (const float*)d_in[14];
  const float* Wc = (const float*)d_in[15];
  const float* bc = (const float*)d_in[16];

  const int M = in_sizes[0] / 256;   // 50000
  const int E = in_sizes[2] / 2;     // 800000

  char* ws = (char*)d_ws;
  size_t off = 0;
  auto carve = [&](size_t bytes) {
    char* p = ws + off;
    off = (off + bytes + 255) & ~(size_t)255;
    return p;
  };
  // persistent: modv [M,1536]b; cols 0..1024 reused as h2 (ldo=1536) after ln2
  unsigned short* modv = (unsigned short*)carve((size_t)M * 1536 * 2);  // 153.6MB
  // region D (M*1024 bytes): cs -> qkvp [M,1024B] -> X1b [M,256]bf16
  char* D = carve((size_t)M * 1024);
  unsigned short* cs = (unsigned short*)D;
  unsigned char* qkvp = (unsigned char*)D;
  unsigned short* X1b = (unsigned short*)D;
  unsigned short* Wct   = (unsigned short*)carve((size_t)1536 * 256 * 2);
  unsigned short* Wqkvt = (unsigned short*)carve((size_t)768 * 256 * 2);
  unsigned short* Wot   = (unsigned short*)carve((size_t)256 * 256 * 2);
  unsigned short* W1t   = (unsigned short*)carve((size_t)1024 * 256 * 2);
  unsigned short* W2t   = (unsigned short*)carve((size_t)256 * 1024 * 2);
  float* bqkv = (float*)carve(768 * 4);
  int* flag = (int*)carve(256);
  // CSR buffers
  int* src32  = (int*)carve((size_t)E * 4);
  int* dst32  = (int*)carve((size_t)E * 4);
  int* deg    = (int*)carve((size_t)(M + 4) * 4);
  int* startp = (int*)carve((size_t)(M + 4) * 4);
  int* cursor = (int*)carve((size_t)(M + 4) * 4);
  int* csr    = (int*)carve((size_t)E * 4);
  int* bsum   = (int*)carve(1024);

  // d_out aliases: lo half hbuf/hbuf2 [M,256]b; hi half aggb [M,256]b
  unsigned short* hbuf  = (unsigned short*)d_out;
  unsigned short* hbuf2 = (unsigned short*)d_out;
  unsigned short* aggb  = (unsigned short*)((char*)d_out + (size_t)M * 512);
  float* xout = (float*)d_out;

  if (off > ws_size) {
    sentinel_fill<<<2048, 256, 0, stream>>>((float*)d_out, (long)out_size,
                                            (float)ws_size);
    return;
  }

  const int tb = 256;
  const int EB = (E + tb - 1) / tb;
  const int SB = (M + 255) / 256;

  prep_weights<<<dim3(1536, 11), 256, 0, stream>>>(
      Wc, Wq, Wk, Wv, Wo, W1, W2, Wct, Wqkvt, Wot, W1t, W2t,
      bq, bk, bv, bqkv, deg, M + 4, (const unsigned int*)ei, E, flag,
      c, cs, M * 64);
  // --- CSR build ---
  conv_hist<<<EB, tb, 0, stream>>>(ei, flag, src32, dst32, deg, E);
  block_sum<<<SB, 256, 0, stream>>>(deg, bsum, M);
  scan_final<<<SB, 256, 0, stream>>>(deg, bsum, startp, cursor, M, SB);
  csr_fill<<<EB, tb, 0, stream>>>(src32, dst32, cursor, csr, E);

  auto gsz = [](int Mz, int Nz) {
    int MT = (Mz + 127) / 128, NT = Nz / 128;
    return 8 * ((MT + 7) / 8) * NT;
  };
  // modv = cs @ Wc + bc   [M,1536]
  gemm_bf16<0, 0, 0><<<gsz(M, 1536), 512, 0, stream>>>(
      cs, Wct, bc, nullptr, nullptr, modv, M, 1536, 256, 256, 1536);
  // hbuf = modulate(ln(x), shift_msa, scale_msa)
  ln_modulate<0><<<(M + 3) / 4, 256, 0, stream>>>(x, modv, hbuf, M, 0, 1);
  // merged qkv: cols 0-255 bf16 q, cols 256-767 fp8 kv (EPI4)
  gemm_bf16<4, 0, 0><<<gsz(M, 768), 512, 0, stream>>>(
      hbuf, Wqkvt, bqkv, nullptr, nullptr, qkvp, M, 768, 256, 256, 0);
  // aggb(d_out hi) = per-dst softmax gather (fp8 kv)
  attn_gather<<<(M + 3) / 4, 256, 0, stream>>>(csr, startp, qkvp, aggb, M);
  // X1b(D) = bf16(x + gate_msa * (aggb @ Wo + bo))
  gemm_bf16<2, 0, 1><<<gsz(M, 256), 512, 0, stream>>>(
      aggb, Wot, bo, x, modv + 512, X1b, M, 256, 256, 256, 256);
  // hbuf2(d_out lo) = modulate(ln(X1b), shift_mlp, scale_mlp)
  ln_modulate<1><<<(M + 3) / 4, 256, 0, stream>>>(X1b, modv, hbuf2, M, 3, 4);
  // h2(modv cols 0..1024, ld 1536) = gelu(hbuf2 @ W1 + b1)   [M,1024]
  gemm_bf16<1, 0, 0><<<gsz(M, 1024), 512, 0, stream>>>(
      hbuf2, W1t, b1, nullptr, nullptr, modv, M, 1024, 256, 256, 1536);
  // out(d_out) = X1b + gate_mlp * (h2 @ W2 + b2)   [f32]
  gemm_bf16<2, 1, 0><<<gsz(M, 256), 512, 0, stream>>>(
      modv, W2t, b2, X1b, modv + 1280, xout, M, 256, 1024, 1536, 256);
}

// Round 16
// 463.785 us; speedup vs baseline: 1.3660x; 1.0018x over previous
//
#include <hip/hip_runtime.h>

// ---------------------------------------------------------------------------
// DiT graph-attention block, MI355X (gfx950).
// R16: GEMM K-loop converted to counted-vmcnt pipeline (guide T4/m201):
//      raw s_barrier + s_waitcnt vmcnt(4) (NOT 0) so the newest stage's loads
//      stay in flight across the barrier; restage freed buffer after a
//      lgkmcnt(0)+barrier.  R15 profile: MfmaUtil 14/VALU 14/HBM 24 =>
//      __syncthreads' implicit vmcnt(0) drain was serializing every K-step.
// ---------------------------------------------------------------------------

typedef __attribute__((ext_vector_type(8))) short bf16x8;
typedef __attribute__((ext_vector_type(2))) _Float16 h2_t;
typedef __attribute__((ext_vector_type(4))) float f32x4;

__device__ __forceinline__ float bf2f(unsigned short u) {
  union { float f; unsigned int i; } x; x.i = ((unsigned int)u) << 16; return x.f;
}
__device__ __forceinline__ unsigned short f2bf(float f) {
  union { float f; unsigned int i; } x; x.f = f;
  unsigned int r = x.i + 0x7fffu + ((x.i >> 16) & 1u);  // RNE
  return (unsigned short)(r >> 16);
}
__device__ __forceinline__ float sigm_fast(float t) {
  // sigmoid(t/log2e) form: caller passes t = x*log2(e) pre-scaled
  return __builtin_amdgcn_rcpf(1.f + exp2f(-t));
}

__device__ __forceinline__ void gload_lds16(const void* g, void* l) {
  __builtin_amdgcn_global_load_lds(
      (const __attribute__((address_space(1))) void*)g,
      (__attribute__((address_space(3))) void*)l, 16, 0, 0);
}

// ---------------------------------------------------------------------------
// Unified bf16 GEMM:  out = epilogue(A[M,K](lda) @ Bt[N,K]^T + bias)
// 8 waves/block, wave tile 64x32, depth-2 counted-vmcnt pipeline.
// EPI 0: out bf16 = acc+bias                (full-tile LDS repack, ldo u16)
// EPI 1: out bf16 = gelu(acc+bias)          (repack)
// EPI 2: out = xin + gate*(acc+bias)        (XINBF/OUTBF select f32/bf16)
// EPI 3: out fp8 e5m2 = acc+bias            (byte repack; ldo bytes)
// EPI 4: merged qkv: cb<2 -> bf16 q (row 1024B), cb>=2 -> fp8 kv (+512B)
// ---------------------------------------------------------------------------
template <int EPI, int XINBF, int OUTBF>
__global__ __launch_bounds__(512)
void gemm_bf16(const unsigned short* __restrict__ A,
               const unsigned short* __restrict__ Bt,
               const float* __restrict__ bias,
               const void* __restrict__ xin,
               const unsigned short* __restrict__ gate,
               void* __restrict__ out,
               int M, int N, int K, int lda, int ldo) {
  const int NT = N >> 7;
  const int MT = (M + 127) >> 7;
  const int pid = blockIdx.x;
  const int j = pid >> 3;
  const int rb = (pid & 7) + 8 * (j / NT);
  const int cb = j - (j / NT) * NT;
  if (rb >= MT) return;  // uniform across block

  __shared__ char smem[65536];  // 2 buffers x (At 16KB | Bs 16KB)
  const int tid = threadIdx.x;
  const int wid = tid >> 6;
  const int lane = tid & 63;
  const int l15 = lane & 15, l4 = lane >> 4;
  const int row0 = rb * 128, col0 = cb * 128;
  const int wr = (wid >> 2) * 64;   // 0,64
  const int wc = (wid & 3) * 32;    // 0,32,64,96

  f32x4 acc[4][2];
  const f32x4 zf = {0.f, 0.f, 0.f, 0.f};
  for (int m = 0; m < 4; ++m)
    for (int n = 0; n < 2; ++n) acc[m][n] = zf;

  // stage one 128x64 A-tile + B-tile pair (4 load instrs per thread/wave)
  auto STAGE = [&](int buf, int kt) {
    char* At = smem + buf * 32768;
    char* Bs = At + 16384;
#pragma unroll
    for (int s = 0; s < 2; ++s) {
      const int p = s * 8192 + tid * 16;           // byte in 16KB tile
      const int r = p >> 7;                        // tile row 0..127
      const int scb = (p & 127) ^ ((r & 7) << 4);  // swizzled source col byte
      int gr = row0 + r; gr = gr < M ? gr : M - 1;
      gload_lds16((const char*)A + ((size_t)gr * lda + kt) * 2 + scb,
                  At + s * 8192 + wid * 1024);
      const int gc = col0 + r;                     // N multiple of 128
      gload_lds16((const char*)Bt + ((size_t)gc * K + kt) * 2 + scb,
                  Bs + s * 8192 + wid * 1024);
    }
  };

  // prologue: 2 stages in flight (K >= 128 for all call sites)
  STAGE(0, 0);
  STAGE(1, 64);
  int cur = 0;
  for (int kt = 0; kt < K; kt += 64) {
    // wait only for buf[cur]'s loads; newer stage (if any) stays in flight
    if (kt + 64 < K) {
      asm volatile("s_waitcnt vmcnt(4)" ::: "memory");
    } else {
      asm volatile("s_waitcnt vmcnt(0)" ::: "memory");
    }
    __builtin_amdgcn_s_barrier();
    const char* At = smem + cur * 32768;
    const char* Bs = At + 16384;
#pragma unroll
    for (int kk = 0; kk < 64; kk += 32) {
      bf16x8 af[4], bfr[2];
#pragma unroll
      for (int m = 0; m < 4; ++m) {
        const int r = wr + m * 16 + l15;
        const int cb2 = ((kk + l4 * 8) * 2) ^ ((r & 7) << 4);
        af[m] = *(const bf16x8*)(At + r * 128 + cb2);
      }
#pragma unroll
      for (int n = 0; n < 2; ++n) {
        const int r = wc + n * 16 + l15;
        const int cb2 = ((kk + l4 * 8) * 2) ^ ((r & 7) << 4);
        bfr[n] = *(const bf16x8*)(Bs + r * 128 + cb2);
      }
#pragma unroll
      for (int m = 0; m < 4; ++m)
#pragma unroll
        for (int n = 0; n < 2; ++n)
          acc[m][n] = __builtin_amdgcn_mfma_f32_16x16x32_bf16(af[m], bfr[n],
                                                              acc[m][n], 0, 0, 0);
    }
    // all waves done reading buf[cur] -> safe to overwrite
    asm volatile("s_waitcnt lgkmcnt(0)" ::: "memory");
    __builtin_amdgcn_s_barrier();
    if (kt + 128 < K) STAGE(cur, kt + 128);
    cur ^= 1;
  }

  const bool fp8path = (EPI == 3) || (EPI == 4 && cb >= 2);
  // C/D layout: col=lane&15, row=(lane>>4)*4+reg   [guide §3, m89/m91]
  if (EPI == 2) {
#pragma unroll
    for (int m = 0; m < 4; ++m)
#pragma unroll
      for (int jj = 0; jj < 4; ++jj) {
        const int gr = row0 + wr + m * 16 + l4 * 4 + jj;
        if (gr >= M) continue;
#pragma unroll
        for (int n = 0; n < 2; ++n) {
          const int gc = col0 + wc + n * 16 + l15;
          const float v = acc[m][n][jj] + bias[gc];
          const float gt = bf2f(gate[(size_t)gr * 1536 + gc]);
          const float xv =
              XINBF ? bf2f(((const unsigned short*)xin)[(size_t)gr * ldo + gc])
                    : ((const float*)xin)[(size_t)gr * ldo + gc];
          const float rv = xv + gt * v;
          if (OUTBF)
            ((unsigned short*)out)[(size_t)gr * ldo + gc] = f2bf(rv);
          else
            ((float*)out)[(size_t)gr * ldo + gc] = rv;
        }
      }
  } else if (fp8path) {
    // fp8 e5m2: byte repack through smem [128][128]B, 16B stores
#pragma unroll
    for (int m = 0; m < 4; ++m)
#pragma unroll
      for (int jj = 0; jj < 4; ++jj) {
        const int row_l = wr + m * 16 + l4 * 4 + jj;  // 0..127
        const int swz = (row_l & 12) << 2;
#pragma unroll
        for (int n = 0; n < 2; ++n) {
          const int col = wc + n * 16 + l15;          // 0..127
          const float v = acc[m][n][jj] + bias[col0 + col];
          const unsigned short h =
              __builtin_bit_cast(unsigned short, (_Float16)v);
          const unsigned char b8 =
              (unsigned char)((h + 0x7fu + ((h >> 8) & 1u)) >> 8);
          ((unsigned char*)smem)[row_l * 128 + (col ^ swz)] = b8;
        }
      }
    __syncthreads();
#pragma unroll
    for (int pp = 0; pp < 2; ++pp) {
      const int u = pp * 512 + tid;       // 1024 16B units
      const int row_l = u >> 3;
      const int cb16 = (u & 7) * 16;
      const int gr = row0 + row_l;
      if (gr < M) {
        const bf16x8 vv = *(const bf16x8*)((const unsigned char*)smem +
                                           row_l * 128 +
                                           (cb16 ^ ((row_l & 12) << 2)));
        unsigned char* op =
            (EPI == 4)
                ? (unsigned char*)out + (size_t)gr * 1024 + 512 +
                      (col0 - 256) + cb16
                : (unsigned char*)out + (size_t)gr * ldo + col0 + cb16;
        *(bf16x8*)op = vv;
      }
    }
  } else {
    // bf16 out: full-tile repack through smem [128][128] u16, 16B stores
    unsigned short* R = (unsigned short*)smem;
#pragma unroll
    for (int m = 0; m < 4; ++m)
#pragma unroll
      for (int jj = 0; jj < 4; ++jj) {
        const int row_l = wr + m * 16 + l4 * 4 + jj;  // 0..127
        const int swz = (row_l & 12) << 2;            // u16 XOR 0/16/32/48
#pragma unroll
        for (int n = 0; n < 2; ++n) {
          const int col = wc + n * 16 + l15;
          float v = acc[m][n][jj] + bias[col0 + col];
          if (EPI == 1) {
            // gelu_tanh(v) == v*sigmoid(2u); 2u*log2e = 2.3026(v+0.044715v^3)
            v = v * sigm_fast(2.3025851f * (v + 0.044715f * v * v * v));
          }
          R[row_l * 128 + (col ^ swz)] = f2bf(v);
        }
      }
    __syncthreads();
#pragma unroll
    for (int pp = 0; pp < 4; ++pp) {
      const int u = pp * 512 + tid;       // 2048 16B units
      const int row_l = u >> 4;
      const int col8 = (u & 15) * 8;
      const int gr = row0 + row_l;
      if (gr < M) {
        const bf16x8 vv =
            *(const bf16x8*)&R[row_l * 128 + (col8 ^ ((row_l & 12) << 2))];
        unsigned short* op =
            (EPI == 4) ? (unsigned short*)out + (size_t)gr * 512 + col0 + col8
                       : (unsigned short*)out + (size_t)gr * ldo + col0 + col8;
        *(bf16x8*)op = vv;
      }
    }
  }
}

// ---------------------------------------------------------------------------
// helpers
// ---------------------------------------------------------------------------
__global__ void sentinel_fill(float* o, long n, float v) {
  long i = (long)blockIdx.x * blockDim.x + threadIdx.x;
  const long st = (long)gridDim.x * blockDim.x;
  for (; i < n; i += st) o[i] = (i == 0) ? v : 0.f;
}

// fused prep: weight transposes (kv-interleave for Wk/Wv), bias concat,
// deg zeroing, int64-detect, silu(c)->bf16 (grid-stride).  dim3(1536, 11).
__global__ void prep_weights(const float* __restrict__ Wc, const float* __restrict__ Wq,
                             const float* __restrict__ Wk, const float* __restrict__ Wv,
                             const float* __restrict__ Wo, const float* __restrict__ W1,
                             const float* __restrict__ W2,
                             unsigned short* __restrict__ Wct,
                             unsigned short* __restrict__ Wqkvt,
                             unsigned short* __restrict__ Wot,
                             unsigned short* __restrict__ W1t,
                             unsigned short* __restrict__ W2t,
                             const float* __restrict__ bq, const float* __restrict__ bk,
                             const float* __restrict__ bv, float* __restrict__ bqkv,
                             int* __restrict__ deg, int Mdeg,
                             const unsigned int* __restrict__ ei_u32, int E,
                             int* __restrict__ flag,
                             const float* __restrict__ c,
                             unsigned short* __restrict__ cs, int silu4) {
  const int job = blockIdx.y;
  const int i = blockIdx.x * 256 + threadIdx.x;
  if (job == 7) {  // bias concat (kv-interleaved)
    if (i < 256) bqkv[i] = bq[i];
    else if (i < 512) { int d = i - 256; bqkv[256 + ((d >> 2) << 3) + (d & 3)] = bk[d]; }
    else if (i < 768) { int d = i - 512; bqkv[256 + ((d >> 2) << 3) + 4 + (d & 3)] = bv[d]; }
    return;
  }
  if (job == 8) {  // zero deg
    if (i < Mdeg) deg[i] = 0;
    return;
  }
  if (job == 9) {  // int64 detect (block 0 only)
    if (blockIdx.x != 0) return;
    __shared__ int bad;
    if (threadIdx.x == 0) bad = 0;
    __syncthreads();
    const int n = E < 256 ? E : 256;
    if ((int)threadIdx.x < n && ei_u32[2 * threadIdx.x + 1] != 0u) atomicAdd(&bad, 1);
    __syncthreads();
    if (threadIdx.x == 0) *flag = (bad == 0);
    return;
  }
  if (job == 10) {  // silu(c) -> bf16, grid-stride over float4 granules
    const int stride = gridDim.x * 256;
    for (int g = i; g < silu4; g += stride) {
      float4 v = *(const float4*)&c[(size_t)g * 4];
      ushort4 r;
      r.x = f2bf(v.x * sigm_fast(1.4426950f * v.x));
      r.y = f2bf(v.y * sigm_fast(1.4426950f * v.y));
      r.z = f2bf(v.z * sigm_fast(1.4426950f * v.z));
      r.w = f2bf(v.w * sigm_fast(1.4426950f * v.w));
      *(ushort4*)&cs[(size_t)g * 4] = r;
    }
    return;
  }
  const float* W; unsigned short* Wt; int N, kc, mode = 0;
  switch (job) {
    case 0: W = Wc; Wt = Wct; N = 1536; kc = 256; break;
    case 1: W = Wq; Wt = Wqkvt; N = 256; kc = 256; break;
    case 2: W = Wk; Wt = Wqkvt + 256 * 256; N = 256; kc = 256; mode = 1; break;
    case 3: W = Wv; Wt = Wqkvt + 256 * 256; N = 256; kc = 256; mode = 2; break;
    case 4: W = Wo; Wt = Wot; N = 256; kc = 256; break;
    case 5: W = W1; Wt = W1t; N = 1024; kc = 256; break;
    default: W = W2; Wt = W2t; N = 256; kc = 1024; break;
  }
  if (i >= N * kc) return;
  const int kk = i / N, n = i - kk * N;
  int r = n;
  if (mode == 1) r = ((n >> 2) << 3) + (n & 3);
  else if (mode == 2) r = ((n >> 2) << 3) + 4 + (n & 3);
  Wt[(size_t)r * kc + kk] = f2bf(W[(size_t)kk * N + n]);
}

// one wave per row: h = ((x-mean)*rstd)*(1+scale)+shift -> bf16
template <int INBF>
__global__ void ln_modulate(const void* __restrict__ xin,
                            const unsigned short* __restrict__ modv,
                            unsigned short* __restrict__ hout,
                            int M, int cshift, int cscale) {
  const int wid = threadIdx.x >> 6, lane = threadIdx.x & 63;
  const int row = blockIdx.x * 4 + wid;
  if (row >= M) return;
  float4 x4;
  if (INBF) {
    const ushort4 u4 =
        *(const ushort4*)((const unsigned short*)xin + (size_t)row * 256 + lane * 4);
    x4.x = bf2f(u4.x); x4.y = bf2f(u4.y); x4.z = bf2f(u4.z); x4.w = bf2f(u4.w);
  } else {
    x4 = *(const float4*)((const float*)xin + (size_t)row * 256 + lane * 4);
  }
  float s = x4.x + x4.y + x4.z + x4.w;
  float ss = x4.x * x4.x + x4.y * x4.y + x4.z * x4.z + x4.w * x4.w;
#pragma unroll
  for (int m = 1; m < 64; m <<= 1) {
    s += __shfl_xor(s, m, 64);
    ss += __shfl_xor(ss, m, 64);
  }
  const float mean = s * (1.f / 256.f);
  const float var = ss * (1.f / 256.f) - mean * mean;
  const float rstd = rsqrtf(var + 1e-6f);
  const ushort4 sh4 = *(const ushort4*)&modv[(size_t)row * 1536 + cshift * 256 + lane * 4];
  const ushort4 sc4 = *(const ushort4*)&modv[(size_t)row * 1536 + cscale * 256 + lane * 4];
  ushort4 o;
  o.x = f2bf((x4.x - mean) * rstd * (1.f + bf2f(sc4.x)) + bf2f(sh4.x));
  o.y = f2bf((x4.y - mean) * rstd * (1.f + bf2f(sc4.y)) + bf2f(sh4.y));
  o.z = f2bf((x4.z - mean) * rstd * (1.f + bf2f(sc4.z)) + bf2f(sh4.z));
  o.w = f2bf((x4.w - mean) * rstd * (1.f + bf2f(sc4.w)) + bf2f(sh4.w));
  *(ushort4*)&hout[(size_t)row * 256 + lane * 4] = o;
}

// unpack edge_index -> src32/dst32 and histogram dst degree (fused)
__global__ void conv_hist(const void* __restrict__ ei, const int* __restrict__ flag,
                          int* __restrict__ src32, int* __restrict__ dst32,
                          int* __restrict__ deg, int E) {
  int e = blockIdx.x * blockDim.x + threadIdx.x;
  if (e >= E) return;
  int s, d;
  if (*flag) {
    const long long* p = (const long long*)ei;
    s = (int)p[e]; d = (int)p[E + e];
  } else {
    const int* p = (const int*)ei;
    s = p[e]; d = p[E + e];
  }
  src32[e] = s; dst32[e] = d;
  atomicAdd(&deg[d], 1);
}

// 2-phase scan: per-block sums, then scan_final self-reduces the block sums
__global__ __launch_bounds__(256)
void block_sum(const int* __restrict__ deg, int* __restrict__ bsum, int M) {
  int i = blockIdx.x * 256 + threadIdx.x;
  int v = (i < M) ? deg[i] : 0;
#pragma unroll
  for (int d = 1; d < 64; d <<= 1) v += __shfl_xor(v, d, 64);
  __shared__ int ws[4];
  const int lane = threadIdx.x & 63, w = threadIdx.x >> 6;
  if (lane == 0) ws[w] = v;
  __syncthreads();
  if (threadIdx.x == 0) bsum[blockIdx.x] = ws[0] + ws[1] + ws[2] + ws[3];
}

__global__ __launch_bounds__(256)
void scan_final(const int* __restrict__ deg, const int* __restrict__ bsum,
                int* __restrict__ start, int* __restrict__ cursor, int M, int NB) {
  const int b = blockIdx.x, t = threadIdx.x, i = b * 256 + t;
  const int lane = t & 63, w = t >> 6;
  __shared__ int ws[4];
  __shared__ int pref;
  const int v = (i < M) ? deg[i] : 0;
  int s = v;
#pragma unroll
  for (int d = 1; d < 64; d <<= 1) {
    int u = __shfl_up(s, d, 64);
    if (lane >= d) s += u;
  }
  if (lane == 63) ws[w] = s;
  if (t < 64) {  // wave 0 reduces bsum[0..b-1]
    int acc = 0;
    for (int base = 0; base < b; base += 64) {
      const int idx = base + lane;
      acc += (idx < b) ? bsum[idx] : 0;
    }
#pragma unroll
    for (int d = 1; d < 64; d <<= 1) acc += __shfl_xor(acc, d, 64);
    if (lane == 0) pref = acc;
  }
  __syncthreads();
  int add = pref;
  for (int k = 0; k < w; ++k) add += ws[k];
  const int excl = s - v + add;
  if (i < M) { start[i] = excl; cursor[i] = excl; }
  if (i == M - 1) start[M] = excl + v;
}

__global__ void csr_fill(const int* __restrict__ src32, const int* __restrict__ dst32,
                         int* __restrict__ cursor, int* __restrict__ csr, int E) {
  int e = blockIdx.x * blockDim.x + threadIdx.x;
  if (e >= E) return;
  int pos = atomicAdd(&cursor[dst32[e]], 1);
  csr[pos] = src32[e];
}

// one wave per dst node; 2-deep batch-4 pipeline.  Row layout (1024 B):
// [q bf16 512B][kv fp8 e5m2 512B, lane l's 8B = k[4l..4l+3]|v[4l..4l+3]].
// Decode: v_perm_b32; QK dot in packed f16, accumulation in f32.
__global__ __launch_bounds__(256)
void attn_gather(const int* __restrict__ csr, const int* __restrict__ start,
                 const unsigned char* __restrict__ qkvp,
                 unsigned short* __restrict__ aggb, int M) {
  const int wid = threadIdx.x >> 6, lane = threadIdx.x & 63;
  const int row = blockIdx.x * 4 + wid;
  if (row >= M) return;
  const ushort4 q4 = *(const ushort4*)(qkvp + (size_t)row * 1024 + lane * 8);
  const float SC = 0.17677669529663687f;  // 32^-0.5, folded into q
  h2_t q01h, q23h;
  q01h[0] = (_Float16)(bf2f(q4.x) * SC); q01h[1] = (_Float16)(bf2f(q4.y) * SC);
  q23h[0] = (_Float16)(bf2f(q4.z) * SC); q23h[1] = (_Float16)(bf2f(q4.w) * SC);
  const int b0 = start[row], e0 = start[row + 1];
  float den = 0.f, a0 = 0.f, a1 = 0.f, a2 = 0.f, a3 = 0.f;

  auto LDKV = [&](int src) {
    return *(const uint2*)(qkvp + (size_t)src * 1024 + 512 + lane * 8);
  };
#define PROC(kv2)                                                              \
  {                                                                            \
    const unsigned kd = kv2.x, vd = kv2.y;                                     \
    const h2_t k01 = __builtin_bit_cast(                                       \
        h2_t, __builtin_amdgcn_perm(0u, kd, 0x010C000Cu));                     \
    const h2_t k23 = __builtin_bit_cast(                                       \
        h2_t, __builtin_amdgcn_perm(0u, kd, 0x030C020Cu));                     \
    h2_t ph = k01 * q01h;                                                      \
    ph = k23 * q23h + ph;                                                      \
    float s = (float)ph[0] + (float)ph[1];                                     \
    s += __shfl_xor(s, 1, 64);                                                 \
    s += __shfl_xor(s, 2, 64);                                                 \
    s += __shfl_xor(s, 4, 64);                                                 \
    const float ex = __expf(s);                                                \
    const h2_t v01 = __builtin_bit_cast(                                       \
        h2_t, __builtin_amdgcn_perm(0u, vd, 0x010C000Cu));                     \
    const h2_t v23 = __builtin_bit_cast(                                       \
        h2_t, __builtin_amdgcn_perm(0u, vd, 0x030C020Cu));                     \
    den += ex;                                                                 \
    a0 += ex * (float)v01[0]; a1 += ex * (float)v01[1];                        \
    a2 += ex * (float)v23[0]; a3 += ex * (float)v23[1];                        \
  }

  int i = b0;
  if (i + 4 <= e0) {
    uint2 A0 = LDKV(csr[i]), A1 = LDKV(csr[i + 1]);
    uint2 A2 = LDKV(csr[i + 2]), A3 = LDKV(csr[i + 3]);
    while (i + 8 <= e0) {
      const uint2 B0 = LDKV(csr[i + 4]), B1 = LDKV(csr[i + 5]);
      const uint2 B2 = LDKV(csr[i + 6]), B3 = LDKV(csr[i + 7]);
      PROC(A0); PROC(A1); PROC(A2); PROC(A3);
      A0 = B0; A1 = B1; A2 = B2; A3 = B3;
      i += 4;
    }
    PROC(A0); PROC(A1); PROC(A2); PROC(A3);
    i += 4;
  }
  for (; i < e0; ++i) {
    const uint2 kv2 = LDKV(csr[i]);
    PROC(kv2);
  }
#undef PROC

  const float inv = den > 0.f ? __builtin_amdgcn_rcpf(den) : 0.f;
  ushort4 r;
  r.x = f2bf(a0 * inv); r.y = f2bf(a1 * inv);
  r.z = f2bf(a2 * inv); r.w = f2bf(a3 * inv);
  *(ushort4*)&aggb[(size_t)row * 256 + lane * 4] = r;
}

// ---------------------------------------------------------------------------
extern "C" void kernel_launch(void* const* d_in, const int* in_sizes, int n_in,
                              void* d_out, int out_size, void* d_ws, size_t ws_size,
                              hipStream_t stream) {
  (void)n_in;
  const float* x  = (const float*)d_in[0];
  const float* c  = (const float*)d_in[1];
  const void*  ei = d_in[2];
  const float* Wq = (const float*)d_in[3];
  const float* bq = (const float*)d_in[4];
  const float* Wk = (const float*)d_in[5];
  const float* bk = (const float*)d_in[6];
  const float* Wv = (const float*)d_in[7];
  const float* bv = (const float*)d_in[8];
  const float* Wo = (const float*)d_in[9];
  const float* bo = (const float*)d_in[10];
  const float* W1 = (const float*)d_in[11];
  const float* b1 = (const float*)d_in[12];
  const float* W2 = (const float*)d_in[13];
  const float* b2 = (const float*)d_in[14];
  const float* Wc = (const float*)d_in[15];
  const float* bc = (const float*)d_in[16];

  const int M = in_sizes[0] / 256;   // 50000
  const int E = in_sizes[2] / 2;     // 800000

  char* ws = (char*)d_ws;
  size_t off = 0;
  auto carve = [&](size_t bytes) {
    char* p = ws + off;
    off = (off + bytes + 255) & ~(size_t)255;
    return p;
  };
  // persistent: modv [M,1536]b; cols 0..1024 reused as h2 (ldo=1536) after ln2
  unsigned short* modv = (unsigned short*)carve((size_t)M * 1536 * 2);  // 153.6MB
  // region D (M*1024 bytes): cs -> qkvp [M,1024B] -> X1b [M,256]bf16
  char* D = carve((size_t)M * 1024);
  unsigned short* cs = (unsigned short*)D;
  unsigned char* qkvp = (unsigned char*)D;
  unsigned short* X1b = (unsigned short*)D;
  unsigned short* Wct   = (unsigned short*)carve((size_t)1536 * 256 * 2);
  unsigned short* Wqkvt = (unsigned short*)carve((size_t)768 * 256 * 2);
  unsigned short* Wot   = (unsigned short*)carve((size_t)256 * 256 * 2);
  unsigned short* W1t   = (unsigned short*)carve((size_t)1024 * 256 * 2);
  unsigned short* W2t   = (unsigned short*)carve((size_t)256 * 1024 * 2);
  float* bqkv = (float*)carve(768 * 4);
  int* flag = (int*)carve(256);
  // CSR buffers
  int* src32  = (int*)carve((size_t)E * 4);
  int* dst32  = (int*)carve((size_t)E * 4);
  int* deg    = (int*)carve((size_t)(M + 4) * 4);
  int* startp = (int*)carve((size_t)(M + 4) * 4);
  int* cursor = (int*)carve((size_t)(M + 4) * 4);
  int* csr    = (int*)carve((size_t)E * 4);
  int* bsum   = (int*)carve(1024);

  // d_out aliases: lo half hbuf/hbuf2 [M,256]b; hi half aggb [M,256]b
  unsigned short* hbuf  = (unsigned short*)d_out;
  unsigned short* hbuf2 = (unsigned short*)d_out;
  unsigned short* aggb  = (unsigned short*)((char*)d_out + (size_t)M * 512);
  float* xout = (float*)d_out;

  if (off > ws_size) {
    sentinel_fill<<<2048, 256, 0, stream>>>((float*)d_out, (long)out_size,
                                            (float)ws_size);
    return;
  }

  const int tb = 256;
  const int EB = (E + tb - 1) / tb;
  const int SB = (M + 255) / 256;

  prep_weights<<<dim3(1536, 11), 256, 0, stream>>>(
      Wc, Wq, Wk, Wv, Wo, W1, W2, Wct, Wqkvt, Wot, W1t, W2t,
      bq, bk, bv, bqkv, deg, M + 4, (const unsigned int*)ei, E, flag,
      c, cs, M * 64);
  // --- CSR build ---
  conv_hist<<<EB, tb, 0, stream>>>(ei, flag, src32, dst32, deg, E);
  block_sum<<<SB, 256, 0, stream>>>(deg, bsum, M);
  scan_final<<<SB, 256, 0, stream>>>(deg, bsum, startp, cursor, M, SB);
  csr_fill<<<EB, tb, 0, stream>>>(src32, dst32, cursor, csr, E);

  auto gsz = [](int Mz, int Nz) {
    int MT = (Mz + 127) / 128, NT = Nz / 128;
    return 8 * ((MT + 7) / 8) * NT;
  };
  // modv = cs @ Wc + bc   [M,1536]
  gemm_bf16<0, 0, 0><<<gsz(M, 1536), 512, 0, stream>>>(
      cs, Wct, bc, nullptr, nullptr, modv, M, 1536, 256, 256, 1536);
  // hbuf = modulate(ln(x), shift_msa, scale_msa)
  ln_modulate<0><<<(M + 3) / 4, 256, 0, stream>>>(x, modv, hbuf, M, 0, 1);
  // merged qkv: cols 0-255 bf16 q, cols 256-767 fp8 kv (EPI4)
  gemm_bf16<4, 0, 0><<<gsz(M, 768), 512, 0, stream>>>(
      hbuf, Wqkvt, bqkv, nullptr, nullptr, qkvp, M, 768, 256, 256, 0);
  // aggb(d_out hi) = per-dst softmax gather (fp8 kv)
  attn_gather<<<(M + 3) / 4, 256, 0, stream>>>(csr, startp, qkvp, aggb, M);
  // X1b(D) = bf16(x + gate_msa * (aggb @ Wo + bo))
  gemm_bf16<2, 0, 1><<<gsz(M, 256), 512, 0, stream>>>(
      aggb, Wot, bo, x, modv + 512, X1b, M, 256, 256, 256, 256);
  // hbuf2(d_out lo) = modulate(ln(X1b), shift_mlp, scale_mlp)
  ln_modulate<1><<<(M + 3) / 4, 256, 0, stream>>>(X1b, modv, hbuf2, M, 3, 4);
  // h2(modv cols 0..1024, ld 1536) = gelu(hbuf2 @ W1 + b1)   [M,1024]
  gemm_bf16<1, 0, 0><<<gsz(M, 1024), 512, 0, stream>>>(
      hbuf2, W1t, b1, nullptr, nullptr, modv, M, 1024, 256, 256, 1536);
  // out(d_out) = X1b + gate_mlp * (h2 @ W2 + b2)   [f32]
  gemm_bf16<2, 1, 0><<<gsz(M, 256), 512, 0, stream>>>(
      modv, W2t, b2, X1b, modv + 1280, xout, M, 256, 1024, 1536, 256);
}